// Round 7
// baseline (944.230 us; speedup 1.0000x reference)
//
#include <hip/hip_runtime.h>
#include <math.h>

// GATNet_MLP R7: LDS-free register GEMM. Insight: with a 64x32 wave tile the A
// fragments have zero cross-wave reuse (rows partitioned by wave/mt/frow) and B
// (256KB weights) is L2-resident -- LDS staging was pure overhead (R6 counters:
// 72KB/block-iter LDS traffic + 4.8M conflict cyc + barrier coupling = 73us).
// Waves load fragments global->VGPR, manually double-buffered over K; no barriers.
// A-plane rows padded to 50048 + zeroed per call -> unguarded loads.

#define N_NODES 50000
#define NPAD    50048    // 782 * 64
#define N_EDGES 400000
#define N_GRAPH 64
#define DIN     128
#define NHC     256
#define DOUT    32

typedef _Float16 f16x8 __attribute__((ext_vector_type(8)));
typedef _Float16 f16x4 __attribute__((ext_vector_type(4)));
typedef float    f32x4 __attribute__((ext_vector_type(4)));

// ================= fp16x2-split register MFMA GEMM =================
// Block = 4 waves = 64 rows x 128 cols (wave: 64x32). A planes [NPAD][K],
// B planes [Npad_cols][K] transposed. mode 0: C fp32 [nrow][256];
// mode 1: bias+gelu -> fp16 planes (stride 256); mode 2: bias -> fp32 [nrow][ncols].
__global__ __launch_bounds__(256) void mfma_gemm_kernel(
    const _Float16* __restrict__ Ah, const _Float16* __restrict__ Al,
    const _Float16* __restrict__ Bh, const _Float16* __restrict__ Bl,
    const float* __restrict__ bias, float* __restrict__ C,
    _Float16* __restrict__ Oh, _Float16* __restrict__ Ol,
    int nrow, int K, int ncols, int mode)
{
    const int lane = threadIdx.x & 63, wid = threadIdx.x >> 6;

    // XCD swizzle (gridX==2): bids b,b+8 (same XCD slot mod 8) are the two
    // col-slabs of one 64-row slab -> A slab L2-resident per XCD (R5-verified idea).
    int xt, yt;
    if (gridDim.x == 2) {
        int bid = blockIdx.x + (blockIdx.y << 1);
        yt = (bid >> 4) * 8 + (bid & 7);
        xt = (bid >> 3) & 1;
    } else { xt = blockIdx.x; yt = blockIdx.y; }
    const int row0 = yt * 64;
    if (row0 >= nrow) return;                    // uniform exit (grid Y padded)
    const int col0 = xt * 128 + wid * 32;

    const int frow = lane & 15;
    const long koff = (long)(lane >> 4) * 8;

    long aoff[4], boff[2];
#pragma unroll
    for (int mt = 0; mt < 4; mt++) aoff[mt] = (long)(row0 + mt * 16 + frow) * K + koff;
#pragma unroll
    for (int nt = 0; nt < 2; nt++) boff[nt] = (long)(col0 + nt * 16 + frow) * K + koff;

    f32x4 acc[4][2] = {};
    f16x8 a0[4][2], b0[2][2], a1[4][2], b1[2][2];

#define LOADSET(as, bs, kb) do {                                              \
    _Pragma("unroll") for (int mt = 0; mt < 4; mt++) {                        \
        as[mt][0] = *(const f16x8*)(Ah + aoff[mt] + (kb));                    \
        as[mt][1] = *(const f16x8*)(Al + aoff[mt] + (kb)); }                  \
    _Pragma("unroll") for (int nt = 0; nt < 2; nt++) {                        \
        bs[nt][0] = *(const f16x8*)(Bh + boff[nt] + (kb));                    \
        bs[nt][1] = *(const f16x8*)(Bl + boff[nt] + (kb)); }                  \
} while (0)

#define MFMASET(as, bs) do {                                                  \
    _Pragma("unroll") for (int mt = 0; mt < 4; mt++)                          \
    _Pragma("unroll") for (int nt = 0; nt < 2; nt++) {                        \
        acc[mt][nt] = __builtin_amdgcn_mfma_f32_16x16x32_f16(as[mt][0], bs[nt][0], acc[mt][nt], 0, 0, 0); \
        acc[mt][nt] = __builtin_amdgcn_mfma_f32_16x16x32_f16(as[mt][0], bs[nt][1], acc[mt][nt], 0, 0, 0); \
        acc[mt][nt] = __builtin_amdgcn_mfma_f32_16x16x32_f16(as[mt][1], bs[nt][0], acc[mt][nt], 0, 0, 0); } \
} while (0)

    LOADSET(a0, b0, 0);
    const int iters = K >> 5;                    // 4 (K=128) or 8 (K=256): even
    for (int it = 0; it < iters; it += 2) {
        LOADSET(a1, b1, (long)(it + 1) * 32);    // in flight during MFMA(set0)
        MFMASET(a0, b0);
        if (it + 2 < iters) LOADSET(a0, b0, (long)(it + 2) * 32);
        MFMASET(a1, b1);
    }
#undef LOADSET
#undef MFMASET

    // epilogue: C/D layout col=lane&15, row=(lane>>4)*4+reg
    const int crow0 = row0 + (lane >> 4) * 4;
    const int ccol0 = col0 + (lane & 15);
#pragma unroll
    for (int mt = 0; mt < 4; mt++) {
#pragma unroll
        for (int nt = 0; nt < 2; nt++) {
            int col = ccol0 + nt * 16;
#pragma unroll
            for (int r = 0; r < 4; r++) {
                int row = crow0 + mt * 16 + r;
                if (row >= nrow) continue;
                float v = acc[mt][nt][r];
                if (mode == 0) {
                    C[(long)row * 256 + col] = v;
                } else if (mode == 1) {
                    v += bias[col];
                    v = 0.5f * v * (1.f + erff(v * 0.7071067811865475f));
                    _Float16 hh = (_Float16)v;
                    Oh[(long)row * 256 + col] = hh;
                    Ol[(long)row * 256 + col] = (_Float16)(v - (float)hh);
                } else {
                    if (col < ncols) {
                        v += bias[col];
                        C[(long)row * ncols + col] = v;
                    }
                }
            }
        }
    }
}

// -------- split fp32 -> fp16 hi/lo planes --------
__global__ __launch_bounds__(256) void split_kernel(
    const float* __restrict__ in, _Float16* __restrict__ oh, _Float16* __restrict__ ol, int n4)
{
    int i = blockIdx.x * 256 + threadIdx.x;
    if (i >= n4) return;
    float4 v = ((const float4*)in)[i];
    f16x4 h, l;
    h[0] = (_Float16)v.x; l[0] = (_Float16)(v.x - (float)h[0]);
    h[1] = (_Float16)v.y; l[1] = (_Float16)(v.y - (float)h[1]);
    h[2] = (_Float16)v.z; l[2] = (_Float16)(v.z - (float)h[2]);
    h[3] = (_Float16)v.w; l[3] = (_Float16)(v.w - (float)h[3]);
    *(f16x4*)(oh + (long)i * 4) = h;
    *(f16x4*)(ol + (long)i * 4) = l;
}

// -------- transpose + split weights: W[K][N] fp32 -> planes [Npad][K] --------
__global__ __launch_bounds__(256) void tsplit_kernel(
    const float* __restrict__ W, _Float16* __restrict__ Bh, _Float16* __restrict__ Bl,
    int K, int N, int Npad)
{
    int id = blockIdx.x * 256 + threadIdx.x;
    if (id >= Npad * K) return;
    int n = id / K, k = id - n * K;
    float v = (n < N) ? W[(long)k * N + n] : 0.f;
    _Float16 h = (_Float16)v;
    Bh[id] = h;
    Bl[id] = (_Float16)(v - (float)h);
}

// -------- per-node attention scalars --------
__global__ __launch_bounds__(256) void asd_kernel(
    const float* __restrict__ h, const float* __restrict__ atts, const float* __restrict__ attd,
    float* __restrict__ asb, float* __restrict__ adb, int total, int H, int C)
{
    int i = blockIdx.x * 256 + threadIdx.x;
    if (i >= total) return;
    int n = i / H, hh = i - n * H;
    const float4* hp = (const float4*)(h + (long)n * NHC + hh * C);
    const float4* sp = (const float4*)(atts + hh * C);
    const float4* dp = (const float4*)(attd + hh * C);
    float ss = 0.f, dd = 0.f;
    for (int c = 0; c < C / 4; c++) {
        float4 hv = hp[c], sv = sp[c], dv = dp[c];
        ss += hv.x * sv.x + hv.y * sv.y + hv.z * sv.z + hv.w * sv.w;
        dd += hv.x * dv.x + hv.y * dv.y + hv.z * dv.z + hv.w * dv.w;
    }
    asb[i] = ss; adb[i] = dd;
}

// -------- Me[j,h] = sum_c We[j, h*C+c] * ae[h*C+c] --------
__global__ void me_kernel(const float* __restrict__ We, const float* __restrict__ ae,
                          float* __restrict__ Me, int H, int C)
{
    int i = threadIdx.x;
    if (i >= 5 * H) return;
    int j = i / H, hh = i - j * H;
    float s = 0.f;
    for (int c = 0; c < C; c++) s += We[j * NHC + hh * C + c] * ae[hh * C + c];
    Me[i] = s;
}

// -------- edge-parallel p --------
__global__ __launch_bounds__(256) void edge_p_kernel(
    const int* __restrict__ ei, const float* __restrict__ ea,
    const float* __restrict__ asb, const float* __restrict__ adb,
    const float* __restrict__ Me, float* __restrict__ p, int E, int H)
{
    int e = blockIdx.x * 256 + threadIdx.x;
    if (e >= E) return;
    int src = ei[e], dst = ei[E + e];
    float a0 = ea[e * 5 + 0], a1 = ea[e * 5 + 1], a2 = ea[e * 5 + 2],
          a3 = ea[e * 5 + 3], a4 = ea[e * 5 + 4];
    for (int h = 0; h < H; h++) {
        float aeh = a0 * Me[0 * H + h] + a1 * Me[1 * H + h] + a2 * Me[2 * H + h]
                  + a3 * Me[3 * H + h] + a4 * Me[4 * H + h];
        float al = asb[src * H + h] + adb[dst * H + h] + aeh;
        al = fmaxf(al, 0.2f * al);
        p[(long)e * H + h] = expf(al);
    }
}

// ================= CSR build (entries packed int2{src,eid}) =================
__global__ __launch_bounds__(256) void count_kernel(
    const int* __restrict__ ei, int* __restrict__ deg, int E)
{
    int e = blockIdx.x * 256 + threadIdx.x;
    if (e < E) atomicAdd(&deg[ei[E + e]], 1);
}

__global__ __launch_bounds__(256) void scan_block_kernel(
    const int* __restrict__ deg, int* __restrict__ rowstart, int* __restrict__ partial, int n)
{
    __shared__ int s[256];
    int i = blockIdx.x * 256 + threadIdx.x;
    int v = (i < n) ? deg[i] : 0;
    s[threadIdx.x] = v;
    __syncthreads();
    for (int off = 1; off < 256; off <<= 1) {
        int t = (threadIdx.x >= off) ? s[threadIdx.x - off] : 0;
        __syncthreads();
        s[threadIdx.x] += t;
        __syncthreads();
    }
    if (i < n) rowstart[i] = s[threadIdx.x] - v;
    if (threadIdx.x == 255) partial[blockIdx.x] = s[255];
}

__global__ __launch_bounds__(256) void scan_partial_kernel(int* __restrict__ partial, int nb)
{
    __shared__ int s[256];
    int v = (threadIdx.x < nb) ? partial[threadIdx.x] : 0;
    s[threadIdx.x] = v;
    __syncthreads();
    for (int off = 1; off < 256; off <<= 1) {
        int t = (threadIdx.x >= off) ? s[threadIdx.x - off] : 0;
        __syncthreads();
        s[threadIdx.x] += t;
        __syncthreads();
    }
    if (threadIdx.x < nb) partial[threadIdx.x] = s[threadIdx.x] - v;
}

__global__ __launch_bounds__(256) void scan_add_kernel(
    int* __restrict__ rowstart, const int* __restrict__ partial, int* __restrict__ cursor,
    int n, int E)
{
    int i = blockIdx.x * 256 + threadIdx.x;
    if (i < n) {
        int v = rowstart[i] + partial[blockIdx.x];
        rowstart[i] = v;
        cursor[i] = v;
    }
    if (i == 0) rowstart[n] = E;
}

__global__ __launch_bounds__(256) void fill_kernel(
    const int* __restrict__ ei, int* __restrict__ cursor, int2* __restrict__ csr, int E)
{
    int e = blockIdx.x * 256 + threadIdx.x;
    if (e >= E) return;
    int dst = ei[E + e];
    int pos = atomicAdd(&cursor[dst], 1);
    csr[pos] = make_int2(ei[e], e);
}

// ========== fused GAT aggregation: 1 wave/node, 4 ch/lane, 4x unrolled ==========
__global__ __launch_bounds__(256) void gat_agg_kernel(
    const int* __restrict__ rowstart, const int2* __restrict__ csr,
    const float* __restrict__ p, const float* __restrict__ h, const float* __restrict__ bias,
    _Float16* __restrict__ Oh, _Float16* __restrict__ Ol, int H, int clog2)
{
    int node = blockIdx.x * 4 + (threadIdx.x >> 6);
    if (node >= N_NODES) return;
    int lane = threadIdx.x & 63;
    int c0 = lane * 4;
    int head = c0 >> clog2;
    int beg = rowstart[node], end = rowstart[node + 1];
    float ax0 = 0.f, ay0 = 0.f, az0 = 0.f, aw0 = 0.f, den0 = 0.f;
    float ax1 = 0.f, ay1 = 0.f, az1 = 0.f, aw1 = 0.f, den1 = 0.f;
    int i = beg;
    for (; i + 3 < end; i += 4) {
        int2 se0 = csr[i], se1 = csr[i + 1], se2 = csr[i + 2], se3 = csr[i + 3];
        float pv0 = p[(long)se0.y * H + head];
        float pv1 = p[(long)se1.y * H + head];
        float pv2 = p[(long)se2.y * H + head];
        float pv3 = p[(long)se3.y * H + head];
        const float4 h0 = *(const float4*)(h + (long)se0.x * NHC + c0);
        const float4 h1 = *(const float4*)(h + (long)se1.x * NHC + c0);
        const float4 h2 = *(const float4*)(h + (long)se2.x * NHC + c0);
        const float4 h3 = *(const float4*)(h + (long)se3.x * NHC + c0);
        den0 += pv0 + pv2; den1 += pv1 + pv3;
        ax0 += pv0 * h0.x + pv2 * h2.x; ay0 += pv0 * h0.y + pv2 * h2.y;
        az0 += pv0 * h0.z + pv2 * h2.z; aw0 += pv0 * h0.w + pv2 * h2.w;
        ax1 += pv1 * h1.x + pv3 * h3.x; ay1 += pv1 * h1.y + pv3 * h3.y;
        az1 += pv1 * h1.z + pv3 * h3.z; aw1 += pv1 * h1.w + pv3 * h3.w;
    }
    for (; i < end; i++) {
        int2 se = csr[i];
        float pv = p[(long)se.y * H + head];
        const float4 hv = *(const float4*)(h + (long)se.x * NHC + c0);
        den0 += pv;
        ax0 += pv * hv.x; ay0 += pv * hv.y; az0 += pv * hv.z; aw0 += pv * hv.w;
    }
    float w = 1.0f / (den0 + den1 + 1e-16f);
    const float4 bv = *(const float4*)(bias + c0);
    float4 v;
    v.x = (ax0 + ax1) * w + bv.x;  v.y = (ay0 + ay1) * w + bv.y;
    v.z = (az0 + az1) * w + bv.z;  v.w = (aw0 + aw1) * w + bv.w;
    v.x = (v.x > 0.f) ? v.x : expm1f(v.x);
    v.y = (v.y > 0.f) ? v.y : expm1f(v.y);
    v.z = (v.z > 0.f) ? v.z : expm1f(v.z);
    v.w = (v.w > 0.f) ? v.w : expm1f(v.w);
    f16x4 oh, ol;
    oh[0] = (_Float16)v.x; ol[0] = (_Float16)(v.x - (float)oh[0]);
    oh[1] = (_Float16)v.y; ol[1] = (_Float16)(v.y - (float)oh[1]);
    oh[2] = (_Float16)v.z; ol[2] = (_Float16)(v.z - (float)oh[2]);
    oh[3] = (_Float16)v.w; ol[3] = (_Float16)(v.w - (float)oh[3]);
    *(f16x4*)(Oh + (long)node * NHC + c0) = oh;
    *(f16x4*)(Ol + (long)node * NHC + c0) = ol;
}

// ================= pooling (batch sorted) =================
__global__ __launch_bounds__(256) void hist_kernel(
    const int* __restrict__ batch, int* __restrict__ gcnt, int N)
{
    __shared__ int hist[N_GRAPH];
    if (threadIdx.x < N_GRAPH) hist[threadIdx.x] = 0;
    __syncthreads();
    int i = blockIdx.x * 256 + threadIdx.x;
    if (i < N) atomicAdd(&hist[batch[i]], 1);
    __syncthreads();
    if (threadIdx.x < N_GRAPH && hist[threadIdx.x] > 0)
        atomicAdd(&gcnt[threadIdx.x], hist[threadIdx.x]);
}

__global__ void gstart_kernel(const int* __restrict__ gcnt, int* __restrict__ gstart)
{
    __shared__ int s[N_GRAPH];
    int t = threadIdx.x;
    int v = gcnt[t];
    s[t] = v;
    __syncthreads();
    for (int off = 1; off < N_GRAPH; off <<= 1) {
        int x = (t >= off) ? s[t - off] : 0;
        __syncthreads();
        s[t] += x;
        __syncthreads();
    }
    gstart[t] = s[t] - v;
    if (t == N_GRAPH - 1) gstart[N_GRAPH] = s[t];
}

__global__ __launch_bounds__(256) void pool_reduce_kernel(
    const float* __restrict__ f2, const int* __restrict__ gstart, float* __restrict__ out)
{
    __shared__ float red[8][32];
    int g = blockIdx.x;
    int c = threadIdx.x & 31, rsub = threadIdx.x >> 5;
    int beg = gstart[g], end = gstart[g + 1];
    float acc = 0.f;
    for (int row = beg + rsub; row < end; row += 8)
        acc += f2[(long)row * 32 + c];
    red[rsub][c] = acc;
    __syncthreads();
    if (rsub == 0) {
        float s = red[0][c] + red[1][c] + red[2][c] + red[3][c]
                + red[4][c] + red[5][c] + red[6][c] + red[7][c];
        out[g * 32 + c] = s / fmaxf((float)(end - beg), 1.0f);
    }
}

extern "C" void kernel_launch(void* const* d_in, const int* in_sizes, int n_in,
                              void* d_out, int out_size, void* d_ws, size_t ws_size,
                              hipStream_t stream)
{
    const float* x    = (const float*)d_in[0];
    const int*   ei   = (const int*)  d_in[1];
    const float* ea   = (const float*)d_in[2];
    const int*   bat  = (const int*)  d_in[3];
    const float* W[3]   = {(const float*)d_in[4],  (const float*)d_in[10], (const float*)d_in[16]};
    const float* Asl[3] = {(const float*)d_in[5],  (const float*)d_in[11], (const float*)d_in[17]};
    const float* Adl[3] = {(const float*)d_in[6],  (const float*)d_in[12], (const float*)d_in[18]};
    const float* Wel[3] = {(const float*)d_in[7],  (const float*)d_in[13], (const float*)d_in[19]};
    const float* Ael[3] = {(const float*)d_in[8],  (const float*)d_in[14], (const float*)d_in[20]};
    const float* Bil[3] = {(const float*)d_in[9],  (const float*)d_in[15], (const float*)d_in[21]};
    const float* fcW1 = (const float*)d_in[22];
    const float* fcb1 = (const float*)d_in[23];
    const float* fcW2 = (const float*)d_in[24];
    const float* fcb2 = (const float*)d_in[25];

    // ---- workspace carve (bytes); A-plane buffers padded to NPAD rows ----
    char* w = (char*)d_ws;
    float*    h    = (float*)w;        w += (size_t)NPAD * NHC * 4;      // also f1 planes (2x NPAD*256 f16)
    _Float16* xh   = (_Float16*)w;     w += (size_t)NPAD * DIN * 2;
    _Float16* xl   = (_Float16*)w;     w += (size_t)NPAD * DIN * 2;
    _Float16* xbh  = (_Float16*)w;     w += (size_t)NPAD * NHC * 2;
    _Float16* xbl  = (_Float16*)w;     w += (size_t)NPAD * NHC * 2;
    float*    f2   = (float*)w;        w += (size_t)N_NODES * DOUT * 4;
    float*    asb  = (float*)w;        w += (size_t)N_NODES * 8 * 4;
    float*    adb  = (float*)w;        w += (size_t)N_NODES * 8 * 4;
    float*    pbuf = (float*)w;        w += (size_t)N_EDGES * 8 * 4;
    float*    Me   = (float*)w;        w += 64 * 4;
    _Float16* W1th = (_Float16*)w;     w += (size_t)NHC * DIN * 2;
    _Float16* W1tl = (_Float16*)w;     w += (size_t)NHC * DIN * 2;
    _Float16* W2th = (_Float16*)w;     w += (size_t)NHC * NHC * 2;
    _Float16* W2tl = (_Float16*)w;     w += (size_t)NHC * NHC * 2;
    _Float16* W3th = (_Float16*)w;     w += (size_t)NHC * NHC * 2;
    _Float16* W3tl = (_Float16*)w;     w += (size_t)NHC * NHC * 2;
    _Float16* F1th = (_Float16*)w;     w += (size_t)NHC * NHC * 2;
    _Float16* F1tl = (_Float16*)w;     w += (size_t)NHC * NHC * 2;
    _Float16* F2th = (_Float16*)w;     w += (size_t)128 * NHC * 2;
    _Float16* F2tl = (_Float16*)w;     w += (size_t)128 * NHC * 2;
    int* gcnt     = (int*)w;           w += N_GRAPH * 4;
    int* gstart   = (int*)w;           w += (N_GRAPH + 1) * 4;
    int* deg      = (int*)w;           w += (size_t)N_NODES * 4;
    int* rowstart = (int*)w;           w += (size_t)(N_NODES + 1) * 4;
    int* cursor   = (int*)w;           w += (size_t)N_NODES * 4;
    int* partial  = (int*)w;           w += 256 * 4;
    w = (char*)(((size_t)w + 15) & ~(size_t)15);
    int2* csr     = (int2*)w;          w += (size_t)N_EDGES * 8;
    _Float16* f1h = (_Float16*)h;                       // [NPAD][256] planes overlaying h
    _Float16* f1l = f1h + (size_t)NPAD * NHC;

    const int NB = (N_NODES + 255) / 256;
    const int PADROWS = NPAD - N_NODES;                 // 48

    // ---- prep: splits + pad-row zeroing (A-planes must be clean for unguarded loads) ----
    split_kernel<<<(N_NODES * DIN / 4 + 255) / 256, 256, 0, stream>>>(x, xh, xl, N_NODES * DIN / 4);
    hipMemsetAsync(xh  + (size_t)N_NODES * DIN, 0, (size_t)PADROWS * DIN * 2, stream);
    hipMemsetAsync(xl  + (size_t)N_NODES * DIN, 0, (size_t)PADROWS * DIN * 2, stream);
    hipMemsetAsync(xbh + (size_t)N_NODES * NHC, 0, (size_t)PADROWS * NHC * 2, stream);
    hipMemsetAsync(xbl + (size_t)N_NODES * NHC, 0, (size_t)PADROWS * NHC * 2, stream);
    tsplit_kernel<<<(NHC * DIN + 255) / 256, 256, 0, stream>>>(W[0], W1th, W1tl, DIN, NHC, NHC);
    tsplit_kernel<<<(NHC * NHC + 255) / 256, 256, 0, stream>>>(W[1], W2th, W2tl, NHC, NHC, NHC);
    tsplit_kernel<<<(NHC * NHC + 255) / 256, 256, 0, stream>>>(W[2], W3th, W3tl, NHC, NHC, NHC);
    tsplit_kernel<<<(NHC * NHC + 255) / 256, 256, 0, stream>>>(fcW1, F1th, F1tl, NHC, NHC, NHC);
    tsplit_kernel<<<(128 * NHC + 255) / 256, 256, 0, stream>>>(fcW2, F2th, F2tl, NHC, DOUT, 128);

    // ---- CSR build ----
    hipMemsetAsync(deg, 0, (size_t)N_NODES * 4, stream);
    count_kernel<<<(N_EDGES + 255) / 256, 256, 0, stream>>>(ei, deg, N_EDGES);
    scan_block_kernel<<<NB, 256, 0, stream>>>(deg, rowstart, partial, N_NODES);
    scan_partial_kernel<<<1, 256, 0, stream>>>(partial, NB);
    scan_add_kernel<<<NB, 256, 0, stream>>>(rowstart, partial, cursor, N_NODES, N_EDGES);
    fill_kernel<<<(N_EDGES + 255) / 256, 256, 0, stream>>>(ei, cursor, csr, N_EDGES);

    // ---- graph ranges for pooling ----
    hipMemsetAsync(gcnt, 0, N_GRAPH * 4, stream);
    hist_kernel<<<NB, 256, 0, stream>>>(bat, gcnt, N_NODES);
    gstart_kernel<<<1, N_GRAPH, 0, stream>>>(gcnt, gstart);

    const int Hs[3] = {8, 8, 1};
    const int Cs[3] = {32, 32, 256};
    const int CL[3] = {5, 5, 8};
    const int Ks[3] = {DIN, NHC, NHC};

    const dim3 ggrid(2, 784);               // 64-row slabs; Y padded %8 for swizzle

    const _Float16* curh = xh;
    const _Float16* curl = xl;
    const _Float16* Wth[3] = {W1th, W2th, W3th};
    const _Float16* Wtl[3] = {W1tl, W2tl, W3tl};
    for (int l = 0; l < 3; l++) {
        const int H = Hs[l], C = Cs[l];
        const int nh = N_NODES * H;
        mfma_gemm_kernel<<<ggrid, 256, 0, stream>>>(
            curh, curl, Wth[l], Wtl[l], nullptr, h, nullptr, nullptr,
            N_NODES, Ks[l], NHC, 0);
        asd_kernel<<<(nh + 255) / 256, 256, 0, stream>>>(h, Asl[l], Adl[l], asb, adb, nh, H, C);
        me_kernel<<<1, 64, 0, stream>>>(Wel[l], Ael[l], Me, H, C);
        edge_p_kernel<<<(N_EDGES + 255) / 256, 256, 0, stream>>>(ei, ea, asb, adb, Me, pbuf, N_EDGES, H);
        gat_agg_kernel<<<(N_NODES + 3) / 4, 256, 0, stream>>>(
            rowstart, csr, pbuf, h, Bil[l], xbh, xbl, H, CL[l]);
        curh = xbh; curl = xbl;
    }

    // f1 pad rows: zero AFTER layer-3 consumers of h (f1 overlays h), before fc1/fc2
    hipMemsetAsync(f1h + (size_t)N_NODES * NHC, 0, (size_t)PADROWS * NHC * 2, stream);
    hipMemsetAsync(f1l + (size_t)N_NODES * NHC, 0, (size_t)PADROWS * NHC * 2, stream);

    // fc1: gelu(xb @ fcW1 + b) -> f1 planes
    mfma_gemm_kernel<<<ggrid, 256, 0, stream>>>(
        xbh, xbl, F1th, F1tl, fcb1, nullptr, f1h, f1l, N_NODES, NHC, NHC, 1);
    // fc2: f1 @ fcW2 + b -> f2 fp32 (block covers cols 0..127; stores masked to 32)
    const dim3 g2(1, 782);
    mfma_gemm_kernel<<<g2, 256, 0, stream>>>(
        f1h, f1l, F2th, F2tl, fcb2, f2, nullptr, nullptr, N_NODES, NHC, DOUT, 2);

    // pooling
    pool_reduce_kernel<<<N_GRAPH, 256, 0, stream>>>(f2, gstart, (float*)d_out);
}

// Round 8
// 741.328 us; speedup vs baseline: 1.2737x; 1.2737x over previous
//
#include <hip/hip_runtime.h>
#include <math.h>

// GATNet_MLP R8: GEMM reverted to R6 (LDS 128x64 + reg-prefetch; the ~73us
// plateau is robust — R5/R6/R7 tried 128x128, prefetch, no-LDS: 71/73/109us).
// NEW: asd fused into GEMM epilogue (a_s/a_d from resident acc regs via 16-lane
// shuffle butterfly + low-contention global atomics) — deletes 3 x 51MB re-reads.
// gat_agg keeps R7's 4x unroll.

#define N_NODES 50000
#define N_EDGES 400000
#define N_GRAPH 64
#define DIN     128
#define NHC     256
#define DOUT    32

typedef _Float16 f16x8 __attribute__((ext_vector_type(8)));
typedef _Float16 f16x4 __attribute__((ext_vector_type(4)));
typedef float    f32x4 __attribute__((ext_vector_type(4)));

#define LDP 40   // padded LDS row stride in halfs (80B)

// ================= fp16x2-split MFMA GEMM, 128x64 tile, pipelined =================
// mode 0: C fp32 [nrow][256]; if asb!=null also fused a_s/a_d reduction
//   (asl/adl flat [256] per-col vectors; head = col>>clog2; asb/adb [nrow][H], pre-zeroed).
// mode 1: bias+gelu -> fp16 planes. mode 2: bias -> fp32 C [nrow][ncols] masked.
__global__ __launch_bounds__(256) void mfma_gemm_kernel(
    const _Float16* __restrict__ Ah, const _Float16* __restrict__ Al,
    const _Float16* __restrict__ Bh, const _Float16* __restrict__ Bl,
    const float* __restrict__ bias, float* __restrict__ C,
    _Float16* __restrict__ Oh, _Float16* __restrict__ Ol,
    const float* __restrict__ asl, const float* __restrict__ adl,
    float* __restrict__ asb, float* __restrict__ adb,
    int nrow, int K, int ncols, int mode, int H, int clog2)
{
    __shared__ __align__(16) _Float16 sAh[128][LDP];
    __shared__ __align__(16) _Float16 sAl[128][LDP];
    __shared__ __align__(16) _Float16 sBh[64][LDP];
    __shared__ __align__(16) _Float16 sBl[64][LDP];

    const int tid = threadIdx.x, lane = tid & 63, wid = tid >> 6;
    const int wm = wid & 1, wn = wid >> 1;

    // XCD swizzle (gridX==4): 4 col-tiles of a row-block share one XCD's L2.
    int xt, yt;
    if (gridDim.x == 4) {
        int bid = blockIdx.x + (blockIdx.y << 2);
        yt = (bid >> 5) * 8 + (bid & 7);
        xt = (bid >> 3) & 3;
    } else { xt = blockIdx.x; yt = blockIdx.y; }
    const int row0 = yt * 128, col0 = xt * 64;
    if (row0 >= nrow) return;

    const int frow = lane & 15, fk = (lane >> 4) * 8;
    const int ra = tid >> 2, kq = (tid & 3) * 8;

    f32x4 acc[4][2] = {};
    f16x8 pAh[2], pAl[2], pBh, pBl;

    // prefetch tile 0
    {
#pragma unroll
        for (int p = 0; p < 2; p++) {
            int gr = row0 + p * 64 + ra;
            long go = (long)gr * K + kq;
            pAh[p] = (gr < nrow) ? *(const f16x8*)(Ah + go) : (f16x8)0;
            pAl[p] = (gr < nrow) ? *(const f16x8*)(Al + go) : (f16x8)0;
        }
        long gob = (long)(col0 + ra) * K + kq;
        pBh = *(const f16x8*)(Bh + gob);
        pBl = *(const f16x8*)(Bl + gob);
    }

    for (int k0 = 0; k0 < K; k0 += 32) {
#pragma unroll
        for (int p = 0; p < 2; p++) {
            *(f16x8*)&sAh[p * 64 + ra][kq] = pAh[p];
            *(f16x8*)&sAl[p * 64 + ra][kq] = pAl[p];
        }
        *(f16x8*)&sBh[ra][kq] = pBh;
        *(f16x8*)&sBl[ra][kq] = pBl;
        __syncthreads();

        if (k0 + 32 < K) {
            int kn = k0 + 32 + kq;
#pragma unroll
            for (int p = 0; p < 2; p++) {
                int gr = row0 + p * 64 + ra;
                long go = (long)gr * K + kn;
                pAh[p] = (gr < nrow) ? *(const f16x8*)(Ah + go) : (f16x8)0;
                pAl[p] = (gr < nrow) ? *(const f16x8*)(Al + go) : (f16x8)0;
            }
            long gob = (long)(col0 + ra) * K + kn;
            pBh = *(const f16x8*)(Bh + gob);
            pBl = *(const f16x8*)(Bl + gob);
        }

        f16x8 bh[2], bl[2];
#pragma unroll
        for (int nt = 0; nt < 2; nt++) {
            bh[nt] = *(const f16x8*)&sBh[wn * 32 + nt * 16 + frow][fk];
            bl[nt] = *(const f16x8*)&sBl[wn * 32 + nt * 16 + frow][fk];
        }
#pragma unroll
        for (int mt = 0; mt < 4; mt++) {
            f16x8 ah = *(const f16x8*)&sAh[wm * 64 + mt * 16 + frow][fk];
            f16x8 al = *(const f16x8*)&sAl[wm * 64 + mt * 16 + frow][fk];
#pragma unroll
            for (int nt = 0; nt < 2; nt++) {
                acc[mt][nt] = __builtin_amdgcn_mfma_f32_16x16x32_f16(ah, bh[nt], acc[mt][nt], 0, 0, 0);
                acc[mt][nt] = __builtin_amdgcn_mfma_f32_16x16x32_f16(ah, bl[nt], acc[mt][nt], 0, 0, 0);
                acc[mt][nt] = __builtin_amdgcn_mfma_f32_16x16x32_f16(al, bh[nt], acc[mt][nt], 0, 0, 0);
            }
        }
        __syncthreads();
    }

    // epilogue: C/D layout col=lane&15, row=(lane>>4)*4+reg
    const int crow0 = row0 + wm * 64 + (lane >> 4) * 4;
    const int ccol0 = col0 + wn * 32 + (lane & 15);
#pragma unroll
    for (int mt = 0; mt < 4; mt++) {
#pragma unroll
        for (int nt = 0; nt < 2; nt++) {
            int col = ccol0 + nt * 16;
#pragma unroll
            for (int r = 0; r < 4; r++) {
                int row = crow0 + mt * 16 + r;
                if (row >= nrow) continue;
                float v = acc[mt][nt][r];
                if (mode == 0) {
                    C[(long)row * 256 + col] = v;
                } else if (mode == 1) {
                    v += bias[col];
                    v = 0.5f * v * (1.f + erff(v * 0.7071067811865475f));
                    _Float16 hh = (_Float16)v;
                    Oh[(long)row * 256 + col] = hh;
                    Ol[(long)row * 256 + col] = (_Float16)(v - (float)hh);
                } else {
                    if (col < ncols) {
                        v += bias[col];
                        C[(long)row * ncols + col] = v;
                    }
                }
            }
        }
    }

    // ---- fused a_s / a_d (mode 0): wave's 32-col slab lies in one head (C=32);
    // C=256 -> head 0, partials combine via global atomics across blocks/waves.
    if (mode == 0 && asb != nullptr) {
        const float asl0 = asl[ccol0], asl1 = asl[ccol0 + 16];
        const float adl0 = adl[ccol0], adl1 = adl[ccol0 + 16];
        const int headw = (col0 + wn * 32) >> clog2;
#pragma unroll
        for (int mt = 0; mt < 4; mt++) {
#pragma unroll
            for (int r = 0; r < 4; r++) {
                float s = acc[mt][0][r] * asl0 + acc[mt][1][r] * asl1;
                float d = acc[mt][0][r] * adl0 + acc[mt][1][r] * adl1;
                s += __shfl_xor(s, 1); s += __shfl_xor(s, 2);
                s += __shfl_xor(s, 4); s += __shfl_xor(s, 8);
                d += __shfl_xor(d, 1); d += __shfl_xor(d, 2);
                d += __shfl_xor(d, 4); d += __shfl_xor(d, 8);
                if ((lane & 15) == 0) {
                    int row = crow0 + mt * 16 + r;
                    if (row < nrow) {
                        atomicAdd(&asb[row * H + headw], s);
                        atomicAdd(&adb[row * H + headw], d);
                    }
                }
            }
        }
    }
}

// -------- split fp32 -> fp16 hi/lo planes --------
__global__ __launch_bounds__(256) void split_kernel(
    const float* __restrict__ in, _Float16* __restrict__ oh, _Float16* __restrict__ ol, int n4)
{
    int i = blockIdx.x * 256 + threadIdx.x;
    if (i >= n4) return;
    float4 v = ((const float4*)in)[i];
    f16x4 h, l;
    h[0] = (_Float16)v.x; l[0] = (_Float16)(v.x - (float)h[0]);
    h[1] = (_Float16)v.y; l[1] = (_Float16)(v.y - (float)h[1]);
    h[2] = (_Float16)v.z; l[2] = (_Float16)(v.z - (float)h[2]);
    h[3] = (_Float16)v.w; l[3] = (_Float16)(v.w - (float)h[3]);
    *(f16x4*)(oh + (long)i * 4) = h;
    *(f16x4*)(ol + (long)i * 4) = l;
}

// -------- transpose + split weights: W[K][N] fp32 -> planes [Npad][K] --------
__global__ __launch_bounds__(256) void tsplit_kernel(
    const float* __restrict__ W, _Float16* __restrict__ Bh, _Float16* __restrict__ Bl,
    int K, int N, int Npad)
{
    int id = blockIdx.x * 256 + threadIdx.x;
    if (id >= Npad * K) return;
    int n = id / K, k = id - n * K;
    float v = (n < N) ? W[(long)k * N + n] : 0.f;
    _Float16 h = (_Float16)v;
    Bh[id] = h;
    Bl[id] = (_Float16)(v - (float)h);
}

// -------- Me[j,h] = sum_c We[j, h*C+c] * ae[h*C+c] --------
__global__ void me_kernel(const float* __restrict__ We, const float* __restrict__ ae,
                          float* __restrict__ Me, int H, int C)
{
    int i = threadIdx.x;
    if (i >= 5 * H) return;
    int j = i / H, hh = i - j * H;
    float s = 0.f;
    for (int c = 0; c < C; c++) s += We[j * NHC + hh * C + c] * ae[hh * C + c];
    Me[i] = s;
}

// -------- edge-parallel p --------
__global__ __launch_bounds__(256) void edge_p_kernel(
    const int* __restrict__ ei, const float* __restrict__ ea,
    const float* __restrict__ asb, const float* __restrict__ adb,
    const float* __restrict__ Me, float* __restrict__ p, int E, int H)
{
    int e = blockIdx.x * 256 + threadIdx.x;
    if (e >= E) return;
    int src = ei[e], dst = ei[E + e];
    float a0 = ea[e * 5 + 0], a1 = ea[e * 5 + 1], a2 = ea[e * 5 + 2],
          a3 = ea[e * 5 + 3], a4 = ea[e * 5 + 4];
    for (int h = 0; h < H; h++) {
        float aeh = a0 * Me[0 * H + h] + a1 * Me[1 * H + h] + a2 * Me[2 * H + h]
                  + a3 * Me[3 * H + h] + a4 * Me[4 * H + h];
        float al = asb[src * H + h] + adb[dst * H + h] + aeh;
        al = fmaxf(al, 0.2f * al);
        p[(long)e * H + h] = expf(al);
    }
}

// ================= CSR build (entries packed int2{src,eid}) =================
__global__ __launch_bounds__(256) void count_kernel(
    const int* __restrict__ ei, int* __restrict__ deg, int E)
{
    int e = blockIdx.x * 256 + threadIdx.x;
    if (e < E) atomicAdd(&deg[ei[E + e]], 1);
}

__global__ __launch_bounds__(256) void scan_block_kernel(
    const int* __restrict__ deg, int* __restrict__ rowstart, int* __restrict__ partial, int n)
{
    __shared__ int s[256];
    int i = blockIdx.x * 256 + threadIdx.x;
    int v = (i < n) ? deg[i] : 0;
    s[threadIdx.x] = v;
    __syncthreads();
    for (int off = 1; off < 256; off <<= 1) {
        int t = (threadIdx.x >= off) ? s[threadIdx.x - off] : 0;
        __syncthreads();
        s[threadIdx.x] += t;
        __syncthreads();
    }
    if (i < n) rowstart[i] = s[threadIdx.x] - v;
    if (threadIdx.x == 255) partial[blockIdx.x] = s[255];
}

__global__ __launch_bounds__(256) void scan_partial_kernel(int* __restrict__ partial, int nb)
{
    __shared__ int s[256];
    int v = (threadIdx.x < nb) ? partial[threadIdx.x] : 0;
    s[threadIdx.x] = v;
    __syncthreads();
    for (int off = 1; off < 256; off <<= 1) {
        int t = (threadIdx.x >= off) ? s[threadIdx.x - off] : 0;
        __syncthreads();
        s[threadIdx.x] += t;
        __syncthreads();
    }
    if (threadIdx.x < nb) partial[threadIdx.x] = s[threadIdx.x] - v;
}

__global__ __launch_bounds__(256) void scan_add_kernel(
    int* __restrict__ rowstart, const int* __restrict__ partial, int* __restrict__ cursor,
    int n, int E)
{
    int i = blockIdx.x * 256 + threadIdx.x;
    if (i < n) {
        int v = rowstart[i] + partial[blockIdx.x];
        rowstart[i] = v;
        cursor[i] = v;
    }
    if (i == 0) rowstart[n] = E;
}

__global__ __launch_bounds__(256) void fill_kernel(
    const int* __restrict__ ei, int* __restrict__ cursor, int2* __restrict__ csr, int E)
{
    int e = blockIdx.x * 256 + threadIdx.x;
    if (e >= E) return;
    int dst = ei[E + e];
    int pos = atomicAdd(&cursor[dst], 1);
    csr[pos] = make_int2(ei[e], e);
}

// ========== fused GAT aggregation: 1 wave/node, 4 ch/lane, 4x unrolled ==========
__global__ __launch_bounds__(256) void gat_agg_kernel(
    const int* __restrict__ rowstart, const int2* __restrict__ csr,
    const float* __restrict__ p, const float* __restrict__ h, const float* __restrict__ bias,
    _Float16* __restrict__ Oh, _Float16* __restrict__ Ol, int H, int clog2)
{
    int node = blockIdx.x * 4 + (threadIdx.x >> 6);
    if (node >= N_NODES) return;
    int lane = threadIdx.x & 63;
    int c0 = lane * 4;
    int head = c0 >> clog2;
    int beg = rowstart[node], end = rowstart[node + 1];
    float ax0 = 0.f, ay0 = 0.f, az0 = 0.f, aw0 = 0.f, den0 = 0.f;
    float ax1 = 0.f, ay1 = 0.f, az1 = 0.f, aw1 = 0.f, den1 = 0.f;
    int i = beg;
    for (; i + 3 < end; i += 4) {
        int2 se0 = csr[i], se1 = csr[i + 1], se2 = csr[i + 2], se3 = csr[i + 3];
        float pv0 = p[(long)se0.y * H + head];
        float pv1 = p[(long)se1.y * H + head];
        float pv2 = p[(long)se2.y * H + head];
        float pv3 = p[(long)se3.y * H + head];
        const float4 h0 = *(const float4*)(h + (long)se0.x * NHC + c0);
        const float4 h1 = *(const float4*)(h + (long)se1.x * NHC + c0);
        const float4 h2 = *(const float4*)(h + (long)se2.x * NHC + c0);
        const float4 h3 = *(const float4*)(h + (long)se3.x * NHC + c0);
        den0 += pv0 + pv2; den1 += pv1 + pv3;
        ax0 += pv0 * h0.x + pv2 * h2.x; ay0 += pv0 * h0.y + pv2 * h2.y;
        az0 += pv0 * h0.z + pv2 * h2.z; aw0 += pv0 * h0.w + pv2 * h2.w;
        ax1 += pv1 * h1.x + pv3 * h3.x; ay1 += pv1 * h1.y + pv3 * h3.y;
        az1 += pv1 * h1.z + pv3 * h3.z; aw1 += pv1 * h1.w + pv3 * h3.w;
    }
    for (; i < end; i++) {
        int2 se = csr[i];
        float pv = p[(long)se.y * H + head];
        const float4 hv = *(const float4*)(h + (long)se.x * NHC + c0);
        den0 += pv;
        ax0 += pv * hv.x; ay0 += pv * hv.y; az0 += pv * hv.z; aw0 += pv * hv.w;
    }
    float w = 1.0f / (den0 + den1 + 1e-16f);
    const float4 bv = *(const float4*)(bias + c0);
    float4 v;
    v.x = (ax0 + ax1) * w + bv.x;  v.y = (ay0 + ay1) * w + bv.y;
    v.z = (az0 + az1) * w + bv.z;  v.w = (aw0 + aw1) * w + bv.w;
    v.x = (v.x > 0.f) ? v.x : expm1f(v.x);
    v.y = (v.y > 0.f) ? v.y : expm1f(v.y);
    v.z = (v.z > 0.f) ? v.z : expm1f(v.z);
    v.w = (v.w > 0.f) ? v.w : expm1f(v.w);
    f16x4 oh, ol;
    oh[0] = (_Float16)v.x; ol[0] = (_Float16)(v.x - (float)oh[0]);
    oh[1] = (_Float16)v.y; ol[1] = (_Float16)(v.y - (float)oh[1]);
    oh[2] = (_Float16)v.z; ol[2] = (_Float16)(v.z - (float)oh[2]);
    oh[3] = (_Float16)v.w; ol[3] = (_Float16)(v.w - (float)oh[3]);
    *(f16x4*)(Oh + (long)node * NHC + c0) = oh;
    *(f16x4*)(Ol + (long)node * NHC + c0) = ol;
}

// ================= pooling (batch sorted) =================
__global__ __launch_bounds__(256) void hist_kernel(
    const int* __restrict__ batch, int* __restrict__ gcnt, int N)
{
    __shared__ int hist[N_GRAPH];
    if (threadIdx.x < N_GRAPH) hist[threadIdx.x] = 0;
    __syncthreads();
    int i = blockIdx.x * 256 + threadIdx.x;
    if (i < N) atomicAdd(&hist[batch[i]], 1);
    __syncthreads();
    if (threadIdx.x < N_GRAPH && hist[threadIdx.x] > 0)
        atomicAdd(&gcnt[threadIdx.x], hist[threadIdx.x]);
}

__global__ void gstart_kernel(const int* __restrict__ gcnt, int* __restrict__ gstart)
{
    __shared__ int s[N_GRAPH];
    int t = threadIdx.x;
    int v = gcnt[t];
    s[t] = v;
    __syncthreads();
    for (int off = 1; off < N_GRAPH; off <<= 1) {
        int x = (t >= off) ? s[t - off] : 0;
        __syncthreads();
        s[t] += x;
        __syncthreads();
    }
    gstart[t] = s[t] - v;
    if (t == N_GRAPH - 1) gstart[N_GRAPH] = s[t];
}

__global__ __launch_bounds__(256) void pool_reduce_kernel(
    const float* __restrict__ f2, const int* __restrict__ gstart, float* __restrict__ out)
{
    __shared__ float red[8][32];
    int g = blockIdx.x;
    int c = threadIdx.x & 31, rsub = threadIdx.x >> 5;
    int beg = gstart[g], end = gstart[g + 1];
    float acc = 0.f;
    for (int row = beg + rsub; row < end; row += 8)
        acc += f2[(long)row * 32 + c];
    red[rsub][c] = acc;
    __syncthreads();
    if (rsub == 0) {
        float s = red[0][c] + red[1][c] + red[2][c] + red[3][c]
                + red[4][c] + red[5][c] + red[6][c] + red[7][c];
        out[g * 32 + c] = s / fmaxf((float)(end - beg), 1.0f);
    }
}

extern "C" void kernel_launch(void* const* d_in, const int* in_sizes, int n_in,
                              void* d_out, int out_size, void* d_ws, size_t ws_size,
                              hipStream_t stream)
{
    const float* x    = (const float*)d_in[0];
    const int*   ei   = (const int*)  d_in[1];
    const float* ea   = (const float*)d_in[2];
    const int*   bat  = (const int*)  d_in[3];
    const float* W[3]   = {(const float*)d_in[4],  (const float*)d_in[10], (const float*)d_in[16]};
    const float* Asl[3] = {(const float*)d_in[5],  (const float*)d_in[11], (const float*)d_in[17]};
    const float* Adl[3] = {(const float*)d_in[6],  (const float*)d_in[12], (const float*)d_in[18]};
    const float* Wel[3] = {(const float*)d_in[7],  (const float*)d_in[13], (const float*)d_in[19]};
    const float* Ael[3] = {(const float*)d_in[8],  (const float*)d_in[14], (const float*)d_in[20]};
    const float* Bil[3] = {(const float*)d_in[9],  (const float*)d_in[15], (const float*)d_in[21]};
    const float* fcW1 = (const float*)d_in[22];
    const float* fcb1 = (const float*)d_in[23];
    const float* fcW2 = (const float*)d_in[24];
    const float* fcb2 = (const float*)d_in[25];

    // ---- workspace carve (bytes) ----
    char* w = (char*)d_ws;
    float*    h    = (float*)w;        w += (size_t)N_NODES * NHC * 4;   // reused as f1 planes
    _Float16* xh   = (_Float16*)w;     w += (size_t)N_NODES * DIN * 2;
    _Float16* xl   = (_Float16*)w;     w += (size_t)N_NODES * DIN * 2;
    _Float16* xbh  = (_Float16*)w;     w += (size_t)N_NODES * NHC * 2;
    _Float16* xbl  = (_Float16*)w;     w += (size_t)N_NODES * NHC * 2;
    float*    f2   = (float*)w;        w += (size_t)N_NODES * DOUT * 4;
    float*    asb  = (float*)w;        w += (size_t)N_NODES * 8 * 4;
    float*    adb  = (float*)w;        w += (size_t)N_NODES * 8 * 4;
    float*    pbuf = (float*)w;        w += (size_t)N_EDGES * 8 * 4;
    float*    Me   = (float*)w;        w += 64 * 4;
    _Float16* W1th = (_Float16*)w;     w += (size_t)NHC * DIN * 2;
    _Float16* W1tl = (_Float16*)w;     w += (size_t)NHC * DIN * 2;
    _Float16* W2th = (_Float16*)w;     w += (size_t)NHC * NHC * 2;
    _Float16* W2tl = (_Float16*)w;     w += (size_t)NHC * NHC * 2;
    _Float16* W3th = (_Float16*)w;     w += (size_t)NHC * NHC * 2;
    _Float16* W3tl = (_Float16*)w;     w += (size_t)NHC * NHC * 2;
    _Float16* F1th = (_Float16*)w;     w += (size_t)NHC * NHC * 2;
    _Float16* F1tl = (_Float16*)w;     w += (size_t)NHC * NHC * 2;
    _Float16* F2th = (_Float16*)w;     w += (size_t)128 * NHC * 2;
    _Float16* F2tl = (_Float16*)w;     w += (size_t)128 * NHC * 2;
    int* gcnt     = (int*)w;           w += N_GRAPH * 4;
    int* gstart   = (int*)w;           w += (N_GRAPH + 1) * 4;
    int* deg      = (int*)w;           w += (size_t)N_NODES * 4;
    int* rowstart = (int*)w;           w += (size_t)(N_NODES + 1) * 4;
    int* cursor   = (int*)w;           w += (size_t)N_NODES * 4;
    int* partial  = (int*)w;           w += 256 * 4;
    w = (char*)(((size_t)w + 15) & ~(size_t)15);
    int2* csr     = (int2*)w;          w += (size_t)N_EDGES * 8;
    _Float16* f1h = (_Float16*)h;
    _Float16* f1l = f1h + (size_t)N_NODES * NHC;

    const int NB = (N_NODES + 255) / 256;

    // ---- prep: splits ----
    split_kernel<<<(N_NODES * DIN / 4 + 255) / 256, 256, 0, stream>>>(x, xh, xl, N_NODES * DIN / 4);
    tsplit_kernel<<<(NHC * DIN + 255) / 256, 256, 0, stream>>>(W[0], W1th, W1tl, DIN, NHC, NHC);
    tsplit_kernel<<<(NHC * NHC + 255) / 256, 256, 0, stream>>>(W[1], W2th, W2tl, NHC, NHC, NHC);
    tsplit_kernel<<<(NHC * NHC + 255) / 256, 256, 0, stream>>>(W[2], W3th, W3tl, NHC, NHC, NHC);
    tsplit_kernel<<<(NHC * NHC + 255) / 256, 256, 0, stream>>>(fcW1, F1th, F1tl, NHC, NHC, NHC);
    tsplit_kernel<<<(128 * NHC + 255) / 256, 256, 0, stream>>>(fcW2, F2th, F2tl, NHC, DOUT, 128);

    // ---- CSR build ----
    hipMemsetAsync(deg, 0, (size_t)N_NODES * 4, stream);
    count_kernel<<<(N_EDGES + 255) / 256, 256, 0, stream>>>(ei, deg, N_EDGES);
    scan_block_kernel<<<NB, 256, 0, stream>>>(deg, rowstart, partial, N_NODES);
    scan_partial_kernel<<<1, 256, 0, stream>>>(partial, NB);
    scan_add_kernel<<<NB, 256, 0, stream>>>(rowstart, partial, cursor, N_NODES, N_EDGES);
    fill_kernel<<<(N_EDGES + 255) / 256, 256, 0, stream>>>(ei, cursor, csr, N_EDGES);

    // ---- graph ranges for pooling ----
    hipMemsetAsync(gcnt, 0, N_GRAPH * 4, stream);
    hist_kernel<<<NB, 256, 0, stream>>>(bat, gcnt, N_NODES);
    gstart_kernel<<<1, N_GRAPH, 0, stream>>>(gcnt, gstart);

    const int Hs[3] = {8, 8, 1};
    const int CL[3] = {5, 5, 8};
    const int Ks[3] = {DIN, NHC, NHC};

    const dim3 ggrid(4, 392);               // 1568 blocks; Y padded %8 for swizzle

    const _Float16* curh = xh;
    const _Float16* curl = xl;
    const _Float16* Wth[3] = {W1th, W2th, W3th};
    const _Float16* Wtl[3] = {W1tl, W2tl, W3tl};
    for (int l = 0; l < 3; l++) {
        const int H = Hs[l];
        // zero asd accumulators (fused GEMM epilogue atomically adds partials)
        hipMemsetAsync(asb, 0, (size_t)N_NODES * 8 * 4, stream);
        hipMemsetAsync(adb, 0, (size_t)N_NODES * 8 * 4, stream);
        mfma_gemm_kernel<<<ggrid, 256, 0, stream>>>(
            curh, curl, Wth[l], Wtl[l], nullptr, h, nullptr, nullptr,
            Asl[l], Adl[l], asb, adb,
            N_NODES, Ks[l], NHC, 0, H, CL[l]);
        me_kernel<<<1, 64, 0, stream>>>(Wel[l], Ael[l], Me, H, (l == 2) ? NHC : 32);
        edge_p_kernel<<<(N_EDGES + 255) / 256, 256, 0, stream>>>(ei, ea, asb, adb, Me, pbuf, N_EDGES, H);
        gat_agg_kernel<<<(N_NODES + 3) / 4, 256, 0, stream>>>(
            rowstart, csr, pbuf, h, Bil[l], xbh, xbl, H, CL[l]);
        curh = xbh; curl = xbl;
    }

    // fc1: gelu(xb @ fcW1 + b) -> f1 planes (overlays dead h)
    mfma_gemm_kernel<<<ggrid, 256, 0, stream>>>(
        xbh, xbl, F1th, F1tl, fcb1, nullptr, f1h, f1l,
        nullptr, nullptr, nullptr, nullptr,
        N_NODES, NHC, NHC, 1, 0, 0);
    // fc2: f1 @ fcW2 + b -> f2 fp32 (tile covers cols 0..63, masked to 32)
    const dim3 g2(1, (N_NODES + 127) / 128);
    mfma_gemm_kernel<<<g2, 256, 0, stream>>>(
        f1h, f1l, F2th, F2tl, fcb2, f2, nullptr, nullptr,
        nullptr, nullptr, nullptr, nullptr,
        N_NODES, NHC, DOUT, 2, 0, 0);

    // pooling
    pool_reduce_kernel<<<N_GRAPH, 256, 0, stream>>>(f2, gstart, (float*)d_out);
}

// Round 9
// 666.245 us; speedup vs baseline: 1.4172x; 1.1127x over previous
//
#include <hip/hip_runtime.h>
#include <math.h>

// GATNet_MLP R9: R6 GEMM/asd (the verified 714us structure) +
//  (a) edge_p fused into gat_agg with NO redundancy: per 8-edge chunk, lane l
//      computes alpha/exp for (edge l>>3, head l&7) -> 64 pairs = 1/lane; channel
//      lanes shuffle their head's p. Deletes 3 launches + 25.6MB/layer p traffic.
//  (b) launch-count 33 -> 19: single prep kernel (split+5 tsplits+zeroing),
//      count+hist merged, scan_partial+gstart merged, all 3 Me in one launch.

#define N_NODES 50000
#define N_EDGES 400000
#define N_GRAPH 64
#define DIN     128
#define NHC     256
#define DOUT    32

typedef _Float16 f16x8 __attribute__((ext_vector_type(8)));
typedef _Float16 f16x4 __attribute__((ext_vector_type(4)));
typedef float    f32x4 __attribute__((ext_vector_type(4)));

#define LDP 40   // padded LDS row stride in halfs (80B; kills b128 conflicts)

// ================= fp16x2-split MFMA GEMM, 128x64 tile, pipelined (R6 exact) =====
__global__ __launch_bounds__(256) void mfma_gemm_kernel(
    const _Float16* __restrict__ Ah, const _Float16* __restrict__ Al,
    const _Float16* __restrict__ Bh, const _Float16* __restrict__ Bl,
    const float* __restrict__ bias, float* __restrict__ C,
    _Float16* __restrict__ Oh, _Float16* __restrict__ Ol,
    int nrow, int K, int ncols, int mode)
{
    __shared__ __align__(16) _Float16 sAh[128][LDP];
    __shared__ __align__(16) _Float16 sAl[128][LDP];
    __shared__ __align__(16) _Float16 sBh[64][LDP];
    __shared__ __align__(16) _Float16 sBl[64][LDP];

    const int tid = threadIdx.x, lane = tid & 63, wid = tid >> 6;
    const int wm = wid & 1, wn = wid >> 1;

    int xt, yt;
    if (gridDim.x == 4) {
        int bid = blockIdx.x + (blockIdx.y << 2);
        yt = (bid >> 5) * 8 + (bid & 7);
        xt = (bid >> 3) & 3;
    } else { xt = blockIdx.x; yt = blockIdx.y; }
    const int row0 = yt * 128, col0 = xt * 64;
    if (row0 >= nrow) return;

    const int frow = lane & 15, fk = (lane >> 4) * 8;
    const int ra = tid >> 2, kq = (tid & 3) * 8;

    f32x4 acc[4][2] = {};
    f16x8 pAh[2], pAl[2], pBh, pBl;

    {
#pragma unroll
        for (int p = 0; p < 2; p++) {
            int gr = row0 + p * 64 + ra;
            long go = (long)gr * K + kq;
            pAh[p] = (gr < nrow) ? *(const f16x8*)(Ah + go) : (f16x8)0;
            pAl[p] = (gr < nrow) ? *(const f16x8*)(Al + go) : (f16x8)0;
        }
        long gob = (long)(col0 + ra) * K + kq;
        pBh = *(const f16x8*)(Bh + gob);
        pBl = *(const f16x8*)(Bl + gob);
    }

    for (int k0 = 0; k0 < K; k0 += 32) {
#pragma unroll
        for (int p = 0; p < 2; p++) {
            *(f16x8*)&sAh[p * 64 + ra][kq] = pAh[p];
            *(f16x8*)&sAl[p * 64 + ra][kq] = pAl[p];
        }
        *(f16x8*)&sBh[ra][kq] = pBh;
        *(f16x8*)&sBl[ra][kq] = pBl;
        __syncthreads();

        if (k0 + 32 < K) {
            int kn = k0 + 32 + kq;
#pragma unroll
            for (int p = 0; p < 2; p++) {
                int gr = row0 + p * 64 + ra;
                long go = (long)gr * K + kn;
                pAh[p] = (gr < nrow) ? *(const f16x8*)(Ah + go) : (f16x8)0;
                pAl[p] = (gr < nrow) ? *(const f16x8*)(Al + go) : (f16x8)0;
            }
            long gob = (long)(col0 + ra) * K + kn;
            pBh = *(const f16x8*)(Bh + gob);
            pBl = *(const f16x8*)(Bl + gob);
        }

        f16x8 bh[2], bl[2];
#pragma unroll
        for (int nt = 0; nt < 2; nt++) {
            bh[nt] = *(const f16x8*)&sBh[wn * 32 + nt * 16 + frow][fk];
            bl[nt] = *(const f16x8*)&sBl[wn * 32 + nt * 16 + frow][fk];
        }
#pragma unroll
        for (int mt = 0; mt < 4; mt++) {
            f16x8 ah = *(const f16x8*)&sAh[wm * 64 + mt * 16 + frow][fk];
            f16x8 al = *(const f16x8*)&sAl[wm * 64 + mt * 16 + frow][fk];
#pragma unroll
            for (int nt = 0; nt < 2; nt++) {
                acc[mt][nt] = __builtin_amdgcn_mfma_f32_16x16x32_f16(ah, bh[nt], acc[mt][nt], 0, 0, 0);
                acc[mt][nt] = __builtin_amdgcn_mfma_f32_16x16x32_f16(ah, bl[nt], acc[mt][nt], 0, 0, 0);
                acc[mt][nt] = __builtin_amdgcn_mfma_f32_16x16x32_f16(al, bh[nt], acc[mt][nt], 0, 0, 0);
            }
        }
        __syncthreads();
    }

    const int crow0 = row0 + wm * 64 + (lane >> 4) * 4;
    const int ccol0 = col0 + wn * 32 + (lane & 15);
#pragma unroll
    for (int mt = 0; mt < 4; mt++) {
#pragma unroll
        for (int nt = 0; nt < 2; nt++) {
            int col = ccol0 + nt * 16;
#pragma unroll
            for (int r = 0; r < 4; r++) {
                int row = crow0 + mt * 16 + r;
                if (row >= nrow) continue;
                float v = acc[mt][nt][r];
                if (mode == 0) {
                    C[(long)row * 256 + col] = v;
                } else if (mode == 1) {
                    v += bias[col];
                    v = 0.5f * v * (1.f + erff(v * 0.7071067811865475f));
                    _Float16 hh = (_Float16)v;
                    Oh[(long)row * 256 + col] = hh;
                    Ol[(long)row * 256 + col] = (_Float16)(v - (float)hh);
                } else {
                    if (col < ncols) {
                        v += bias[col];
                        C[(long)row * ncols + col] = v;
                    }
                }
            }
        }
    }
}

// ================= single prep kernel: x split + 5 weight tsplits + zeroing ======
#define J0 1600000                       // x split (float4 units): N*DIN/4
#define J1 32768                         // W1 tsplit (256x128)
#define J2 65536                         // W2
#define J3 65536                         // W3
#define J4 65536                         // fcW1
#define J5 32768                         // fcW2 (padded 128 cols x 256)
#define J6 N_NODES                       // zero deg
#define J7 64                            // zero gcnt
#define JTOT (J0+J1+J2+J3+J4+J5+J6+J7)   // 1,912,208

__device__ __forceinline__ void tsplit_one(const float* W, _Float16* Bh, _Float16* Bl,
                                           int id, int K, int N, int realN)
{
    int n = id / K, k = id - n * K;
    float v = (n < realN) ? W[(long)k * realN + n] : 0.f;
    _Float16 h = (_Float16)v;
    Bh[id] = h;
    Bl[id] = (_Float16)(v - (float)h);
}

__global__ __launch_bounds__(256) void prep_kernel(
    const float* __restrict__ x,
    const float* __restrict__ W1, const float* __restrict__ W2, const float* __restrict__ W3,
    const float* __restrict__ F1, const float* __restrict__ F2,
    _Float16* __restrict__ xh, _Float16* __restrict__ xl,
    _Float16* __restrict__ W1th, _Float16* __restrict__ W1tl,
    _Float16* __restrict__ W2th, _Float16* __restrict__ W2tl,
    _Float16* __restrict__ W3th, _Float16* __restrict__ W3tl,
    _Float16* __restrict__ F1th, _Float16* __restrict__ F1tl,
    _Float16* __restrict__ F2th, _Float16* __restrict__ F2tl,
    int* __restrict__ deg, int* __restrict__ gcnt)
{
    int idx = blockIdx.x * 256 + threadIdx.x;
    if (idx < J0) {
        float4 v = ((const float4*)x)[idx];
        f16x4 h, l;
        h[0] = (_Float16)v.x; l[0] = (_Float16)(v.x - (float)h[0]);
        h[1] = (_Float16)v.y; l[1] = (_Float16)(v.y - (float)h[1]);
        h[2] = (_Float16)v.z; l[2] = (_Float16)(v.z - (float)h[2]);
        h[3] = (_Float16)v.w; l[3] = (_Float16)(v.w - (float)h[3]);
        *(f16x4*)(xh + (long)idx * 4) = h;
        *(f16x4*)(xl + (long)idx * 4) = l;
        return;
    }
    idx -= J0;
    if (idx < J1) { tsplit_one(W1, W1th, W1tl, idx, DIN, NHC, NHC); return; }
    idx -= J1;
    if (idx < J2) { tsplit_one(W2, W2th, W2tl, idx, NHC, NHC, NHC); return; }
    idx -= J2;
    if (idx < J3) { tsplit_one(W3, W3th, W3tl, idx, NHC, NHC, NHC); return; }
    idx -= J3;
    if (idx < J4) { tsplit_one(F1, F1th, F1tl, idx, NHC, NHC, NHC); return; }
    idx -= J4;
    if (idx < J5) { tsplit_one(F2, F2th, F2tl, idx, NHC, 128, DOUT); return; }
    idx -= J5;
    if (idx < J6) { deg[idx] = 0; return; }
    idx -= J6;
    if (idx < J7) { gcnt[idx] = 0; return; }
}

// -------- all 3 layers' Me[5][H] in one launch (weights-only dependency) --------
__global__ void me_all_kernel(
    const float* __restrict__ We1, const float* __restrict__ ae1,
    const float* __restrict__ We2, const float* __restrict__ ae2,
    const float* __restrict__ We3, const float* __restrict__ ae3,
    float* __restrict__ MeAll)
{
    int l = blockIdx.x;
    const float* We = (l == 0) ? We1 : (l == 1) ? We2 : We3;
    const float* ae = (l == 0) ? ae1 : (l == 1) ? ae2 : ae3;
    int H = (l == 2) ? 1 : 8, C = (l == 2) ? 256 : 32;
    int t = threadIdx.x;
    if (t >= 5 * H) return;
    int j = t / H, hh = t - j * H;
    float s = 0.f;
    for (int c = 0; c < C; c++) s += We[j * NHC + hh * C + c] * ae[hh * C + c];
    MeAll[l * 40 + j * H + hh] = s;
}

// -------- per-node attention scalars (R6 exact) --------
__global__ __launch_bounds__(256) void asd_kernel(
    const float* __restrict__ h, const float* __restrict__ atts, const float* __restrict__ attd,
    float* __restrict__ asb, float* __restrict__ adb, int total, int H, int C)
{
    int i = blockIdx.x * 256 + threadIdx.x;
    if (i >= total) return;
    int n = i / H, hh = i - n * H;
    const float4* hp = (const float4*)(h + (long)n * NHC + hh * C);
    const float4* sp = (const float4*)(atts + hh * C);
    const float4* dp = (const float4*)(attd + hh * C);
    float ss = 0.f, dd = 0.f;
    for (int c = 0; c < C / 4; c++) {
        float4 hv = hp[c], sv = sp[c], dv = dp[c];
        ss += hv.x * sv.x + hv.y * sv.y + hv.z * sv.z + hv.w * sv.w;
        dd += hv.x * dv.x + hv.y * dv.y + hv.z * dv.z + hv.w * dv.w;
    }
    asb[i] = ss; adb[i] = dd;
}

// ================= CSR build =================
__global__ __launch_bounds__(256) void count_hist_kernel(
    const int* __restrict__ ei, const int* __restrict__ batch,
    int* __restrict__ deg, int* __restrict__ gcnt, int E, int N)
{
    __shared__ int hist[N_GRAPH];
    int t = threadIdx.x;
    if (t < N_GRAPH) hist[t] = 0;
    __syncthreads();
    int i = blockIdx.x * 256 + t;
    if (i < E) atomicAdd(&deg[ei[E + i]], 1);
    if (i < N) atomicAdd(&hist[batch[i]], 1);
    __syncthreads();
    if (t < N_GRAPH && hist[t] > 0) atomicAdd(&gcnt[t], hist[t]);
}

__global__ __launch_bounds__(256) void scan_block_kernel(
    const int* __restrict__ deg, int* __restrict__ rowstart, int* __restrict__ partial, int n)
{
    __shared__ int s[256];
    int i = blockIdx.x * 256 + threadIdx.x;
    int v = (i < n) ? deg[i] : 0;
    s[threadIdx.x] = v;
    __syncthreads();
    for (int off = 1; off < 256; off <<= 1) {
        int t = (threadIdx.x >= off) ? s[threadIdx.x - off] : 0;
        __syncthreads();
        s[threadIdx.x] += t;
        __syncthreads();
    }
    if (i < n) rowstart[i] = s[threadIdx.x] - v;
    if (threadIdx.x == 255) partial[blockIdx.x] = s[255];
}

// merged: partial exclusive scan (nb<=256) + gstart exclusive scan (64)
__global__ __launch_bounds__(256) void scan_partial_gstart_kernel(
    int* __restrict__ partial, int nb, const int* __restrict__ gcnt, int* __restrict__ gstart)
{
    __shared__ int s[256];
    __shared__ int g[N_GRAPH];
    int t = threadIdx.x;
    int v = (t < nb) ? partial[t] : 0;
    s[t] = v;
    if (t < N_GRAPH) g[t] = gcnt[t];
    __syncthreads();
    for (int off = 1; off < 256; off <<= 1) {
        int x = (t >= off) ? s[t - off] : 0;
        int y = (t >= off && t < N_GRAPH) ? g[t - off] : 0;
        __syncthreads();
        s[t] += x;
        if (t < N_GRAPH) g[t] += y;
        __syncthreads();
    }
    if (t < nb) partial[t] = s[t] - v;
    if (t < N_GRAPH) gstart[t] = g[t] - gcnt[t];
    if (t == N_GRAPH - 1) gstart[N_GRAPH] = g[t];
}

__global__ __launch_bounds__(256) void scan_add_kernel(
    int* __restrict__ rowstart, const int* __restrict__ partial, int* __restrict__ cursor,
    int n, int E)
{
    int i = blockIdx.x * 256 + threadIdx.x;
    if (i < n) {
        int v = rowstart[i] + partial[blockIdx.x];
        rowstart[i] = v;
        cursor[i] = v;
    }
    if (i == 0) rowstart[n] = E;
}

__global__ __launch_bounds__(256) void fill_kernel(
    const int* __restrict__ ei, int* __restrict__ cursor, int2* __restrict__ csr, int E)
{
    int e = blockIdx.x * 256 + threadIdx.x;
    if (e >= E) return;
    int dst = ei[E + e];
    int pos = atomicAdd(&cursor[dst], 1);
    csr[pos] = make_int2(ei[e], e);
}

// ========== fused GAT aggregation WITH in-wave p computation ==========
// 1 wave/node, 4 ch/lane. Per 8-edge chunk: lane l computes alpha/exp for
// (edge l>>3, head l&(H-1)) -- 64 pairs, zero redundancy at H=8 -- then channel
// lanes pull their head's p via shuffle from lane j*8+hc.
__global__ __launch_bounds__(256) void gat_agg_kernel(
    const int* __restrict__ rowstart, const int2* __restrict__ csr,
    const float* __restrict__ ea, const float* __restrict__ asb,
    const float* __restrict__ adb, const float* __restrict__ MeL,
    const float* __restrict__ h, const float* __restrict__ bias,
    _Float16* __restrict__ Oh, _Float16* __restrict__ Ol, int H, int clog2)
{
    int node = blockIdx.x * 4 + (threadIdx.x >> 6);
    if (node >= N_NODES) return;
    int lane = threadIdx.x & 63;
    int c0 = lane * 4;
    int hc = c0 >> clog2;                 // head owning my 4 channels
    int heff = lane & (H - 1);            // head for my alpha role (H=8 or 1)
    float Mh0 = MeL[0 * H + heff], Mh1 = MeL[1 * H + heff], Mh2 = MeL[2 * H + heff],
          Mh3 = MeL[3 * H + heff], Mh4 = MeL[4 * H + heff];
    float adn = adb[node * H + heff];
    int beg = rowstart[node], end = rowstart[node + 1];
    float ax = 0.f, ay = 0.f, az = 0.f, aw = 0.f, den = 0.f;
    for (int i = beg; i < end; i += 8) {
        int idx = i + (lane >> 3);
        if (idx >= end) idx = end - 1;     // clamp: value unused past nrem
        int2 se = csr[idx];
        const float* eap = ea + (long)se.y * 5;
        float aeh = eap[0] * Mh0 + eap[1] * Mh1 + eap[2] * Mh2 + eap[3] * Mh3 + eap[4] * Mh4;
        float al = asb[se.x * H + heff] + adn + aeh;
        al = fmaxf(al, 0.2f * al);
        float pv = expf(al);
        int nrem = end - i;
#pragma unroll
        for (int j = 0; j < 8; j++) {
            if (j >= nrem) break;
            float pj  = __shfl(pv, j * 8 + hc);
            int  srcj = __shfl(se.x, j * 8);
            const float4 hv = *(const float4*)(h + (long)srcj * NHC + c0);
            den += pj;
            ax += pj * hv.x; ay += pj * hv.y; az += pj * hv.z; aw += pj * hv.w;
        }
    }
    float w = 1.0f / (den + 1e-16f);
    const float4 bv = *(const float4*)(bias + c0);
    float4 v;
    v.x = ax * w + bv.x;  v.y = ay * w + bv.y;
    v.z = az * w + bv.z;  v.w = aw * w + bv.w;
    v.x = (v.x > 0.f) ? v.x : expm1f(v.x);
    v.y = (v.y > 0.f) ? v.y : expm1f(v.y);
    v.z = (v.z > 0.f) ? v.z : expm1f(v.z);
    v.w = (v.w > 0.f) ? v.w : expm1f(v.w);
    f16x4 oh, ol;
    oh[0] = (_Float16)v.x; ol[0] = (_Float16)(v.x - (float)oh[0]);
    oh[1] = (_Float16)v.y; ol[1] = (_Float16)(v.y - (float)oh[1]);
    oh[2] = (_Float16)v.z; ol[2] = (_Float16)(v.z - (float)oh[2]);
    oh[3] = (_Float16)v.w; ol[3] = (_Float16)(v.w - (float)oh[3]);
    *(f16x4*)(Oh + (long)node * NHC + c0) = oh;
    *(f16x4*)(Ol + (long)node * NHC + c0) = ol;
}

// ================= pooling =================
__global__ __launch_bounds__(256) void pool_reduce_kernel(
    const float* __restrict__ f2, const int* __restrict__ gstart, float* __restrict__ out)
{
    __shared__ float red[8][32];
    int g = blockIdx.x;
    int c = threadIdx.x & 31, rsub = threadIdx.x >> 5;
    int beg = gstart[g], end = gstart[g + 1];
    float acc = 0.f;
    for (int row = beg + rsub; row < end; row += 8)
        acc += f2[(long)row * 32 + c];
    red[rsub][c] = acc;
    __syncthreads();
    if (rsub == 0) {
        float s = red[0][c] + red[1][c] + red[2][c] + red[3][c]
                + red[4][c] + red[5][c] + red[6][c] + red[7][c];
        out[g * 32 + c] = s / fmaxf((float)(end - beg), 1.0f);
    }
}

extern "C" void kernel_launch(void* const* d_in, const int* in_sizes, int n_in,
                              void* d_out, int out_size, void* d_ws, size_t ws_size,
                              hipStream_t stream)
{
    const float* x    = (const float*)d_in[0];
    const int*   ei   = (const int*)  d_in[1];
    const float* ea   = (const float*)d_in[2];
    const int*   bat  = (const int*)  d_in[3];
    const float* W[3]   = {(const float*)d_in[4],  (const float*)d_in[10], (const float*)d_in[16]};
    const float* Asl[3] = {(const float*)d_in[5],  (const float*)d_in[11], (const float*)d_in[17]};
    const float* Adl[3] = {(const float*)d_in[6],  (const float*)d_in[12], (const float*)d_in[18]};
    const float* Wel[3] = {(const float*)d_in[7],  (const float*)d_in[13], (const float*)d_in[19]};
    const float* Ael[3] = {(const float*)d_in[8],  (const float*)d_in[14], (const float*)d_in[20]};
    const float* Bil[3] = {(const float*)d_in[9],  (const float*)d_in[15], (const float*)d_in[21]};
    const float* fcW1 = (const float*)d_in[22];
    const float* fcb1 = (const float*)d_in[23];
    const float* fcW2 = (const float*)d_in[24];
    const float* fcb2 = (const float*)d_in[25];

    // ---- workspace carve (bytes) ----
    char* w = (char*)d_ws;
    float*    h    = (float*)w;        w += (size_t)N_NODES * NHC * 4;   // reused as f1 planes
    _Float16* xh   = (_Float16*)w;     w += (size_t)N_NODES * DIN * 2;
    _Float16* xl   = (_Float16*)w;     w += (size_t)N_NODES * DIN * 2;
    _Float16* xbh  = (_Float16*)w;     w += (size_t)N_NODES * NHC * 2;
    _Float16* xbl  = (_Float16*)w;     w += (size_t)N_NODES * NHC * 2;
    float*    f2   = (float*)w;        w += (size_t)N_NODES * DOUT * 4;
    float*    asb  = (float*)w;        w += (size_t)N_NODES * 8 * 4;
    float*    adb  = (float*)w;        w += (size_t)N_NODES * 8 * 4;
    float*    MeAll= (float*)w;        w += 120 * 4;
    _Float16* W1th = (_Float16*)w;     w += (size_t)NHC * DIN * 2;
    _Float16* W1tl = (_Float16*)w;     w += (size_t)NHC * DIN * 2;
    _Float16* W2th = (_Float16*)w;     w += (size_t)NHC * NHC * 2;
    _Float16* W2tl = (_Float16*)w;     w += (size_t)NHC * NHC * 2;
    _Float16* W3th = (_Float16*)w;     w += (size_t)NHC * NHC * 2;
    _Float16* W3tl = (_Float16*)w;     w += (size_t)NHC * NHC * 2;
    _Float16* F1th = (_Float16*)w;     w += (size_t)NHC * NHC * 2;
    _Float16* F1tl = (_Float16*)w;     w += (size_t)NHC * NHC * 2;
    _Float16* F2th = (_Float16*)w;     w += (size_t)128 * NHC * 2;
    _Float16* F2tl = (_Float16*)w;     w += (size_t)128 * NHC * 2;
    int* gcnt     = (int*)w;           w += N_GRAPH * 4;
    int* gstart   = (int*)w;           w += (N_GRAPH + 1) * 4;
    int* deg      = (int*)w;           w += (size_t)N_NODES * 4;
    int* rowstart = (int*)w;           w += (size_t)(N_NODES + 1) * 4;
    int* cursor   = (int*)w;           w += (size_t)N_NODES * 4;
    int* partial  = (int*)w;           w += 256 * 4;
    w = (char*)(((size_t)w + 15) & ~(size_t)15);
    int2* csr     = (int2*)w;          w += (size_t)N_EDGES * 8;
    _Float16* f1h = (_Float16*)h;
    _Float16* f1l = f1h + (size_t)N_NODES * NHC;

    const int NB = (N_NODES + 255) / 256;   // 196 scan blocks

    // 1. prep: x split + all weight tsplits + deg/gcnt zeroing
    prep_kernel<<<(JTOT + 255) / 256, 256, 0, stream>>>(
        x, W[0], W[1], W[2], fcW1, fcW2,
        xh, xl, W1th, W1tl, W2th, W2tl, W3th, W3tl, F1th, F1tl, F2th, F2tl,
        deg, gcnt);
    // 2-6. CSR + graph ranges
    count_hist_kernel<<<(N_EDGES + 255) / 256, 256, 0, stream>>>(ei, bat, deg, gcnt, N_EDGES, N_NODES);
    scan_block_kernel<<<NB, 256, 0, stream>>>(deg, rowstart, partial, N_NODES);
    scan_partial_gstart_kernel<<<1, 256, 0, stream>>>(partial, NB, gcnt, gstart);
    scan_add_kernel<<<NB, 256, 0, stream>>>(rowstart, partial, cursor, N_NODES, N_EDGES);
    fill_kernel<<<(N_EDGES + 255) / 256, 256, 0, stream>>>(ei, cursor, csr, N_EDGES);
    // 7. all Me
    me_all_kernel<<<3, 64, 0, stream>>>(Wel[0], Ael[0], Wel[1], Ael[1], Wel[2], Ael[2], MeAll);

    const int Hs[3] = {8, 8, 1};
    const int Cs[3] = {32, 32, 256};
    const int CL[3] = {5, 5, 8};
    const int Ks[3] = {DIN, NHC, NHC};

    const dim3 ggrid(4, 392);               // Y padded %8 for XCD swizzle

    const _Float16* curh = xh;
    const _Float16* curl = xl;
    const _Float16* Wth[3] = {W1th, W2th, W3th};
    const _Float16* Wtl[3] = {W1tl, W2tl, W3tl};
    for (int l = 0; l < 3; l++) {
        const int H = Hs[l], C = Cs[l];
        const int nh = N_NODES * H;
        mfma_gemm_kernel<<<ggrid, 256, 0, stream>>>(
            curh, curl, Wth[l], Wtl[l], nullptr, h, nullptr, nullptr,
            N_NODES, Ks[l], NHC, 0);
        asd_kernel<<<(nh + 255) / 256, 256, 0, stream>>>(h, Asl[l], Adl[l], asb, adb, nh, H, C);
        gat_agg_kernel<<<(N_NODES + 3) / 4, 256, 0, stream>>>(
            rowstart, csr, ea, asb, adb, MeAll + l * 40, h, Bil[l], xbh, xbl, H, CL[l]);
        curh = xbh; curl = xbl;
    }

    // fc1: gelu(xb @ fcW1 + b) -> f1 planes (overlays dead h)
    mfma_gemm_kernel<<<ggrid, 256, 0, stream>>>(
        xbh, xbl, F1th, F1tl, fcb1, nullptr, f1h, f1l, N_NODES, NHC, NHC, 1);
    // fc2: f1 @ fcW2 + b -> f2 fp32 (cols masked to 32)
    const dim3 g2(1, (N_NODES + 127) / 128);
    mfma_gemm_kernel<<<g2, 256, 0, stream>>>(
        f1h, f1l, F2th, F2tl, fcb2, f2, nullptr, nullptr, N_NODES, NHC, DOUT, 2);

    // pooling
    pool_reduce_kernel<<<N_GRAPH, 256, 0, stream>>>(f2, gstart, (float*)d_out);
}

// Round 10
// 649.714 us; speedup vs baseline: 1.4533x; 1.0254x over previous
//
#include <hip/hip_runtime.h>
#include <math.h>

// GATNet_MLP R10: R9 +
//  (a) asd fused into GEMM epilogue for layers 1-2 with PLAIN STORES (C=32:
//      each wave slab = one head, owned by exactly one wave -> no atomics; R8's
//      regression was atomic-RMW traffic). Layer 3 keeps the asd kernel.
//  (b) fc2 linearity: pool(gelu(f1)@W2+b) = pool(gelu(f1))@W2+b. Pooling fused
//      into fc1 epilogue (LDS per-graph table reusing sAh, batch sorted) ->
//      fc2 GEMM + pool launch + fc1's 51MB output write all deleted.

#define N_NODES 50000
#define N_EDGES 400000
#define N_GRAPH 64
#define DIN     128
#define NHC     256
#define DOUT    32

typedef _Float16 f16x8 __attribute__((ext_vector_type(8)));
typedef _Float16 f16x4 __attribute__((ext_vector_type(4)));
typedef float    f32x4 __attribute__((ext_vector_type(4)));

#define LDP 40   // padded LDS row stride in halfs (80B; kills b128 conflicts)

// ================= fp16x2-split MFMA GEMM, 128x64 tile, pipelined =================
// mode 0: C fp32 [nrow][256]; if asl!=null also per-head a_s/a_d via slab butterfly
//         (valid only when C=32: head = col>>5, one wave per (rowblock,head)).
// mode 3: NO C write; v=gelu(v+bias); per-graph pooled sums (batch sorted).
__global__ __launch_bounds__(256) void mfma_gemm_kernel(
    const _Float16* __restrict__ Ah, const _Float16* __restrict__ Al,
    const _Float16* __restrict__ Bh, const _Float16* __restrict__ Bl,
    const float* __restrict__ bias, float* __restrict__ C,
    const float* __restrict__ asl, const float* __restrict__ adl,
    float* __restrict__ asb, float* __restrict__ adb,
    const int* __restrict__ batch, float* __restrict__ pooled,
    int nrow, int K, int mode)
{
    __shared__ __align__(16) _Float16 sAh[128][LDP];
    __shared__ __align__(16) _Float16 sAl[128][LDP];
    __shared__ __align__(16) _Float16 sBh[64][LDP];
    __shared__ __align__(16) _Float16 sBl[64][LDP];

    const int tid = threadIdx.x, lane = tid & 63, wid = tid >> 6;
    const int wm = wid & 1, wn = wid >> 1;

    int xt, yt;
    if (gridDim.x == 4) {
        int bid = blockIdx.x + (blockIdx.y << 2);
        yt = (bid >> 5) * 8 + (bid & 7);
        xt = (bid >> 3) & 3;
    } else { xt = blockIdx.x; yt = blockIdx.y; }
    const int row0 = yt * 128, col0 = xt * 64;
    if (row0 >= nrow) return;

    const int frow = lane & 15, fk = (lane >> 4) * 8;
    const int ra = tid >> 2, kq = (tid & 3) * 8;

    f32x4 acc[4][2] = {};
    f16x8 pAh[2], pAl[2], pBh, pBl;

    {
#pragma unroll
        for (int p = 0; p < 2; p++) {
            int gr = row0 + p * 64 + ra;
            long go = (long)gr * K + kq;
            pAh[p] = (gr < nrow) ? *(const f16x8*)(Ah + go) : (f16x8)0;
            pAl[p] = (gr < nrow) ? *(const f16x8*)(Al + go) : (f16x8)0;
        }
        long gob = (long)(col0 + ra) * K + kq;
        pBh = *(const f16x8*)(Bh + gob);
        pBl = *(const f16x8*)(Bl + gob);
    }

    for (int k0 = 0; k0 < K; k0 += 32) {
#pragma unroll
        for (int p = 0; p < 2; p++) {
            *(f16x8*)&sAh[p * 64 + ra][kq] = pAh[p];
            *(f16x8*)&sAl[p * 64 + ra][kq] = pAl[p];
        }
        *(f16x8*)&sBh[ra][kq] = pBh;
        *(f16x8*)&sBl[ra][kq] = pBl;
        __syncthreads();

        if (k0 + 32 < K) {
            int kn = k0 + 32 + kq;
#pragma unroll
            for (int p = 0; p < 2; p++) {
                int gr = row0 + p * 64 + ra;
                long go = (long)gr * K + kn;
                pAh[p] = (gr < nrow) ? *(const f16x8*)(Ah + go) : (f16x8)0;
                pAl[p] = (gr < nrow) ? *(const f16x8*)(Al + go) : (f16x8)0;
            }
            long gob = (long)(col0 + ra) * K + kn;
            pBh = *(const f16x8*)(Bh + gob);
            pBl = *(const f16x8*)(Bl + gob);
        }

        f16x8 bh[2], bl[2];
#pragma unroll
        for (int nt = 0; nt < 2; nt++) {
            bh[nt] = *(const f16x8*)&sBh[wn * 32 + nt * 16 + frow][fk];
            bl[nt] = *(const f16x8*)&sBl[wn * 32 + nt * 16 + frow][fk];
        }
#pragma unroll
        for (int mt = 0; mt < 4; mt++) {
            f16x8 ah = *(const f16x8*)&sAh[wm * 64 + mt * 16 + frow][fk];
            f16x8 al = *(const f16x8*)&sAl[wm * 64 + mt * 16 + frow][fk];
#pragma unroll
            for (int nt = 0; nt < 2; nt++) {
                acc[mt][nt] = __builtin_amdgcn_mfma_f32_16x16x32_f16(ah, bh[nt], acc[mt][nt], 0, 0, 0);
                acc[mt][nt] = __builtin_amdgcn_mfma_f32_16x16x32_f16(ah, bl[nt], acc[mt][nt], 0, 0, 0);
                acc[mt][nt] = __builtin_amdgcn_mfma_f32_16x16x32_f16(al, bh[nt], acc[mt][nt], 0, 0, 0);
            }
        }
        __syncthreads();
    }
    // NOTE: loop ends with __syncthreads -> LDS reusable by epilogue.

    const int crow0 = row0 + wm * 64 + (lane >> 4) * 4;
    const int ccol0 = col0 + wn * 32 + (lane & 15);

    if (mode == 0) {
#pragma unroll
        for (int mt = 0; mt < 4; mt++)
#pragma unroll
            for (int nt = 0; nt < 2; nt++) {
                int col = ccol0 + nt * 16;
#pragma unroll
                for (int r = 0; r < 4; r++) {
                    int row = crow0 + mt * 16 + r;
                    if (row < nrow) C[(long)row * 256 + col] = acc[mt][nt][r];
                }
            }
        // fused a_s/a_d (C=32 layers): slab sum == full head dot; plain store.
        if (asl != nullptr) {
            const float asl0 = asl[ccol0], asl1 = asl[ccol0 + 16];
            const float adl0 = adl[ccol0], adl1 = adl[ccol0 + 16];
            const int headw = (col0 + wn * 32) >> 5;   // head of this wave's slab
#pragma unroll
            for (int mt = 0; mt < 4; mt++) {
#pragma unroll
                for (int r = 0; r < 4; r++) {
                    float s = acc[mt][0][r] * asl0 + acc[mt][1][r] * asl1;
                    float d = acc[mt][0][r] * adl0 + acc[mt][1][r] * adl1;
                    s += __shfl_xor(s, 1); s += __shfl_xor(s, 2);
                    s += __shfl_xor(s, 4); s += __shfl_xor(s, 8);
                    d += __shfl_xor(d, 1); d += __shfl_xor(d, 2);
                    d += __shfl_xor(d, 4); d += __shfl_xor(d, 8);
                    if ((lane & 15) == 0) {
                        int row = crow0 + mt * 16 + r;
                        if (row < nrow) {
                            asb[row * 8 + headw] = s;
                            adb[row * 8 + headw] = d;
                        }
                    }
                }
            }
        }
    } else {
        // mode 3: gelu(v+bias) -> per-graph pooled sums. LDS table reuses sAh.
        float* pool = (float*)&sAh[0][0];            // 16*64 floats = 4KB (<10KB)
        const int g0 = batch[row0];
        const int rlast = (row0 + 127 < nrow) ? row0 + 127 : nrow - 1;
        const int gspan = batch[rlast] - g0 + 1;
        const bool fits = (gspan <= 16);
        for (int i = tid; i < 16 * 64; i += 256) pool[i] = 0.f;
        __syncthreads();
#pragma unroll
        for (int mt = 0; mt < 4; mt++)
#pragma unroll
            for (int nt = 0; nt < 2; nt++) {
                int col = ccol0 + nt * 16;
#pragma unroll
                for (int r = 0; r < 4; r++) {
                    int row = crow0 + mt * 16 + r;
                    if (row >= nrow) continue;
                    float v = acc[mt][nt][r] + bias[col];
                    v = 0.5f * v * (1.f + erff(v * 0.7071067811865475f));
                    int gi = batch[row] - g0;
                    if (fits) atomicAdd(&pool[gi * 64 + (col - col0)], v);
                    else      atomicAdd(&pooled[(g0 + gi) * 256 + col], v);
                }
            }
        __syncthreads();
        if (fits) {
            for (int i = tid; i < gspan * 64; i += 256) {
                float val = pool[i];
                if (val != 0.f)
                    atomicAdd(&pooled[(g0 + (i >> 6)) * 256 + col0 + (i & 63)], val);
            }
        }
    }
}

// ================= single prep kernel: x split + 4 weight tsplits + zeroing ======
#define J0 1600000                       // x split (float4 units): N*DIN/4
#define J1 32768                         // W1 tsplit (256 x 128)
#define J2 65536                         // W2
#define J3 65536                         // W3
#define J4 65536                         // fcW1
#define J5 16384                         // zero pooled (64*256)
#define J6 N_NODES                       // zero deg
#define J7 64                            // zero gcnt
#define JTOT (J0+J1+J2+J3+J4+J5+J6+J7)

__device__ __forceinline__ void tsplit_one(const float* W, _Float16* Bh, _Float16* Bl,
                                           int id, int K, int realN)
{
    int n = id / K, k = id - n * K;
    float v = W[(long)k * realN + n];
    _Float16 h = (_Float16)v;
    Bh[id] = h;
    Bl[id] = (_Float16)(v - (float)h);
}

__global__ __launch_bounds__(256) void prep_kernel(
    const float* __restrict__ x,
    const float* __restrict__ W1, const float* __restrict__ W2, const float* __restrict__ W3,
    const float* __restrict__ F1,
    _Float16* __restrict__ xh, _Float16* __restrict__ xl,
    _Float16* __restrict__ W1th, _Float16* __restrict__ W1tl,
    _Float16* __restrict__ W2th, _Float16* __restrict__ W2tl,
    _Float16* __restrict__ W3th, _Float16* __restrict__ W3tl,
    _Float16* __restrict__ F1th, _Float16* __restrict__ F1tl,
    float* __restrict__ pooled, int* __restrict__ deg, int* __restrict__ gcnt)
{
    int idx = blockIdx.x * 256 + threadIdx.x;
    if (idx < J0) {
        float4 v = ((const float4*)x)[idx];
        f16x4 h, l;
        h[0] = (_Float16)v.x; l[0] = (_Float16)(v.x - (float)h[0]);
        h[1] = (_Float16)v.y; l[1] = (_Float16)(v.y - (float)h[1]);
        h[2] = (_Float16)v.z; l[2] = (_Float16)(v.z - (float)h[2]);
        h[3] = (_Float16)v.w; l[3] = (_Float16)(v.w - (float)h[3]);
        *(f16x4*)(xh + (long)idx * 4) = h;
        *(f16x4*)(xl + (long)idx * 4) = l;
        return;
    }
    idx -= J0;
    if (idx < J1) { tsplit_one(W1, W1th, W1tl, idx, DIN, NHC); return; }
    idx -= J1;
    if (idx < J2) { tsplit_one(W2, W2th, W2tl, idx, NHC, NHC); return; }
    idx -= J2;
    if (idx < J3) { tsplit_one(W3, W3th, W3tl, idx, NHC, NHC); return; }
    idx -= J3;
    if (idx < J4) { tsplit_one(F1, F1th, F1tl, idx, NHC, NHC); return; }
    idx -= J4;
    if (idx < J5) { pooled[idx] = 0.f; return; }
    idx -= J5;
    if (idx < J6) { deg[idx] = 0; return; }
    idx -= J6;
    if (idx < J7) { gcnt[idx] = 0; return; }
}

// -------- all 3 layers' Me[5][H] in one launch --------
__global__ void me_all_kernel(
    const float* __restrict__ We1, const float* __restrict__ ae1,
    const float* __restrict__ We2, const float* __restrict__ ae2,
    const float* __restrict__ We3, const float* __restrict__ ae3,
    float* __restrict__ MeAll)
{
    int l = blockIdx.x;
    const float* We = (l == 0) ? We1 : (l == 1) ? We2 : We3;
    const float* ae = (l == 0) ? ae1 : (l == 1) ? ae2 : ae3;
    int H = (l == 2) ? 1 : 8, C = (l == 2) ? 256 : 32;
    int t = threadIdx.x;
    if (t >= 5 * H) return;
    int j = t / H, hh = t - j * H;
    float s = 0.f;
    for (int c = 0; c < C; c++) s += We[j * NHC + hh * C + c] * ae[hh * C + c];
    MeAll[l * 40 + j * H + hh] = s;
}

// -------- asd (layer 3 only: H=1, C=256) --------
__global__ __launch_bounds__(256) void asd_kernel(
    const float* __restrict__ h, const float* __restrict__ atts, const float* __restrict__ attd,
    float* __restrict__ asb, float* __restrict__ adb, int total, int H, int C)
{
    int i = blockIdx.x * 256 + threadIdx.x;
    if (i >= total) return;
    int n = i / H, hh = i - n * H;
    const float4* hp = (const float4*)(h + (long)n * NHC + hh * C);
    const float4* sp = (const float4*)(atts + hh * C);
    const float4* dp = (const float4*)(attd + hh * C);
    float ss = 0.f, dd = 0.f;
    for (int c = 0; c < C / 4; c++) {
        float4 hv = hp[c], sv = sp[c], dv = dp[c];
        ss += hv.x * sv.x + hv.y * sv.y + hv.z * sv.z + hv.w * sv.w;
        dd += hv.x * dv.x + hv.y * dv.y + hv.z * dv.z + hv.w * dv.w;
    }
    asb[i] = ss; adb[i] = dd;
}

// ================= CSR build =================
__global__ __launch_bounds__(256) void count_hist_kernel(
    const int* __restrict__ ei, const int* __restrict__ batch,
    int* __restrict__ deg, int* __restrict__ gcnt, int E, int N)
{
    __shared__ int hist[N_GRAPH];
    int t = threadIdx.x;
    if (t < N_GRAPH) hist[t] = 0;
    __syncthreads();
    int i = blockIdx.x * 256 + t;
    if (i < E) atomicAdd(&deg[ei[E + i]], 1);
    if (i < N) atomicAdd(&hist[batch[i]], 1);
    __syncthreads();
    if (t < N_GRAPH && hist[t] > 0) atomicAdd(&gcnt[t], hist[t]);
}

__global__ __launch_bounds__(256) void scan_block_kernel(
    const int* __restrict__ deg, int* __restrict__ rowstart, int* __restrict__ partial, int n)
{
    __shared__ int s[256];
    int i = blockIdx.x * 256 + threadIdx.x;
    int v = (i < n) ? deg[i] : 0;
    s[threadIdx.x] = v;
    __syncthreads();
    for (int off = 1; off < 256; off <<= 1) {
        int t = (threadIdx.x >= off) ? s[threadIdx.x - off] : 0;
        __syncthreads();
        s[threadIdx.x] += t;
        __syncthreads();
    }
    if (i < n) rowstart[i] = s[threadIdx.x] - v;
    if (threadIdx.x == 255) partial[blockIdx.x] = s[255];
}

__global__ __launch_bounds__(256) void scan_partial_kernel(int* __restrict__ partial, int nb)
{
    __shared__ int s[256];
    int v = (threadIdx.x < nb) ? partial[threadIdx.x] : 0;
    s[threadIdx.x] = v;
    __syncthreads();
    for (int off = 1; off < 256; off <<= 1) {
        int t = (threadIdx.x >= off) ? s[threadIdx.x - off] : 0;
        __syncthreads();
        s[threadIdx.x] += t;
        __syncthreads();
    }
    if (threadIdx.x < nb) partial[threadIdx.x] = s[threadIdx.x] - v;
}

__global__ __launch_bounds__(256) void scan_add_kernel(
    int* __restrict__ rowstart, const int* __restrict__ partial, int* __restrict__ cursor,
    int n, int E)
{
    int i = blockIdx.x * 256 + threadIdx.x;
    if (i < n) {
        int v = rowstart[i] + partial[blockIdx.x];
        rowstart[i] = v;
        cursor[i] = v;
    }
    if (i == 0) rowstart[n] = E;
}

__global__ __launch_bounds__(256) void fill_kernel(
    const int* __restrict__ ei, int* __restrict__ cursor, int2* __restrict__ csr, int E)
{
    int e = blockIdx.x * 256 + threadIdx.x;
    if (e >= E) return;
    int dst = ei[E + e];
    int pos = atomicAdd(&cursor[dst], 1);
    csr[pos] = make_int2(ei[e], e);
}

// ========== fused GAT aggregation with in-wave p computation (R9 exact) ==========
__global__ __launch_bounds__(256) void gat_agg_kernel(
    const int* __restrict__ rowstart, const int2* __restrict__ csr,
    const float* __restrict__ ea, const float* __restrict__ asb,
    const float* __restrict__ adb, const float* __restrict__ MeL,
    const float* __restrict__ h, const float* __restrict__ bias,
    _Float16* __restrict__ Oh, _Float16* __restrict__ Ol, int H, int clog2)
{
    int node = blockIdx.x * 4 + (threadIdx.x >> 6);
    if (node >= N_NODES) return;
    int lane = threadIdx.x & 63;
    int c0 = lane * 4;
    int hc = c0 >> clog2;
    int heff = lane & (H - 1);
    float Mh0 = MeL[0 * H + heff], Mh1 = MeL[1 * H + heff], Mh2 = MeL[2 * H + heff],
          Mh3 = MeL[3 * H + heff], Mh4 = MeL[4 * H + heff];
    float adn = adb[node * H + heff];
    int beg = rowstart[node], end = rowstart[node + 1];
    float ax = 0.f, ay = 0.f, az = 0.f, aw = 0.f, den = 0.f;
    for (int i = beg; i < end; i += 8) {
        int idx = i + (lane >> 3);
        if (idx >= end) idx = end - 1;
        int2 se = csr[idx];
        const float* eap = ea + (long)se.y * 5;
        float aeh = eap[0] * Mh0 + eap[1] * Mh1 + eap[2] * Mh2 + eap[3] * Mh3 + eap[4] * Mh4;
        float al = asb[se.x * H + heff] + adn + aeh;
        al = fmaxf(al, 0.2f * al);
        float pv = expf(al);
        int nrem = end - i;
#pragma unroll
        for (int j = 0; j < 8; j++) {
            if (j >= nrem) break;
            float pj  = __shfl(pv, j * 8 + hc);
            int  srcj = __shfl(se.x, j * 8);
            const float4 hv = *(const float4*)(h + (long)srcj * NHC + c0);
            den += pj;
            ax += pj * hv.x; ay += pj * hv.y; az += pj * hv.z; aw += pj * hv.w;
        }
    }
    float w = 1.0f / (den + 1e-16f);
    const float4 bv = *(const float4*)(bias + c0);
    float4 v;
    v.x = ax * w + bv.x;  v.y = ay * w + bv.y;
    v.z = az * w + bv.z;  v.w = aw * w + bv.w;
    v.x = (v.x > 0.f) ? v.x : expm1f(v.x);
    v.y = (v.y > 0.f) ? v.y : expm1f(v.y);
    v.z = (v.z > 0.f) ? v.z : expm1f(v.z);
    v.w = (v.w > 0.f) ? v.w : expm1f(v.w);
    f16x4 oh, ol;
    oh[0] = (_Float16)v.x; ol[0] = (_Float16)(v.x - (float)oh[0]);
    oh[1] = (_Float16)v.y; ol[1] = (_Float16)(v.y - (float)oh[1]);
    oh[2] = (_Float16)v.z; ol[2] = (_Float16)(v.z - (float)oh[2]);
    oh[3] = (_Float16)v.w; ol[3] = (_Float16)(v.w - (float)oh[3]);
    *(f16x4*)(Oh + (long)node * NHC + c0) = oh;
    *(f16x4*)(Ol + (long)node * NHC + c0) = ol;
}

// ================= final: out[g,:] = (pooled[g,:]@fcW2)/cnt + fcb2 =================
__global__ void final_kernel(const float* __restrict__ pooled, const int* __restrict__ gcnt,
                             const float* __restrict__ fcW2, const float* __restrict__ fcb2,
                             float* __restrict__ out)
{
    int g = blockIdx.x;
    int j = threadIdx.x;
    if (j >= DOUT) return;
    float s = 0.f;
    for (int k = 0; k < NHC; k++) s += pooled[g * NHC + k] * fcW2[k * DOUT + j];
    int c = gcnt[g];
    out[g * DOUT + j] = (c > 0) ? (s / (float)c + fcb2[j]) : 0.f;
}

extern "C" void kernel_launch(void* const* d_in, const int* in_sizes, int n_in,
                              void* d_out, int out_size, void* d_ws, size_t ws_size,
                              hipStream_t stream)
{
    const float* x    = (const float*)d_in[0];
    const int*   ei   = (const int*)  d_in[1];
    const float* ea   = (const float*)d_in[2];
    const int*   bat  = (const int*)  d_in[3];
    const float* W[3]   = {(const float*)d_in[4],  (const float*)d_in[10], (const float*)d_in[16]};
    const float* Asl[3] = {(const float*)d_in[5],  (const float*)d_in[11], (const float*)d_in[17]};
    const float* Adl[3] = {(const float*)d_in[6],  (const float*)d_in[12], (const float*)d_in[18]};
    const float* Wel[3] = {(const float*)d_in[7],  (const float*)d_in[13], (const float*)d_in[19]};
    const float* Ael[3] = {(const float*)d_in[8],  (const float*)d_in[14], (const float*)d_in[20]};
    const float* Bil[3] = {(const float*)d_in[9],  (const float*)d_in[15], (const float*)d_in[21]};
    const float* fcW1 = (const float*)d_in[22];
    const float* fcb1 = (const float*)d_in[23];
    const float* fcW2 = (const float*)d_in[24];
    const float* fcb2 = (const float*)d_in[25];

    // ---- workspace carve (bytes) ----
    char* w = (char*)d_ws;
    float*    h    = (float*)w;        w += (size_t)N_NODES * NHC * 4;
    _Float16* xh   = (_Float16*)w;     w += (size_t)N_NODES * DIN * 2;
    _Float16* xl   = (_Float16*)w;     w += (size_t)N_NODES * DIN * 2;
    _Float16* xbh  = (_Float16*)w;     w += (size_t)N_NODES * NHC * 2;
    _Float16* xbl  = (_Float16*)w;     w += (size_t)N_NODES * NHC * 2;
    float*    asb  = (float*)w;        w += (size_t)N_NODES * 8 * 4;
    float*    adb  = (float*)w;        w += (size_t)N_NODES * 8 * 4;
    float*    MeAll= (float*)w;        w += 120 * 4;
    float*    pooled=(float*)w;        w += (size_t)N_GRAPH * NHC * 4;
    _Float16* W1th = (_Float16*)w;     w += (size_t)NHC * DIN * 2;
    _Float16* W1tl = (_Float16*)w;     w += (size_t)NHC * DIN * 2;
    _Float16* W2th = (_Float16*)w;     w += (size_t)NHC * NHC * 2;
    _Float16* W2tl = (_Float16*)w;     w += (size_t)NHC * NHC * 2;
    _Float16* W3th = (_Float16*)w;     w += (size_t)NHC * NHC * 2;
    _Float16* W3tl = (_Float16*)w;     w += (size_t)NHC * NHC * 2;
    _Float16* F1th = (_Float16*)w;     w += (size_t)NHC * NHC * 2;
    _Float16* F1tl = (_Float16*)w;     w += (size_t)NHC * NHC * 2;
    int* gcnt     = (int*)w;           w += N_GRAPH * 4;
    int* deg      = (int*)w;           w += (size_t)N_NODES * 4;
    int* rowstart = (int*)w;           w += (size_t)(N_NODES + 1) * 4;
    int* cursor   = (int*)w;           w += (size_t)N_NODES * 4;
    int* partial  = (int*)w;           w += 256 * 4;
    w = (char*)(((size_t)w + 15) & ~(size_t)15);
    int2* csr     = (int2*)w;          w += (size_t)N_EDGES * 8;

    const int NB = (N_NODES + 255) / 256;   // 196 scan blocks

    // 1. prep: splits + pooled/deg/gcnt zeroing
    prep_kernel<<<(JTOT + 255) / 256, 256, 0, stream>>>(
        x, W[0], W[1], W[2], fcW1,
        xh, xl, W1th, W1tl, W2th, W2tl, W3th, W3tl, F1th, F1tl,
        pooled, deg, gcnt);
    // 2-6. CSR + graph counts
    count_hist_kernel<<<(N_EDGES + 255) / 256, 256, 0, stream>>>(ei, bat, deg, gcnt, N_EDGES, N_NODES);
    scan_block_kernel<<<NB, 256, 0, stream>>>(deg, rowstart, partial, N_NODES);
    scan_partial_kernel<<<1, 256, 0, stream>>>(partial, NB);
    scan_add_kernel<<<NB, 256, 0, stream>>>(rowstart, partial, cursor, N_NODES, N_EDGES);
    fill_kernel<<<(N_EDGES + 255) / 256, 256, 0, stream>>>(ei, cursor, csr, N_EDGES);
    // 7. all Me
    me_all_kernel<<<3, 64, 0, stream>>>(Wel[0], Ael[0], Wel[1], Ael[1], Wel[2], Ael[2], MeAll);

    const int Hs[3] = {8, 8, 1};
    const int CL[3] = {5, 5, 8};
    const int Ks[3] = {DIN, NHC, NHC};

    const dim3 ggrid(4, 392);               // Y padded %8 for XCD swizzle

    const _Float16* curh = xh;
    const _Float16* curl = xl;
    const _Float16* Wth[3] = {W1th, W2th, W3th};
    const _Float16* Wtl[3] = {W1tl, W2tl, W3tl};
    for (int l = 0; l < 3; l++) {
        const int H = Hs[l];
        const bool fuse = (l != 2);          // C=32 layers: asd fused, plain stores
        mfma_gemm_kernel<<<ggrid, 256, 0, stream>>>(
            curh, curl, Wth[l], Wtl[l], nullptr, h,
            fuse ? Asl[l] : nullptr, fuse ? Adl[l] : nullptr, asb, adb,
            nullptr, nullptr,
            N_NODES, Ks[l], 0);
        if (!fuse)
            asd_kernel<<<(N_NODES + 255) / 256, 256, 0, stream>>>(
                h, Asl[l], Adl[l], asb, adb, N_NODES, 1, NHC);
        gat_agg_kernel<<<(N_NODES + 3) / 4, 256, 0, stream>>>(
            rowstart, csr, ea, asb, adb, MeAll + l * 40, h, Bil[l], xbh, xbl, H, CL[l]);
        curh = xbh; curl = xbl;
    }

    // fc1 + fused gelu + per-graph pooling (fc2 commutes with pooling)
    mfma_gemm_kernel<<<ggrid, 256, 0, stream>>>(
        xbh, xbl, F1th, F1tl, fcb1, nullptr,
        nullptr, nullptr, nullptr, nullptr,
        bat, pooled,
        N_NODES, NHC, 3);
    // final: (pooled @ fcW2)/cnt + fcb2
    final_kernel<<<N_GRAPH, 64, 0, stream>>>(pooled, gcnt, fcW2, fcb2, (float*)d_out);
}

// Round 11
// 582.767 us; speedup vs baseline: 1.6203x; 1.1149x over previous
//
#include <hip/hip_runtime.h>
#include <math.h>

// GATNet_MLP R11: R10 with the mode-3 (fc1+gelu+pool) epilogue fixed:
// register pre-accumulation grouped by graph id (128-row block spans ~1-2 graphs)
// -> LDS float atomics 8192/block -> ~512-1024/block (R10 counters: mode-3 GEMM
// 105us vs 74us mode-1; epilogue LDS atomic contention was the +31us).

#define N_NODES 50000
#define N_EDGES 400000
#define N_GRAPH 64
#define DIN     128
#define NHC     256
#define DOUT    32

typedef _Float16 f16x8 __attribute__((ext_vector_type(8)));
typedef _Float16 f16x4 __attribute__((ext_vector_type(4)));
typedef float    f32x4 __attribute__((ext_vector_type(4)));

#define LDP 40   // padded LDS row stride in halfs (80B; kills b128 conflicts)

// ================= fp16x2-split MFMA GEMM, 128x64 tile, pipelined =================
// mode 0: C fp32 [nrow][256]; if asl!=null also per-head a_s/a_d (C=32 layers only).
// mode 3: NO C write; v=gelu(v+bias); per-graph pooled sums (batch sorted).
__global__ __launch_bounds__(256) void mfma_gemm_kernel(
    const _Float16* __restrict__ Ah, const _Float16* __restrict__ Al,
    const _Float16* __restrict__ Bh, const _Float16* __restrict__ Bl,
    const float* __restrict__ bias, float* __restrict__ C,
    const float* __restrict__ asl, const float* __restrict__ adl,
    float* __restrict__ asb, float* __restrict__ adb,
    const int* __restrict__ batch, float* __restrict__ pooled,
    int nrow, int K, int mode)
{
    __shared__ __align__(16) _Float16 sAh[128][LDP];
    __shared__ __align__(16) _Float16 sAl[128][LDP];
    __shared__ __align__(16) _Float16 sBh[64][LDP];
    __shared__ __align__(16) _Float16 sBl[64][LDP];

    const int tid = threadIdx.x, lane = tid & 63, wid = tid >> 6;
    const int wm = wid & 1, wn = wid >> 1;

    int xt, yt;
    if (gridDim.x == 4) {
        int bid = blockIdx.x + (blockIdx.y << 2);
        yt = (bid >> 5) * 8 + (bid & 7);
        xt = (bid >> 3) & 3;
    } else { xt = blockIdx.x; yt = blockIdx.y; }
    const int row0 = yt * 128, col0 = xt * 64;
    if (row0 >= nrow) return;

    const int frow = lane & 15, fk = (lane >> 4) * 8;
    const int ra = tid >> 2, kq = (tid & 3) * 8;

    f32x4 acc[4][2] = {};
    f16x8 pAh[2], pAl[2], pBh, pBl;

    {
#pragma unroll
        for (int p = 0; p < 2; p++) {
            int gr = row0 + p * 64 + ra;
            long go = (long)gr * K + kq;
            pAh[p] = (gr < nrow) ? *(const f16x8*)(Ah + go) : (f16x8)0;
            pAl[p] = (gr < nrow) ? *(const f16x8*)(Al + go) : (f16x8)0;
        }
        long gob = (long)(col0 + ra) * K + kq;
        pBh = *(const f16x8*)(Bh + gob);
        pBl = *(const f16x8*)(Bl + gob);
    }

    for (int k0 = 0; k0 < K; k0 += 32) {
#pragma unroll
        for (int p = 0; p < 2; p++) {
            *(f16x8*)&sAh[p * 64 + ra][kq] = pAh[p];
            *(f16x8*)&sAl[p * 64 + ra][kq] = pAl[p];
        }
        *(f16x8*)&sBh[ra][kq] = pBh;
        *(f16x8*)&sBl[ra][kq] = pBl;
        __syncthreads();

        if (k0 + 32 < K) {
            int kn = k0 + 32 + kq;
#pragma unroll
            for (int p = 0; p < 2; p++) {
                int gr = row0 + p * 64 + ra;
                long go = (long)gr * K + kn;
                pAh[p] = (gr < nrow) ? *(const f16x8*)(Ah + go) : (f16x8)0;
                pAl[p] = (gr < nrow) ? *(const f16x8*)(Al + go) : (f16x8)0;
            }
            long gob = (long)(col0 + ra) * K + kn;
            pBh = *(const f16x8*)(Bh + gob);
            pBl = *(const f16x8*)(Bl + gob);
        }

        f16x8 bh[2], bl[2];
#pragma unroll
        for (int nt = 0; nt < 2; nt++) {
            bh[nt] = *(const f16x8*)&sBh[wn * 32 + nt * 16 + frow][fk];
            bl[nt] = *(const f16x8*)&sBl[wn * 32 + nt * 16 + frow][fk];
        }
#pragma unroll
        for (int mt = 0; mt < 4; mt++) {
            f16x8 ah = *(const f16x8*)&sAh[wm * 64 + mt * 16 + frow][fk];
            f16x8 al = *(const f16x8*)&sAl[wm * 64 + mt * 16 + frow][fk];
#pragma unroll
            for (int nt = 0; nt < 2; nt++) {
                acc[mt][nt] = __builtin_amdgcn_mfma_f32_16x16x32_f16(ah, bh[nt], acc[mt][nt], 0, 0, 0);
                acc[mt][nt] = __builtin_amdgcn_mfma_f32_16x16x32_f16(ah, bl[nt], acc[mt][nt], 0, 0, 0);
                acc[mt][nt] = __builtin_amdgcn_mfma_f32_16x16x32_f16(al, bh[nt], acc[mt][nt], 0, 0, 0);
            }
        }
        __syncthreads();
    }

    const int crow0 = row0 + wm * 64 + (lane >> 4) * 4;
    const int ccol0 = col0 + wn * 32 + (lane & 15);

    if (mode == 0) {
#pragma unroll
        for (int mt = 0; mt < 4; mt++)
#pragma unroll
            for (int nt = 0; nt < 2; nt++) {
                int col = ccol0 + nt * 16;
#pragma unroll
                for (int r = 0; r < 4; r++) {
                    int row = crow0 + mt * 16 + r;
                    if (row < nrow) C[(long)row * 256 + col] = acc[mt][nt][r];
                }
            }
        // fused a_s/a_d (C=32 layers): slab sum == full head dot; plain store.
        if (asl != nullptr) {
            const float asl0 = asl[ccol0], asl1 = asl[ccol0 + 16];
            const float adl0 = adl[ccol0], adl1 = adl[ccol0 + 16];
            const int headw = (col0 + wn * 32) >> 5;
#pragma unroll
            for (int mt = 0; mt < 4; mt++) {
#pragma unroll
                for (int r = 0; r < 4; r++) {
                    float s = acc[mt][0][r] * asl0 + acc[mt][1][r] * asl1;
                    float d = acc[mt][0][r] * adl0 + acc[mt][1][r] * adl1;
                    s += __shfl_xor(s, 1); s += __shfl_xor(s, 2);
                    s += __shfl_xor(s, 4); s += __shfl_xor(s, 8);
                    d += __shfl_xor(d, 1); d += __shfl_xor(d, 2);
                    d += __shfl_xor(d, 4); d += __shfl_xor(d, 8);
                    if ((lane & 15) == 0) {
                        int row = crow0 + mt * 16 + r;
                        if (row < nrow) {
                            asb[row * 8 + headw] = s;
                            adb[row * 8 + headw] = d;
                        }
                    }
                }
            }
        }
    } else {
        // mode 3: gelu(v+bias) -> per-graph pooled sums.
        // Register pre-accumulation grouped by graph id (rows are consecutive
        // within thread walk order; 128-row block spans ~1-2 graphs), then
        // few LDS atomics, then one global flush. (R10: per-element LDS atomics
        // cost +31us.)
        float* pool = (float*)&sAh[0][0];            // 16*64 floats = 4KB
        const int g0 = batch[row0];
        const int rlast = (row0 + 127 < nrow) ? row0 + 127 : nrow - 1;
        const int gspan = batch[rlast] - g0 + 1;
        const bool fits = (gspan <= 16);
        for (int i = tid; i < 16 * 64; i += 256) pool[i] = 0.f;
        __syncthreads();

        const float b0 = bias[ccol0], b1 = bias[ccol0 + 16];
        const int lc0 = ccol0 - col0, lc1 = lc0 + 16;   // LDS col offsets
        float sum0 = 0.f, sum1 = 0.f;
        int curg = -1;
#pragma unroll
        for (int mt = 0; mt < 4; mt++) {
#pragma unroll
            for (int r = 0; r < 4; r++) {
                int row = crow0 + mt * 16 + r;
                if (row >= nrow) continue;
                int g = batch[row];
                if (g != curg) {
                    if (curg >= 0) {
                        if (fits) {
                            atomicAdd(&pool[(curg - g0) * 64 + lc0], sum0);
                            atomicAdd(&pool[(curg - g0) * 64 + lc1], sum1);
                        } else {
                            atomicAdd(&pooled[curg * 256 + ccol0], sum0);
                            atomicAdd(&pooled[curg * 256 + ccol0 + 16], sum1);
                        }
                    }
                    curg = g; sum0 = 0.f; sum1 = 0.f;
                }
                float v0 = acc[mt][0][r] + b0;
                float v1 = acc[mt][1][r] + b1;
                sum0 += 0.5f * v0 * (1.f + erff(v0 * 0.7071067811865475f));
                sum1 += 0.5f * v1 * (1.f + erff(v1 * 0.7071067811865475f));
            }
        }
        if (curg >= 0) {
            if (fits) {
                atomicAdd(&pool[(curg - g0) * 64 + lc0], sum0);
                atomicAdd(&pool[(curg - g0) * 64 + lc1], sum1);
            } else {
                atomicAdd(&pooled[curg * 256 + ccol0], sum0);
                atomicAdd(&pooled[curg * 256 + ccol0 + 16], sum1);
            }
        }
        __syncthreads();
        if (fits) {
            for (int i = tid; i < gspan * 64; i += 256) {
                float val = pool[i];
                if (val != 0.f)
                    atomicAdd(&pooled[(g0 + (i >> 6)) * 256 + col0 + (i & 63)], val);
            }
        }
    }
}

// ================= single prep kernel =================
#define J0 1600000                       // x split (float4 units): N*DIN/4
#define J1 32768                         // W1 tsplit (256 x 128)
#define J2 65536                         // W2
#define J3 65536                         // W3
#define J4 65536                         // fcW1
#define J5 16384                         // zero pooled (64*256)
#define J6 N_NODES                       // zero deg
#define J7 64                            // zero gcnt
#define JTOT (J0+J1+J2+J3+J4+J5+J6+J7)

__device__ __forceinline__ void tsplit_one(const float* W, _Float16* Bh, _Float16* Bl,
                                           int id, int K, int realN)
{
    int n = id / K, k = id - n * K;
    float v = W[(long)k * realN + n];
    _Float16 h = (_Float16)v;
    Bh[id] = h;
    Bl[id] = (_Float16)(v - (float)h);
}

__global__ __launch_bounds__(256) void prep_kernel(
    const float* __restrict__ x,
    const float* __restrict__ W1, const float* __restrict__ W2, const float* __restrict__ W3,
    const float* __restrict__ F1,
    _Float16* __restrict__ xh, _Float16* __restrict__ xl,
    _Float16* __restrict__ W1th, _Float16* __restrict__ W1tl,
    _Float16* __restrict__ W2th, _Float16* __restrict__ W2tl,
    _Float16* __restrict__ W3th, _Float16* __restrict__ W3tl,
    _Float16* __restrict__ F1th, _Float16* __restrict__ F1tl,
    float* __restrict__ pooled, int* __restrict__ deg, int* __restrict__ gcnt)
{
    int idx = blockIdx.x * 256 + threadIdx.x;
    if (idx < J0) {
        float4 v = ((const float4*)x)[idx];
        f16x4 h, l;
        h[0] = (_Float16)v.x; l[0] = (_Float16)(v.x - (float)h[0]);
        h[1] = (_Float16)v.y; l[1] = (_Float16)(v.y - (float)h[1]);
        h[2] = (_Float16)v.z; l[2] = (_Float16)(v.z - (float)h[2]);
        h[3] = (_Float16)v.w; l[3] = (_Float16)(v.w - (float)h[3]);
        *(f16x4*)(xh + (long)idx * 4) = h;
        *(f16x4*)(xl + (long)idx * 4) = l;
        return;
    }
    idx -= J0;
    if (idx < J1) { tsplit_one(W1, W1th, W1tl, idx, DIN, NHC); return; }
    idx -= J1;
    if (idx < J2) { tsplit_one(W2, W2th, W2tl, idx, NHC, NHC); return; }
    idx -= J2;
    if (idx < J3) { tsplit_one(W3, W3th, W3tl, idx, NHC, NHC); return; }
    idx -= J3;
    if (idx < J4) { tsplit_one(F1, F1th, F1tl, idx, NHC, NHC); return; }
    idx -= J4;
    if (idx < J5) { pooled[idx] = 0.f; return; }
    idx -= J5;
    if (idx < J6) { deg[idx] = 0; return; }
    idx -= J6;
    if (idx < J7) { gcnt[idx] = 0; return; }
}

// -------- all 3 layers' Me[5][H] in one launch --------
__global__ void me_all_kernel(
    const float* __restrict__ We1, const float* __restrict__ ae1,
    const float* __restrict__ We2, const float* __restrict__ ae2,
    const float* __restrict__ We3, const float* __restrict__ ae3,
    float* __restrict__ MeAll)
{
    int l = blockIdx.x;
    const float* We = (l == 0) ? We1 : (l == 1) ? We2 : We3;
    const float* ae = (l == 0) ? ae1 : (l == 1) ? ae2 : ae3;
    int H = (l == 2) ? 1 : 8, C = (l == 2) ? 256 : 32;
    int t = threadIdx.x;
    if (t >= 5 * H) return;
    int j = t / H, hh = t - j * H;
    float s = 0.f;
    for (int c = 0; c < C; c++) s += We[j * NHC + hh * C + c] * ae[hh * C + c];
    MeAll[l * 40 + j * H + hh] = s;
}

// -------- asd (layer 3 only: H=1, C=256) --------
__global__ __launch_bounds__(256) void asd_kernel(
    const float* __restrict__ h, const float* __restrict__ atts, const float* __restrict__ attd,
    float* __restrict__ asb, float* __restrict__ adb, int total, int H, int C)
{
    int i = blockIdx.x * 256 + threadIdx.x;
    if (i >= total) return;
    int n = i / H, hh = i - n * H;
    const float4* hp = (const float4*)(h + (long)n * NHC + hh * C);
    const float4* sp = (const float4*)(atts + hh * C);
    const float4* dp = (const float4*)(attd + hh * C);
    float ss = 0.f, dd = 0.f;
    for (int c = 0; c < C / 4; c++) {
        float4 hv = hp[c], sv = sp[c], dv = dp[c];
        ss += hv.x * sv.x + hv.y * sv.y + hv.z * sv.z + hv.w * sv.w;
        dd += hv.x * dv.x + hv.y * dv.y + hv.z * dv.z + hv.w * dv.w;
    }
    asb[i] = ss; adb[i] = dd;
}

// ================= CSR build =================
__global__ __launch_bounds__(256) void count_hist_kernel(
    const int* __restrict__ ei, const int* __restrict__ batch,
    int* __restrict__ deg, int* __restrict__ gcnt, int E, int N)
{
    __shared__ int hist[N_GRAPH];
    int t = threadIdx.x;
    if (t < N_GRAPH) hist[t] = 0;
    __syncthreads();
    int i = blockIdx.x * 256 + t;
    if (i < E) atomicAdd(&deg[ei[E + i]], 1);
    if (i < N) atomicAdd(&hist[batch[i]], 1);
    __syncthreads();
    if (t < N_GRAPH && hist[t] > 0) atomicAdd(&gcnt[t], hist[t]);
}

__global__ __launch_bounds__(256) void scan_block_kernel(
    const int* __restrict__ deg, int* __restrict__ rowstart, int* __restrict__ partial, int n)
{
    __shared__ int s[256];
    int i = blockIdx.x * 256 + threadIdx.x;
    int v = (i < n) ? deg[i] : 0;
    s[threadIdx.x] = v;
    __syncthreads();
    for (int off = 1; off < 256; off <<= 1) {
        int t = (threadIdx.x >= off) ? s[threadIdx.x - off] : 0;
        __syncthreads();
        s[threadIdx.x] += t;
        __syncthreads();
    }
    if (i < n) rowstart[i] = s[threadIdx.x] - v;
    if (threadIdx.x == 255) partial[blockIdx.x] = s[255];
}

__global__ __launch_bounds__(256) void scan_partial_kernel(int* __restrict__ partial, int nb)
{
    __shared__ int s[256];
    int v = (threadIdx.x < nb) ? partial[threadIdx.x] : 0;
    s[threadIdx.x] = v;
    __syncthreads();
    for (int off = 1; off < 256; off <<= 1) {
        int t = (threadIdx.x >= off) ? s[threadIdx.x - off] : 0;
        __syncthreads();
        s[threadIdx.x] += t;
        __syncthreads();
    }
    if (threadIdx.x < nb) partial[threadIdx.x] = s[threadIdx.x] - v;
}

__global__ __launch_bounds__(256) void scan_add_kernel(
    int* __restrict__ rowstart, const int* __restrict__ partial, int* __restrict__ cursor,
    int n, int E)
{
    int i = blockIdx.x * 256 + threadIdx.x;
    if (i < n) {
        int v = rowstart[i] + partial[blockIdx.x];
        rowstart[i] = v;
        cursor[i] = v;
    }
    if (i == 0) rowstart[n] = E;
}

__global__ __launch_bounds__(256) void fill_kernel(
    const int* __restrict__ ei, int* __restrict__ cursor, int2* __restrict__ csr, int E)
{
    int e = blockIdx.x * 256 + threadIdx.x;
    if (e >= E) return;
    int dst = ei[E + e];
    int pos = atomicAdd(&cursor[dst], 1);
    csr[pos] = make_int2(ei[e], e);
}

// ========== fused GAT aggregation with in-wave p computation ==========
__global__ __launch_bounds__(256) void gat_agg_kernel(
    const int* __restrict__ rowstart, const int2* __restrict__ csr,
    const float* __restrict__ ea, const float* __restrict__ asb,
    const float* __restrict__ adb, const float* __restrict__ MeL,
    const float* __restrict__ h, const float* __restrict__ bias,
    _Float16* __restrict__ Oh, _Float16* __restrict__ Ol, int H, int clog2)
{
    int node = blockIdx.x * 4 + (threadIdx.x >> 6);
    if (node >= N_NODES) return;
    int lane = threadIdx.x & 63;
    int c0 = lane * 4;
    int hc = c0 >> clog2;
    int heff = lane & (H - 1);
    float Mh0 = MeL[0 * H + heff], Mh1 = MeL[1 * H + heff], Mh2 = MeL[2 * H + heff],
          Mh3 = MeL[3 * H + heff], Mh4 = MeL[4 * H + heff];
    float adn = adb[node * H + heff];
    int beg = rowstart[node], end = rowstart[node + 1];
    float ax = 0.f, ay = 0.f, az = 0.f, aw = 0.f, den = 0.f;
    for (int i = beg; i < end; i += 8) {
        int idx = i + (lane >> 3);
        if (idx >= end) idx = end - 1;
        int2 se = csr[idx];
        const float* eap = ea + (long)se.y * 5;
        float aeh = eap[0] * Mh0 + eap[1] * Mh1 + eap[2] * Mh2 + eap[3] * Mh3 + eap[4] * Mh4;
        float al = asb[se.x * H + heff] + adn + aeh;
        al = fmaxf(al, 0.2f * al);
        float pv = expf(al);
        int nrem = end - i;
#pragma unroll
        for (int j = 0; j < 8; j++) {
            if (j >= nrem) break;
            float pj  = __shfl(pv, j * 8 + hc);
            int  srcj = __shfl(se.x, j * 8);
            const float4 hv = *(const float4*)(h + (long)srcj * NHC + c0);
            den += pj;
            ax += pj * hv.x; ay += pj * hv.y; az += pj * hv.z; aw += pj * hv.w;
        }
    }
    float w = 1.0f / (den + 1e-16f);
    const float4 bv = *(const float4*)(bias + c0);
    float4 v;
    v.x = ax * w + bv.x;  v.y = ay * w + bv.y;
    v.z = az * w + bv.z;  v.w = aw * w + bv.w;
    v.x = (v.x > 0.f) ? v.x : expm1f(v.x);
    v.y = (v.y > 0.f) ? v.y : expm1f(v.y);
    v.z = (v.z > 0.f) ? v.z : expm1f(v.z);
    v.w = (v.w > 0.f) ? v.w : expm1f(v.w);
    f16x4 oh, ol;
    oh[0] = (_Float16)v.x; ol[0] = (_Float16)(v.x - (float)oh[0]);
    oh[1] = (_Float16)v.y; ol[1] = (_Float16)(v.y - (float)oh[1]);
    oh[2] = (_Float16)v.z; ol[2] = (_Float16)(v.z - (float)oh[2]);
    oh[3] = (_Float16)v.w; ol[3] = (_Float16)(v.w - (float)oh[3]);
    *(f16x4*)(Oh + (long)node * NHC + c0) = oh;
    *(f16x4*)(Ol + (long)node * NHC + c0) = ol;
}

// ================= final: out[g,:] = (pooled[g,:]@fcW2)/cnt + fcb2 =================
__global__ void final_kernel(const float* __restrict__ pooled, const int* __restrict__ gcnt,
                             const float* __restrict__ fcW2, const float* __restrict__ fcb2,
                             float* __restrict__ out)
{
    int g = blockIdx.x;
    int j = threadIdx.x;
    if (j >= DOUT) return;
    float s = 0.f;
    for (int k = 0; k < NHC; k++) s += pooled[g * NHC + k] * fcW2[k * DOUT + j];
    int c = gcnt[g];
    out[g * DOUT + j] = (c > 0) ? (s / (float)c + fcb2[j]) : 0.f;
}

extern "C" void kernel_launch(void* const* d_in, const int* in_sizes, int n_in,
                              void* d_out, int out_size, void* d_ws, size_t ws_size,
                              hipStream_t stream)
{
    const float* x    = (const float*)d_in[0];
    const int*   ei   = (const int*)  d_in[1];
    const float* ea   = (const float*)d_in[2];
    const int*   bat  = (const int*)  d_in[3];
    const float* W[3]   = {(const float*)d_in[4],  (const float*)d_in[10], (const float*)d_in[16]};
    const float* Asl[3] = {(const float*)d_in[5],  (const float*)d_in[11], (const float*)d_in[17]};
    const float* Adl[3] = {(const float*)d_in[6],  (const float*)d_in[12], (const float*)d_in[18]};
    const float* Wel[3] = {(const float*)d_in[7],  (const float*)d_in[13], (const float*)d_in[19]};
    const float* Ael[3] = {(const float*)d_in[8],  (const float*)d_in[14], (const float*)d_in[20]};
    const float* Bil[3] = {(const float*)d_in[9],  (const float*)d_in[15], (const float*)d_in[21]};
    const float* fcW1 = (const float*)d_in[22];
    const float* fcb1 = (const float*)d_in[23];
    const float* fcW2 = (const float*)d_in[24];
    const float* fcb2 = (const float*)d_in[25];

    // ---- workspace carve (bytes) ----
    char* w = (char*)d_ws;
    float*    h    = (float*)w;        w += (size_t)N_NODES * NHC * 4;
    _Float16* xh   = (_Float16*)w;     w += (size_t)N_NODES * DIN * 2;
    _Float16* xl   = (_Float16*)w;     w += (size_t)N_NODES * DIN * 2;
    _Float16* xbh  = (_Float16*)w;     w += (size_t)N_NODES * NHC * 2;
    _Float16* xbl  = (_Float16*)w;     w += (size_t)N_NODES * NHC * 2;
    float*    asb  = (float*)w;        w += (size_t)N_NODES * 8 * 4;
    float*    adb  = (float*)w;        w += (size_t)N_NODES * 8 * 4;
    float*    MeAll= (float*)w;        w += 120 * 4;
    float*    pooled=(float*)w;        w += (size_t)N_GRAPH * NHC * 4;
    _Float16* W1th = (_Float16*)w;     w += (size_t)NHC * DIN * 2;
    _Float16* W1tl = (_Float16*)w;     w += (size_t)NHC * DIN * 2;
    _Float16* W2th = (_Float16*)w;     w += (size_t)NHC * NHC * 2;
    _Float16* W2tl = (_Float16*)w;     w += (size_t)NHC * NHC * 2;
    _Float16* W3th = (_Float16*)w;     w += (size_t)NHC * NHC * 2;
    _Float16* W3tl = (_Float16*)w;     w += (size_t)NHC * NHC * 2;
    _Float16* F1th = (_Float16*)w;     w += (size_t)NHC * NHC * 2;
    _Float16* F1tl = (_Float16*)w;     w += (size_t)NHC * NHC * 2;
    int* gcnt     = (int*)w;           w += N_GRAPH * 4;
    int* deg      = (int*)w;           w += (size_t)N_NODES * 4;
    int* rowstart = (int*)w;           w += (size_t)(N_NODES + 1) * 4;
    int* cursor   = (int*)w;           w += (size_t)N_NODES * 4;
    int* partial  = (int*)w;           w += 256 * 4;
    w = (char*)(((size_t)w + 15) & ~(size_t)15);
    int2* csr     = (int2*)w;          w += (size_t)N_EDGES * 8;

    const int NB = (N_NODES + 255) / 256;

    prep_kernel<<<(JTOT + 255) / 256, 256, 0, stream>>>(
        x, W[0], W[1], W[2], fcW1,
        xh, xl, W1th, W1tl, W2th, W2tl, W3th, W3tl, F1th, F1tl,
        pooled, deg, gcnt);
    count_hist_kernel<<<(N_EDGES + 255) / 256, 256, 0, stream>>>(ei, bat, deg, gcnt, N_EDGES, N_NODES);
    scan_block_kernel<<<NB, 256, 0, stream>>>(deg, rowstart, partial, N_NODES);
    scan_partial_kernel<<<1, 256, 0, stream>>>(partial, NB);
    scan_add_kernel<<<NB, 256, 0, stream>>>(rowstart, partial, cursor, N_NODES, N_EDGES);
    fill_kernel<<<(N_EDGES + 255) / 256, 256, 0, stream>>>(ei, cursor, csr, N_EDGES);
    me_all_kernel<<<3, 64, 0, stream>>>(Wel[0], Ael[0], Wel[1], Ael[1], Wel[2], Ael[2], MeAll);

    const int Hs[3] = {8, 8, 1};
    const int CL[3] = {5, 5, 8};
    const int Ks[3] = {DIN, NHC, NHC};

    const dim3 ggrid(4, 392);

    const _Float16* curh = xh;
    const _Float16* curl = xl;
    const _Float16* Wth[3] = {W1th, W2th, W3th};
    const _Float16* Wtl[3] = {W1tl, W2tl, W3tl};
    for (int l = 0; l < 3; l++) {
        const int H = Hs[l];
        const bool fuse = (l != 2);
        mfma_gemm_kernel<<<ggrid, 256, 0, stream>>>(
            curh, curl, Wth[l], Wtl[l], nullptr, h,
            fuse ? Asl[l] : nullptr, fuse ? Adl[l] : nullptr, asb, adb,
            nullptr, nullptr,
            N_NODES, Ks[l], 0);
        if (!fuse)
            asd_kernel<<<(N_NODES + 255) / 256, 256, 0, stream>>>(
                h, Asl[l], Adl[l], asb, adb, N_NODES, 1, NHC);
        gat_agg_kernel<<<(N_NODES + 3) / 4, 256, 0, stream>>>(
            rowstart, csr, ea, asb, adb, MeAll + l * 40, h, Bil[l], xbh, xbl, H, CL[l]);
        curh = xbh; curl = xbl;
    }

    // fc1 + fused gelu + per-graph pooling (fc2 commutes with pooling)
    mfma_gemm_kernel<<<ggrid, 256, 0, stream>>>(
        xbh, xbl, F1th, F1tl, fcb1, nullptr,
        nullptr, nullptr, nullptr, nullptr,
        bat, pooled,
        N_NODES, NHC, 3);
    final_kernel<<<N_GRAPH, 64, 0, stream>>>(pooled, gcnt, fcW2, fcb2, (float*)d_out);
}

// Round 12
// 519.858 us; speedup vs baseline: 1.8163x; 1.1210x over previous
//
#include <hip/hip_runtime.h>
#include <math.h>

// GATNet_MLP R12: R11 + h stored as fp16 (hi plane only, 25.6MB vs 51MB fp32).
// gat_agg's random gather was L2-missing and streaming 240MB/dispatch from L3
// (R11 counters); every remaining consumer of h (gather numerator, layer-3 asd)
// tolerates fp16: per-layer output err ~5e-5, alpha err ~1e-4 -> far under the
// 1.24e-4 threshold after 780-node mean pooling. Halves gather bytes.

#define N_NODES 50000
#define N_EDGES 400000
#define N_GRAPH 64
#define DIN     128
#define NHC     256
#define DOUT    32

typedef _Float16 f16x8 __attribute__((ext_vector_type(8)));
typedef _Float16 f16x4 __attribute__((ext_vector_type(4)));
typedef float    f32x4 __attribute__((ext_vector_type(4)));

#define LDP 40   // padded LDS row stride in halfs (80B; kills b128 conflicts)

// ================= fp16x2-split MFMA GEMM, 128x64 tile, pipelined =================
// mode 0: C fp16 [nrow][256]; if asl!=null also per-head a_s/a_d (C=32 layers).
// mode 3: NO C write; v=gelu(v+bias); per-graph pooled sums (batch sorted).
__global__ __launch_bounds__(256) void mfma_gemm_kernel(
    const _Float16* __restrict__ Ah, const _Float16* __restrict__ Al,
    const _Float16* __restrict__ Bh, const _Float16* __restrict__ Bl,
    const float* __restrict__ bias, _Float16* __restrict__ Ch,
    const float* __restrict__ asl, const float* __restrict__ adl,
    float* __restrict__ asb, float* __restrict__ adb,
    const int* __restrict__ batch, float* __restrict__ pooled,
    int nrow, int K, int mode)
{
    __shared__ __align__(16) _Float16 sAh[128][LDP];
    __shared__ __align__(16) _Float16 sAl[128][LDP];
    __shared__ __align__(16) _Float16 sBh[64][LDP];
    __shared__ __align__(16) _Float16 sBl[64][LDP];

    const int tid = threadIdx.x, lane = tid & 63, wid = tid >> 6;
    const int wm = wid & 1, wn = wid >> 1;

    int xt, yt;
    if (gridDim.x == 4) {
        int bid = blockIdx.x + (blockIdx.y << 2);
        yt = (bid >> 5) * 8 + (bid & 7);
        xt = (bid >> 3) & 3;
    } else { xt = blockIdx.x; yt = blockIdx.y; }
    const int row0 = yt * 128, col0 = xt * 64;
    if (row0 >= nrow) return;

    const int frow = lane & 15, fk = (lane >> 4) * 8;
    const int ra = tid >> 2, kq = (tid & 3) * 8;

    f32x4 acc[4][2] = {};
    f16x8 pAh[2], pAl[2], pBh, pBl;

    {
#pragma unroll
        for (int p = 0; p < 2; p++) {
            int gr = row0 + p * 64 + ra;
            long go = (long)gr * K + kq;
            pAh[p] = (gr < nrow) ? *(const f16x8*)(Ah + go) : (f16x8)0;
            pAl[p] = (gr < nrow) ? *(const f16x8*)(Al + go) : (f16x8)0;
        }
        long gob = (long)(col0 + ra) * K + kq;
        pBh = *(const f16x8*)(Bh + gob);
        pBl = *(const f16x8*)(Bl + gob);
    }

    for (int k0 = 0; k0 < K; k0 += 32) {
#pragma unroll
        for (int p = 0; p < 2; p++) {
            *(f16x8*)&sAh[p * 64 + ra][kq] = pAh[p];
            *(f16x8*)&sAl[p * 64 + ra][kq] = pAl[p];
        }
        *(f16x8*)&sBh[ra][kq] = pBh;
        *(f16x8*)&sBl[ra][kq] = pBl;
        __syncthreads();

        if (k0 + 32 < K) {
            int kn = k0 + 32 + kq;
#pragma unroll
            for (int p = 0; p < 2; p++) {
                int gr = row0 + p * 64 + ra;
                long go = (long)gr * K + kn;
                pAh[p] = (gr < nrow) ? *(const f16x8*)(Ah + go) : (f16x8)0;
                pAl[p] = (gr < nrow) ? *(const f16x8*)(Al + go) : (f16x8)0;
            }
            long gob = (long)(col0 + ra) * K + kn;
            pBh = *(const f16x8*)(Bh + gob);
            pBl = *(const f16x8*)(Bl + gob);
        }

        f16x8 bh[2], bl[2];
#pragma unroll
        for (int nt = 0; nt < 2; nt++) {
            bh[nt] = *(const f16x8*)&sBh[wn * 32 + nt * 16 + frow][fk];
            bl[nt] = *(const f16x8*)&sBl[wn * 32 + nt * 16 + frow][fk];
        }
#pragma unroll
        for (int mt = 0; mt < 4; mt++) {
            f16x8 ah = *(const f16x8*)&sAh[wm * 64 + mt * 16 + frow][fk];
            f16x8 al = *(const f16x8*)&sAl[wm * 64 + mt * 16 + frow][fk];
#pragma unroll
            for (int nt = 0; nt < 2; nt++) {
                acc[mt][nt] = __builtin_amdgcn_mfma_f32_16x16x32_f16(ah, bh[nt], acc[mt][nt], 0, 0, 0);
                acc[mt][nt] = __builtin_amdgcn_mfma_f32_16x16x32_f16(ah, bl[nt], acc[mt][nt], 0, 0, 0);
                acc[mt][nt] = __builtin_amdgcn_mfma_f32_16x16x32_f16(al, bh[nt], acc[mt][nt], 0, 0, 0);
            }
        }
        __syncthreads();
    }

    const int crow0 = row0 + wm * 64 + (lane >> 4) * 4;
    const int ccol0 = col0 + wn * 32 + (lane & 15);

    if (mode == 0) {
#pragma unroll
        for (int mt = 0; mt < 4; mt++)
#pragma unroll
            for (int nt = 0; nt < 2; nt++) {
                int col = ccol0 + nt * 16;
#pragma unroll
                for (int r = 0; r < 4; r++) {
                    int row = crow0 + mt * 16 + r;
                    if (row < nrow) Ch[(long)row * 256 + col] = (_Float16)acc[mt][nt][r];
                }
            }
        // fused a_s/a_d from fp32 acc regs (C=32 layers): plain stores.
        if (asl != nullptr) {
            const float asl0 = asl[ccol0], asl1 = asl[ccol0 + 16];
            const float adl0 = adl[ccol0], adl1 = adl[ccol0 + 16];
            const int headw = (col0 + wn * 32) >> 5;
#pragma unroll
            for (int mt = 0; mt < 4; mt++) {
#pragma unroll
                for (int r = 0; r < 4; r++) {
                    float s = acc[mt][0][r] * asl0 + acc[mt][1][r] * asl1;
                    float d = acc[mt][0][r] * adl0 + acc[mt][1][r] * adl1;
                    s += __shfl_xor(s, 1); s += __shfl_xor(s, 2);
                    s += __shfl_xor(s, 4); s += __shfl_xor(s, 8);
                    d += __shfl_xor(d, 1); d += __shfl_xor(d, 2);
                    d += __shfl_xor(d, 4); d += __shfl_xor(d, 8);
                    if ((lane & 15) == 0) {
                        int row = crow0 + mt * 16 + r;
                        if (row < nrow) {
                            asb[row * 8 + headw] = s;
                            adb[row * 8 + headw] = d;
                        }
                    }
                }
            }
        }
    } else {
        // mode 3: gelu(v+bias) -> per-graph pooled sums, register pre-accum (R11).
        float* pool = (float*)&sAh[0][0];            // 16*64 floats = 4KB
        const int g0 = batch[row0];
        const int rlast = (row0 + 127 < nrow) ? row0 + 127 : nrow - 1;
        const int gspan = batch[rlast] - g0 + 1;
        const bool fits = (gspan <= 16);
        for (int i = tid; i < 16 * 64; i += 256) pool[i] = 0.f;
        __syncthreads();

        const float b0 = bias[ccol0], b1 = bias[ccol0 + 16];
        const int lc0 = ccol0 - col0, lc1 = lc0 + 16;
        float sum0 = 0.f, sum1 = 0.f;
        int curg = -1;
#pragma unroll
        for (int mt = 0; mt < 4; mt++) {
#pragma unroll
            for (int r = 0; r < 4; r++) {
                int row = crow0 + mt * 16 + r;
                if (row >= nrow) continue;
                int g = batch[row];
                if (g != curg) {
                    if (curg >= 0) {
                        if (fits) {
                            atomicAdd(&pool[(curg - g0) * 64 + lc0], sum0);
                            atomicAdd(&pool[(curg - g0) * 64 + lc1], sum1);
                        } else {
                            atomicAdd(&pooled[curg * 256 + ccol0], sum0);
                            atomicAdd(&pooled[curg * 256 + ccol0 + 16], sum1);
                        }
                    }
                    curg = g; sum0 = 0.f; sum1 = 0.f;
                }
                float v0 = acc[mt][0][r] + b0;
                float v1 = acc[mt][1][r] + b1;
                sum0 += 0.5f * v0 * (1.f + erff(v0 * 0.7071067811865475f));
                sum1 += 0.5f * v1 * (1.f + erff(v1 * 0.7071067811865475f));
            }
        }
        if (curg >= 0) {
            if (fits) {
                atomicAdd(&pool[(curg - g0) * 64 + lc0], sum0);
                atomicAdd(&pool[(curg - g0) * 64 + lc1], sum1);
            } else {
                atomicAdd(&pooled[curg * 256 + ccol0], sum0);
                atomicAdd(&pooled[curg * 256 + ccol0 + 16], sum1);
            }
        }
        __syncthreads();
        if (fits) {
            for (int i = tid; i < gspan * 64; i += 256) {
                float val = pool[i];
                if (val != 0.f)
                    atomicAdd(&pooled[(g0 + (i >> 6)) * 256 + col0 + (i & 63)], val);
            }
        }
    }
}

// ================= single prep kernel =================
#define J0 1600000
#define J1 32768
#define J2 65536
#define J3 65536
#define J4 65536
#define J5 16384
#define J6 N_NODES
#define J7 64
#define JTOT (J0+J1+J2+J3+J4+J5+J6+J7)

__device__ __forceinline__ void tsplit_one(const float* W, _Float16* Bh, _Float16* Bl,
                                           int id, int K, int realN)
{
    int n = id / K, k = id - n * K;
    float v = W[(long)k * realN + n];
    _Float16 h = (_Float16)v;
    Bh[id] = h;
    Bl[id] = (_Float16)(v - (float)h);
}

__global__ __launch_bounds__(256) void prep_kernel(
    const float* __restrict__ x,
    const float* __restrict__ W1, const float* __restrict__ W2, const float* __restrict__ W3,
    const float* __restrict__ F1,
    _Float16* __restrict__ xh, _Float16* __restrict__ xl,
    _Float16* __restrict__ W1th, _Float16* __restrict__ W1tl,
    _Float16* __restrict__ W2th, _Float16* __restrict__ W2tl,
    _Float16* __restrict__ W3th, _Float16* __restrict__ W3tl,
    _Float16* __restrict__ F1th, _Float16* __restrict__ F1tl,
    float* __restrict__ pooled, int* __restrict__ deg, int* __restrict__ gcnt)
{
    int idx = blockIdx.x * 256 + threadIdx.x;
    if (idx < J0) {
        float4 v = ((const float4*)x)[idx];
        f16x4 h, l;
        h[0] = (_Float16)v.x; l[0] = (_Float16)(v.x - (float)h[0]);
        h[1] = (_Float16)v.y; l[1] = (_Float16)(v.y - (float)h[1]);
        h[2] = (_Float16)v.z; l[2] = (_Float16)(v.z - (float)h[2]);
        h[3] = (_Float16)v.w; l[3] = (_Float16)(v.w - (float)h[3]);
        *(f16x4*)(xh + (long)idx * 4) = h;
        *(f16x4*)(xl + (long)idx * 4) = l;
        return;
    }
    idx -= J0;
    if (idx < J1) { tsplit_one(W1, W1th, W1tl, idx, DIN, NHC); return; }
    idx -= J1;
    if (idx < J2) { tsplit_one(W2, W2th, W2tl, idx, NHC, NHC); return; }
    idx -= J2;
    if (idx < J3) { tsplit_one(W3, W3th, W3tl, idx, NHC, NHC); return; }
    idx -= J3;
    if (idx < J4) { tsplit_one(F1, F1th, F1tl, idx, NHC, NHC); return; }
    idx -= J4;
    if (idx < J5) { pooled[idx] = 0.f; return; }
    idx -= J5;
    if (idx < J6) { deg[idx] = 0; return; }
    idx -= J6;
    if (idx < J7) { gcnt[idx] = 0; return; }
}

// -------- all 3 layers' Me[5][H] in one launch --------
__global__ void me_all_kernel(
    const float* __restrict__ We1, const float* __restrict__ ae1,
    const float* __restrict__ We2, const float* __restrict__ ae2,
    const float* __restrict__ We3, const float* __restrict__ ae3,
    float* __restrict__ MeAll)
{
    int l = blockIdx.x;
    const float* We = (l == 0) ? We1 : (l == 1) ? We2 : We3;
    const float* ae = (l == 0) ? ae1 : (l == 1) ? ae2 : ae3;
    int H = (l == 2) ? 1 : 8, C = (l == 2) ? 256 : 32;
    int t = threadIdx.x;
    if (t >= 5 * H) return;
    int j = t / H, hh = t - j * H;
    float s = 0.f;
    for (int c = 0; c < C; c++) s += We[j * NHC + hh * C + c] * ae[hh * C + c];
    MeAll[l * 40 + j * H + hh] = s;
}

// -------- asd (layer 3 only: H=1, C=256), fp16 h --------
__global__ __launch_bounds__(256) void asd_kernel(
    const _Float16* __restrict__ h, const float* __restrict__ atts, const float* __restrict__ attd,
    float* __restrict__ asb, float* __restrict__ adb, int total)
{
    int n = blockIdx.x * 256 + threadIdx.x;
    if (n >= total) return;
    const f16x8* hp = (const f16x8*)(h + (long)n * NHC);
    const float4* sp = (const float4*)atts;
    const float4* dp = (const float4*)attd;
    float ss = 0.f, dd = 0.f;
    for (int c = 0; c < NHC / 8; c++) {
        f16x8 hv = hp[c];
        float4 s1 = sp[2 * c], s2 = sp[2 * c + 1];
        float4 d1 = dp[2 * c], d2 = dp[2 * c + 1];
        ss += (float)hv[0] * s1.x + (float)hv[1] * s1.y + (float)hv[2] * s1.z + (float)hv[3] * s1.w
            + (float)hv[4] * s2.x + (float)hv[5] * s2.y + (float)hv[6] * s2.z + (float)hv[7] * s2.w;
        dd += (float)hv[0] * d1.x + (float)hv[1] * d1.y + (float)hv[2] * d1.z + (float)hv[3] * d1.w
            + (float)hv[4] * d2.x + (float)hv[5] * d2.y + (float)hv[6] * d2.z + (float)hv[7] * d2.w;
    }
    asb[n * 8] = ss; adb[n * 8] = dd;     // H=1: stride-8 slot 0 (gat_agg heff=0)
}

// ================= CSR build =================
__global__ __launch_bounds__(256) void count_hist_kernel(
    const int* __restrict__ ei, const int* __restrict__ batch,
    int* __restrict__ deg, int* __restrict__ gcnt, int E, int N)
{
    __shared__ int hist[N_GRAPH];
    int t = threadIdx.x;
    if (t < N_GRAPH) hist[t] = 0;
    __syncthreads();
    int i = blockIdx.x * 256 + t;
    if (i < E) atomicAdd(&deg[ei[E + i]], 1);
    if (i < N) atomicAdd(&hist[batch[i]], 1);
    __syncthreads();
    if (t < N_GRAPH && hist[t] > 0) atomicAdd(&gcnt[t], hist[t]);
}

__global__ __launch_bounds__(256) void scan_block_kernel(
    const int* __restrict__ deg, int* __restrict__ rowstart, int* __restrict__ partial, int n)
{
    __shared__ int s[256];
    int i = blockIdx.x * 256 + threadIdx.x;
    int v = (i < n) ? deg[i] : 0;
    s[threadIdx.x] = v;
    __syncthreads();
    for (int off = 1; off < 256; off <<= 1) {
        int t = (threadIdx.x >= off) ? s[threadIdx.x - off] : 0;
        __syncthreads();
        s[threadIdx.x] += t;
        __syncthreads();
    }
    if (i < n) rowstart[i] = s[threadIdx.x] - v;
    if (threadIdx.x == 255) partial[blockIdx.x] = s[255];
}

__global__ __launch_bounds__(256) void scan_partial_kernel(int* __restrict__ partial, int nb)
{
    __shared__ int s[256];
    int v = (threadIdx.x < nb) ? partial[threadIdx.x] : 0;
    s[threadIdx.x] = v;
    __syncthreads();
    for (int off = 1; off < 256; off <<= 1) {
        int t = (threadIdx.x >= off) ? s[threadIdx.x - off] : 0;
        __syncthreads();
        s[threadIdx.x] += t;
        __syncthreads();
    }
    if (threadIdx.x < nb) partial[threadIdx.x] = s[threadIdx.x] - v;
}

__global__ __launch_bounds__(256) void scan_add_kernel(
    int* __restrict__ rowstart, const int* __restrict__ partial, int* __restrict__ cursor,
    int n, int E)
{
    int i = blockIdx.x * 256 + threadIdx.x;
    if (i < n) {
        int v = rowstart[i] + partial[blockIdx.x];
        rowstart[i] = v;
        cursor[i] = v;
    }
    if (i == 0) rowstart[n] = E;
}

__global__ __launch_bounds__(256) void fill_kernel(
    const int* __restrict__ ei, int* __restrict__ cursor, int2* __restrict__ csr, int E)
{
    int e = blockIdx.x * 256 + threadIdx.x;
    if (e >= E) return;
    int dst = ei[E + e];
    int pos = atomicAdd(&cursor[dst], 1);
    csr[pos] = make_int2(ei[e], e);
}

// ========== fused GAT aggregation, fp16 h gather ==========
__global__ __launch_bounds__(256) void gat_agg_kernel(
    const int* __restrict__ rowstart, const int2* __restrict__ csr,
    const float* __restrict__ ea, const float* __restrict__ asb,
    const float* __restrict__ adb, const float* __restrict__ MeL,
    const _Float16* __restrict__ h, const float* __restrict__ bias,
    _Float16* __restrict__ Oh, _Float16* __restrict__ Ol, int H, int clog2)
{
    int node = blockIdx.x * 4 + (threadIdx.x >> 6);
    if (node >= N_NODES) return;
    int lane = threadIdx.x & 63;
    int c0 = lane * 4;
    int hc = c0 >> clog2;
    int heff = lane & (H - 1);
    float Mh0 = MeL[0 * H + heff], Mh1 = MeL[1 * H + heff], Mh2 = MeL[2 * H + heff],
          Mh3 = MeL[3 * H + heff], Mh4 = MeL[4 * H + heff];
    float adn = adb[node * 8 + heff];
    int beg = rowstart[node], end = rowstart[node + 1];
    float ax = 0.f, ay = 0.f, az = 0.f, aw = 0.f, den = 0.f;
    for (int i = beg; i < end; i += 8) {
        int idx = i + (lane >> 3);
        if (idx >= end) idx = end - 1;
        int2 se = csr[idx];
        const float* eap = ea + (long)se.y * 5;
        float aeh = eap[0] * Mh0 + eap[1] * Mh1 + eap[2] * Mh2 + eap[3] * Mh3 + eap[4] * Mh4;
        float al = asb[se.x * 8 + heff] + adn + aeh;
        al = fmaxf(al, 0.2f * al);
        float pv = expf(al);
        int nrem = end - i;
#pragma unroll
        for (int j = 0; j < 8; j++) {
            if (j >= nrem) break;
            float pj  = __shfl(pv, j * 8 + hc);
            int  srcj = __shfl(se.x, j * 8);
            const f16x4 hv = *(const f16x4*)(h + (long)srcj * NHC + c0);
            den += pj;
            ax += pj * (float)hv[0]; ay += pj * (float)hv[1];
            az += pj * (float)hv[2]; aw += pj * (float)hv[3];
        }
    }
    float w = 1.0f / (den + 1e-16f);
    const float4 bv = *(const float4*)(bias + c0);
    float4 v;
    v.x = ax * w + bv.x;  v.y = ay * w + bv.y;
    v.z = az * w + bv.z;  v.w = aw * w + bv.w;
    v.x = (v.x > 0.f) ? v.x : expm1f(v.x);
    v.y = (v.y > 0.f) ? v.y : expm1f(v.y);
    v.z = (v.z > 0.f) ? v.z : expm1f(v.z);
    v.w = (v.w > 0.f) ? v.w : expm1f(v.w);
    f16x4 oh, ol;
    oh[0] = (_Float16)v.x; ol[0] = (_Float16)(v.x - (float)oh[0]);
    oh[1] = (_Float16)v.y; ol[1] = (_Float16)(v.y - (float)oh[1]);
    oh[2] = (_Float16)v.z; ol[2] = (_Float16)(v.z - (float)oh[2]);
    oh[3] = (_Float16)v.w; ol[3] = (_Float16)(v.w - (float)oh[3]);
    *(f16x4*)(Oh + (long)node * NHC + c0) = oh;
    *(f16x4*)(Ol + (long)node * NHC + c0) = ol;
}

// ================= final: out[g,:] = (pooled[g,:]@fcW2)/cnt + fcb2 =================
__global__ void final_kernel(const float* __restrict__ pooled, const int* __restrict__ gcnt,
                             const float* __restrict__ fcW2, const float* __restrict__ fcb2,
                             float* __restrict__ out)
{
    int g = blockIdx.x;
    int j = threadIdx.x;
    if (j >= DOUT) return;
    float s = 0.f;
    for (int k = 0; k < NHC; k++) s += pooled[g * NHC + k] * fcW2[k * DOUT + j];
    int c = gcnt[g];
    out[g * DOUT + j] = (c > 0) ? (s / (float)c + fcb2[j]) : 0.f;
}

extern "C" void kernel_launch(void* const* d_in, const int* in_sizes, int n_in,
                              void* d_out, int out_size, void* d_ws, size_t ws_size,
                              hipStream_t stream)
{
    const float* x    = (const float*)d_in[0];
    const int*   ei   = (const int*)  d_in[1];
    const float* ea   = (const float*)d_in[2];
    const int*   bat  = (const int*)  d_in[3];
    const float* W[3]   = {(const float*)d_in[4],  (const float*)d_in[10], (const float*)d_in[16]};
    const float* Asl[3] = {(const float*)d_in[5],  (const float*)d_in[11], (const float*)d_in[17]};
    const float* Adl[3] = {(const float*)d_in[6],  (const float*)d_in[12], (const float*)d_in[18]};
    const float* Wel[3] = {(const float*)d_in[7],  (const float*)d_in[13], (const float*)d_in[19]};
    const float* Ael[3] = {(const float*)d_in[8],  (const float*)d_in[14], (const float*)d_in[20]};
    const float* Bil[3] = {(const float*)d_in[9],  (const float*)d_in[15], (const float*)d_in[21]};
    const float* fcW1 = (const float*)d_in[22];
    const float* fcb1 = (const float*)d_in[23];
    const float* fcW2 = (const float*)d_in[24];
    const float* fcb2 = (const float*)d_in[25];

    // ---- workspace carve (bytes) ----
    char* w = (char*)d_ws;
    _Float16* h    = (_Float16*)w;     w += (size_t)N_NODES * NHC * 2;   // fp16 h
    _Float16* xh   = (_Float16*)w;     w += (size_t)N_NODES * DIN * 2;
    _Float16* xl   = (_Float16*)w;     w += (size_t)N_NODES * DIN * 2;
    _Float16* xbh  = (_Float16*)w;     w += (size_t)N_NODES * NHC * 2;
    _Float16* xbl  = (_Float16*)w;     w += (size_t)N_NODES * NHC * 2;
    float*    asb  = (float*)w;        w += (size_t)N_NODES * 8 * 4;
    float*    adb  = (float*)w;        w += (size_t)N_NODES * 8 * 4;
    float*    MeAll= (float*)w;        w += 120 * 4;
    float*    pooled=(float*)w;        w += (size_t)N_GRAPH * NHC * 4;
    _Float16* W1th = (_Float16*)w;     w += (size_t)NHC * DIN * 2;
    _Float16* W1tl = (_Float16*)w;     w += (size_t)NHC * DIN * 2;
    _Float16* W2th = (_Float16*)w;     w += (size_t)NHC * NHC * 2;
    _Float16* W2tl = (_Float16*)w;     w += (size_t)NHC * NHC * 2;
    _Float16* W3th = (_Float16*)w;     w += (size_t)NHC * NHC * 2;
    _Float16* W3tl = (_Float16*)w;     w += (size_t)NHC * NHC * 2;
    _Float16* F1th = (_Float16*)w;     w += (size_t)NHC * NHC * 2;
    _Float16* F1tl = (_Float16*)w;     w += (size_t)NHC * NHC * 2;
    int* gcnt     = (int*)w;           w += N_GRAPH * 4;
    int* deg      = (int*)w;           w += (size_t)N_NODES * 4;
    int* rowstart = (int*)w;           w += (size_t)(N_NODES + 1) * 4;
    int* cursor   = (int*)w;           w += (size_t)N_NODES * 4;
    int* partial  = (int*)w;           w += 256 * 4;
    w = (char*)(((size_t)w + 15) & ~(size_t)15);
    int2* csr     = (int2*)w;          w += (size_t)N_EDGES * 8;

    const int NB = (N_NODES + 255) / 256;

    prep_kernel<<<(JTOT + 255) / 256, 256, 0, stream>>>(
        x, W[0], W[1], W[2], fcW1,
        xh, xl, W1th, W1tl, W2th, W2tl, W3th, W3tl, F1th, F1tl,
        pooled, deg, gcnt);
    count_hist_kernel<<<(N_EDGES + 255) / 256, 256, 0, stream>>>(ei, bat, deg, gcnt, N_EDGES, N_NODES);
    scan_block_kernel<<<NB, 256, 0, stream>>>(deg, rowstart, partial, N_NODES);
    scan_partial_kernel<<<1, 256, 0, stream>>>(partial, NB);
    scan_add_kernel<<<NB, 256, 0, stream>>>(rowstart, partial, cursor, N_NODES, N_EDGES);
    fill_kernel<<<(N_EDGES + 255) / 256, 256, 0, stream>>>(ei, cursor, csr, N_EDGES);
    me_all_kernel<<<3, 64, 0, stream>>>(Wel[0], Ael[0], Wel[1], Ael[1], Wel[2], Ael[2], MeAll);

    const int Hs[3] = {8, 8, 1};
    const int CL[3] = {5, 5, 8};
    const int Ks[3] = {DIN, NHC, NHC};

    const dim3 ggrid(4, 392);

    const _Float16* curh = xh;
    const _Float16* curl = xl;
    const _Float16* Wth[3] = {W1th, W2th, W3th};
    const _Float16* Wtl[3] = {W1tl, W2tl, W3tl};
    for (int l = 0; l < 3; l++) {
        const int H = Hs[l];
        const bool fuse = (l != 2);
        mfma_gemm_kernel<<<ggrid, 256, 0, stream>>>(
            curh, curl, Wth[l], Wtl[l], nullptr, h,
            fuse ? Asl[l] : nullptr, fuse ? Adl[l] : nullptr, asb, adb,
            nullptr, nullptr,
            N_NODES, Ks[l], 0);
        if (!fuse)
            asd_kernel<<<(N_NODES + 255) / 256, 256, 0, stream>>>(
                h, Asl[l], Adl[l], asb, adb, N_NODES);
        gat_agg_kernel<<<(N_NODES + 3) / 4, 256, 0, stream>>>(
            rowstart, csr, ea, asb, adb, MeAll + l * 40, h, Bil[l], xbh, xbl, H, CL[l]);
        curh = xbh; curl = xbl;
    }

    // fc1 + fused gelu + per-graph pooling (fc2 commutes with pooling)
    mfma_gemm_kernel<<<ggrid, 256, 0, stream>>>(
        xbh, xbl, F1th, F1tl, fcb1, nullptr,
        nullptr, nullptr, nullptr, nullptr,
        bat, pooled,
        N_NODES, NHC, 3);
    final_kernel<<<N_GRAPH, 64, 0, stream>>>(pooled, gcnt, fcW2, fcb2, (float*)d_out);
}

// Round 13
// 470.113 us; speedup vs baseline: 2.0085x; 1.1058x over previous
//
#include <hip/hip_runtime.h>
#include <math.h>

// GATNet_MLP R13: R12 + A-side lo plane dropped (A inputs plain fp16; weights
// keep hi+lo split). a*b = ah*(bh+bl): 2 MFMAs/product instead of 3 (-33% matrix
// work), A staging + LDS halved (20.5KB -> 7 blocks/CU), gat_agg writes only the
// hi plane (WRITE 50->25MB). Error: A-rounding ~4.9e-4 rel = same mechanism as
// the h-fp16 store that produced absmax 3.05e-5; predict ~6-9e-5 < 1.24e-4.

#define N_NODES 50000
#define N_EDGES 400000
#define N_GRAPH 64
#define DIN     128
#define NHC     256
#define DOUT    32

typedef _Float16 f16x8 __attribute__((ext_vector_type(8)));
typedef _Float16 f16x4 __attribute__((ext_vector_type(4)));
typedef float    f32x4 __attribute__((ext_vector_type(4)));

#define LDP 40   // padded LDS row stride in halfs (80B; kills b128 conflicts)

// ================= fp16-A x fp16x2-B MFMA GEMM, 128x64 tile, pipelined ==========
// mode 0: C fp16 [nrow][256]; if asl!=null also per-head a_s/a_d (C=32 layers).
// mode 3: NO C write; v=gelu(v+bias); per-graph pooled sums (batch sorted).
__global__ __launch_bounds__(256) void mfma_gemm_kernel(
    const _Float16* __restrict__ Ah,
    const _Float16* __restrict__ Bh, const _Float16* __restrict__ Bl,
    const float* __restrict__ bias, _Float16* __restrict__ Ch,
    const float* __restrict__ asl, const float* __restrict__ adl,
    float* __restrict__ asb, float* __restrict__ adb,
    const int* __restrict__ batch, float* __restrict__ pooled,
    int nrow, int K, int mode)
{
    __shared__ __align__(16) _Float16 sAh[128][LDP];
    __shared__ __align__(16) _Float16 sBh[64][LDP];
    __shared__ __align__(16) _Float16 sBl[64][LDP];

    const int tid = threadIdx.x, lane = tid & 63, wid = tid >> 6;
    const int wm = wid & 1, wn = wid >> 1;

    int xt, yt;
    if (gridDim.x == 4) {
        int bid = blockIdx.x + (blockIdx.y << 2);
        yt = (bid >> 5) * 8 + (bid & 7);
        xt = (bid >> 3) & 3;
    } else { xt = blockIdx.x; yt = blockIdx.y; }
    const int row0 = yt * 128, col0 = xt * 64;
    if (row0 >= nrow) return;

    const int frow = lane & 15, fk = (lane >> 4) * 8;
    const int ra = tid >> 2, kq = (tid & 3) * 8;

    f32x4 acc[4][2] = {};
    f16x8 pAh[2], pBh, pBl;

    {
#pragma unroll
        for (int p = 0; p < 2; p++) {
            int gr = row0 + p * 64 + ra;
            pAh[p] = (gr < nrow) ? *(const f16x8*)(Ah + (long)gr * K + kq) : (f16x8)0;
        }
        long gob = (long)(col0 + ra) * K + kq;
        pBh = *(const f16x8*)(Bh + gob);
        pBl = *(const f16x8*)(Bl + gob);
    }

    for (int k0 = 0; k0 < K; k0 += 32) {
#pragma unroll
        for (int p = 0; p < 2; p++)
            *(f16x8*)&sAh[p * 64 + ra][kq] = pAh[p];
        *(f16x8*)&sBh[ra][kq] = pBh;
        *(f16x8*)&sBl[ra][kq] = pBl;
        __syncthreads();

        if (k0 + 32 < K) {
            int kn = k0 + 32 + kq;
#pragma unroll
            for (int p = 0; p < 2; p++) {
                int gr = row0 + p * 64 + ra;
                pAh[p] = (gr < nrow) ? *(const f16x8*)(Ah + (long)gr * K + kn) : (f16x8)0;
            }
            long gob = (long)(col0 + ra) * K + kn;
            pBh = *(const f16x8*)(Bh + gob);
            pBl = *(const f16x8*)(Bl + gob);
        }

        f16x8 bh[2], bl[2];
#pragma unroll
        for (int nt = 0; nt < 2; nt++) {
            bh[nt] = *(const f16x8*)&sBh[wn * 32 + nt * 16 + frow][fk];
            bl[nt] = *(const f16x8*)&sBl[wn * 32 + nt * 16 + frow][fk];
        }
#pragma unroll
        for (int mt = 0; mt < 4; mt++) {
            f16x8 ah = *(const f16x8*)&sAh[wm * 64 + mt * 16 + frow][fk];
#pragma unroll
            for (int nt = 0; nt < 2; nt++) {
                acc[mt][nt] = __builtin_amdgcn_mfma_f32_16x16x32_f16(ah, bh[nt], acc[mt][nt], 0, 0, 0);
                acc[mt][nt] = __builtin_amdgcn_mfma_f32_16x16x32_f16(ah, bl[nt], acc[mt][nt], 0, 0, 0);
            }
        }
        __syncthreads();
    }

    const int crow0 = row0 + wm * 64 + (lane >> 4) * 4;
    const int ccol0 = col0 + wn * 32 + (lane & 15);

    if (mode == 0) {
#pragma unroll
        for (int mt = 0; mt < 4; mt++)
#pragma unroll
            for (int nt = 0; nt < 2; nt++) {
                int col = ccol0 + nt * 16;
#pragma unroll
                for (int r = 0; r < 4; r++) {
                    int row = crow0 + mt * 16 + r;
                    if (row < nrow) Ch[(long)row * 256 + col] = (_Float16)acc[mt][nt][r];
                }
            }
        // fused a_s/a_d from fp32 acc regs (C=32 layers): plain stores.
        if (asl != nullptr) {
            const float asl0 = asl[ccol0], asl1 = asl[ccol0 + 16];
            const float adl0 = adl[ccol0], adl1 = adl[ccol0 + 16];
            const int headw = (col0 + wn * 32) >> 5;
#pragma unroll
            for (int mt = 0; mt < 4; mt++) {
#pragma unroll
                for (int r = 0; r < 4; r++) {
                    float s = acc[mt][0][r] * asl0 + acc[mt][1][r] * asl1;
                    float d = acc[mt][0][r] * adl0 + acc[mt][1][r] * adl1;
                    s += __shfl_xor(s, 1); s += __shfl_xor(s, 2);
                    s += __shfl_xor(s, 4); s += __shfl_xor(s, 8);
                    d += __shfl_xor(d, 1); d += __shfl_xor(d, 2);
                    d += __shfl_xor(d, 4); d += __shfl_xor(d, 8);
                    if ((lane & 15) == 0) {
                        int row = crow0 + mt * 16 + r;
                        if (row < nrow) {
                            asb[row * 8 + headw] = s;
                            adb[row * 8 + headw] = d;
                        }
                    }
                }
            }
        }
    } else {
        // mode 3: gelu(v+bias) -> per-graph pooled sums, register pre-accum (R11).
        float* pool = (float*)&sAh[0][0];            // 16*64 floats = 4KB
        const int g0 = batch[row0];
        const int rlast = (row0 + 127 < nrow) ? row0 + 127 : nrow - 1;
        const int gspan = batch[rlast] - g0 + 1;
        const bool fits = (gspan <= 16);
        for (int i = tid; i < 16 * 64; i += 256) pool[i] = 0.f;
        __syncthreads();

        const float b0 = bias[ccol0], b1 = bias[ccol0 + 16];
        const int lc0 = ccol0 - col0, lc1 = lc0 + 16;
        float sum0 = 0.f, sum1 = 0.f;
        int curg = -1;
#pragma unroll
        for (int mt = 0; mt < 4; mt++) {
#pragma unroll
            for (int r = 0; r < 4; r++) {
                int row = crow0 + mt * 16 + r;
                if (row >= nrow) continue;
                int g = batch[row];
                if (g != curg) {
                    if (curg >= 0) {
                        if (fits) {
                            atomicAdd(&pool[(curg - g0) * 64 + lc0], sum0);
                            atomicAdd(&pool[(curg - g0) * 64 + lc1], sum1);
                        } else {
                            atomicAdd(&pooled[curg * 256 + ccol0], sum0);
                            atomicAdd(&pooled[curg * 256 + ccol0 + 16], sum1);
                        }
                    }
                    curg = g; sum0 = 0.f; sum1 = 0.f;
                }
                float v0 = acc[mt][0][r] + b0;
                float v1 = acc[mt][1][r] + b1;
                sum0 += 0.5f * v0 * (1.f + erff(v0 * 0.7071067811865475f));
                sum1 += 0.5f * v1 * (1.f + erff(v1 * 0.7071067811865475f));
            }
        }
        if (curg >= 0) {
            if (fits) {
                atomicAdd(&pool[(curg - g0) * 64 + lc0], sum0);
                atomicAdd(&pool[(curg - g0) * 64 + lc1], sum1);
            } else {
                atomicAdd(&pooled[curg * 256 + ccol0], sum0);
                atomicAdd(&pooled[curg * 256 + ccol0 + 16], sum1);
            }
        }
        __syncthreads();
        if (fits) {
            for (int i = tid; i < gspan * 64; i += 256) {
                float val = pool[i];
                if (val != 0.f)
                    atomicAdd(&pooled[(g0 + (i >> 6)) * 256 + col0 + (i & 63)], val);
            }
        }
    }
}

// ================= single prep kernel =================
#define J0 1600000                       // x convert (float4 units): N*DIN/4
#define J1 32768                         // W1 tsplit (256 x 128)
#define J2 65536                         // W2
#define J3 65536                         // W3
#define J4 65536                         // fcW1
#define J5 16384                         // zero pooled (64*256)
#define J6 N_NODES                       // zero deg
#define J7 64                            // zero gcnt
#define JTOT (J0+J1+J2+J3+J4+J5+J6+J7)

__device__ __forceinline__ void tsplit_one(const float* W, _Float16* Bh, _Float16* Bl,
                                           int id, int K, int realN)
{
    int n = id / K, k = id - n * K;
    float v = W[(long)k * realN + n];
    _Float16 h = (_Float16)v;
    Bh[id] = h;
    Bl[id] = (_Float16)(v - (float)h);
}

__global__ __launch_bounds__(256) void prep_kernel(
    const float* __restrict__ x,
    const float* __restrict__ W1, const float* __restrict__ W2, const float* __restrict__ W3,
    const float* __restrict__ F1,
    _Float16* __restrict__ xh,
    _Float16* __restrict__ W1th, _Float16* __restrict__ W1tl,
    _Float16* __restrict__ W2th, _Float16* __restrict__ W2tl,
    _Float16* __restrict__ W3th, _Float16* __restrict__ W3tl,
    _Float16* __restrict__ F1th, _Float16* __restrict__ F1tl,
    float* __restrict__ pooled, int* __restrict__ deg, int* __restrict__ gcnt)
{
    int idx = blockIdx.x * 256 + threadIdx.x;
    if (idx < J0) {
        float4 v = ((const float4*)x)[idx];
        f16x4 h;
        h[0] = (_Float16)v.x; h[1] = (_Float16)v.y;
        h[2] = (_Float16)v.z; h[3] = (_Float16)v.w;
        *(f16x4*)(xh + (long)idx * 4) = h;
        return;
    }
    idx -= J0;
    if (idx < J1) { tsplit_one(W1, W1th, W1tl, idx, DIN, NHC); return; }
    idx -= J1;
    if (idx < J2) { tsplit_one(W2, W2th, W2tl, idx, NHC, NHC); return; }
    idx -= J2;
    if (idx < J3) { tsplit_one(W3, W3th, W3tl, idx, NHC, NHC); return; }
    idx -= J3;
    if (idx < J4) { tsplit_one(F1, F1th, F1tl, idx, NHC, NHC); return; }
    idx -= J4;
    if (idx < J5) { pooled[idx] = 0.f; return; }
    idx -= J5;
    if (idx < J6) { deg[idx] = 0; return; }
    idx -= J6;
    if (idx < J7) { gcnt[idx] = 0; return; }
}

// -------- all 3 layers' Me[5][H] in one launch --------
__global__ void me_all_kernel(
    const float* __restrict__ We1, const float* __restrict__ ae1,
    const float* __restrict__ We2, const float* __restrict__ ae2,
    const float* __restrict__ We3, const float* __restrict__ ae3,
    float* __restrict__ MeAll)
{
    int l = blockIdx.x;
    const float* We = (l == 0) ? We1 : (l == 1) ? We2 : We3;
    const float* ae = (l == 0) ? ae1 : (l == 1) ? ae2 : ae3;
    int H = (l == 2) ? 1 : 8, C = (l == 2) ? 256 : 32;
    int t = threadIdx.x;
    if (t >= 5 * H) return;
    int j = t / H, hh = t - j * H;
    float s = 0.f;
    for (int c = 0; c < C; c++) s += We[j * NHC + hh * C + c] * ae[hh * C + c];
    MeAll[l * 40 + j * H + hh] = s;
}

// -------- asd (layer 3 only: H=1, C=256), fp16 h --------
__global__ __launch_bounds__(256) void asd_kernel(
    const _Float16* __restrict__ h, const float* __restrict__ atts, const float* __restrict__ attd,
    float* __restrict__ asb, float* __restrict__ adb, int total)
{
    int n = blockIdx.x * 256 + threadIdx.x;
    if (n >= total) return;
    const f16x8* hp = (const f16x8*)(h + (long)n * NHC);
    const float4* sp = (const float4*)atts;
    const float4* dp = (const float4*)attd;
    float ss = 0.f, dd = 0.f;
    for (int c = 0; c < NHC / 8; c++) {
        f16x8 hv = hp[c];
        float4 s1 = sp[2 * c], s2 = sp[2 * c + 1];
        float4 d1 = dp[2 * c], d2 = dp[2 * c + 1];
        ss += (float)hv[0] * s1.x + (float)hv[1] * s1.y + (float)hv[2] * s1.z + (float)hv[3] * s1.w
            + (float)hv[4] * s2.x + (float)hv[5] * s2.y + (float)hv[6] * s2.z + (float)hv[7] * s2.w;
        dd += (float)hv[0] * d1.x + (float)hv[1] * d1.y + (float)hv[2] * d1.z + (float)hv[3] * d1.w
            + (float)hv[4] * d2.x + (float)hv[5] * d2.y + (float)hv[6] * d2.z + (float)hv[7] * d2.w;
    }
    asb[n * 8] = ss; adb[n * 8] = dd;
}

// ================= CSR build =================
__global__ __launch_bounds__(256) void count_hist_kernel(
    const int* __restrict__ ei, const int* __restrict__ batch,
    int* __restrict__ deg, int* __restrict__ gcnt, int E, int N)
{
    __shared__ int hist[N_GRAPH];
    int t = threadIdx.x;
    if (t < N_GRAPH) hist[t] = 0;
    __syncthreads();
    int i = blockIdx.x * 256 + t;
    if (i < E) atomicAdd(&deg[ei[E + i]], 1);
    if (i < N) atomicAdd(&hist[batch[i]], 1);
    __syncthreads();
    if (t < N_GRAPH && hist[t] > 0) atomicAdd(&gcnt[t], hist[t]);
}

__global__ __launch_bounds__(256) void scan_block_kernel(
    const int* __restrict__ deg, int* __restrict__ rowstart, int* __restrict__ partial, int n)
{
    __shared__ int s[256];
    int i = blockIdx.x * 256 + threadIdx.x;
    int v = (i < n) ? deg[i] : 0;
    s[threadIdx.x] = v;
    __syncthreads();
    for (int off = 1; off < 256; off <<= 1) {
        int t = (threadIdx.x >= off) ? s[threadIdx.x - off] : 0;
        __syncthreads();
        s[threadIdx.x] += t;
        __syncthreads();
    }
    if (i < n) rowstart[i] = s[threadIdx.x] - v;
    if (threadIdx.x == 255) partial[blockIdx.x] = s[255];
}

__global__ __launch_bounds__(256) void scan_partial_kernel(int* __restrict__ partial, int nb)
{
    __shared__ int s[256];
    int v = (threadIdx.x < nb) ? partial[threadIdx.x] : 0;
    s[threadIdx.x] = v;
    __syncthreads();
    for (int off = 1; off < 256; off <<= 1) {
        int t = (threadIdx.x >= off) ? s[threadIdx.x - off] : 0;
        __syncthreads();
        s[threadIdx.x] += t;
        __syncthreads();
    }
    if (threadIdx.x < nb) partial[threadIdx.x] = s[threadIdx.x] - v;
}

__global__ __launch_bounds__(256) void scan_add_kernel(
    int* __restrict__ rowstart, const int* __restrict__ partial, int* __restrict__ cursor,
    int n, int E)
{
    int i = blockIdx.x * 256 + threadIdx.x;
    if (i < n) {
        int v = rowstart[i] + partial[blockIdx.x];
        rowstart[i] = v;
        cursor[i] = v;
    }
    if (i == 0) rowstart[n] = E;
}

__global__ __launch_bounds__(256) void fill_kernel(
    const int* __restrict__ ei, int* __restrict__ cursor, int2* __restrict__ csr, int E)
{
    int e = blockIdx.x * 256 + threadIdx.x;
    if (e >= E) return;
    int dst = ei[E + e];
    int pos = atomicAdd(&cursor[dst], 1);
    csr[pos] = make_int2(ei[e], e);
}

// ========== fused GAT aggregation, fp16 h gather, fp16 output ==========
__global__ __launch_bounds__(256) void gat_agg_kernel(
    const int* __restrict__ rowstart, const int2* __restrict__ csr,
    const float* __restrict__ ea, const float* __restrict__ asb,
    const float* __restrict__ adb, const float* __restrict__ MeL,
    const _Float16* __restrict__ h, const float* __restrict__ bias,
    _Float16* __restrict__ Oh, int H, int clog2)
{
    int node = blockIdx.x * 4 + (threadIdx.x >> 6);
    if (node >= N_NODES) return;
    int lane = threadIdx.x & 63;
    int c0 = lane * 4;
    int hc = c0 >> clog2;
    int heff = lane & (H - 1);
    float Mh0 = MeL[0 * H + heff], Mh1 = MeL[1 * H + heff], Mh2 = MeL[2 * H + heff],
          Mh3 = MeL[3 * H + heff], Mh4 = MeL[4 * H + heff];
    float adn = adb[node * 8 + heff];
    int beg = rowstart[node], end = rowstart[node + 1];
    float ax = 0.f, ay = 0.f, az = 0.f, aw = 0.f, den = 0.f;
    for (int i = beg; i < end; i += 8) {
        int idx = i + (lane >> 3);
        if (idx >= end) idx = end - 1;
        int2 se = csr[idx];
        const float* eap = ea + (long)se.y * 5;
        float aeh = eap[0] * Mh0 + eap[1] * Mh1 + eap[2] * Mh2 + eap[3] * Mh3 + eap[4] * Mh4;
        float al = asb[se.x * 8 + heff] + adn + aeh;
        al = fmaxf(al, 0.2f * al);
        float pv = expf(al);
        int nrem = end - i;
#pragma unroll
        for (int j = 0; j < 8; j++) {
            if (j >= nrem) break;
            float pj  = __shfl(pv, j * 8 + hc);
            int  srcj = __shfl(se.x, j * 8);
            const f16x4 hv = *(const f16x4*)(h + (long)srcj * NHC + c0);
            den += pj;
            ax += pj * (float)hv[0]; ay += pj * (float)hv[1];
            az += pj * (float)hv[2]; aw += pj * (float)hv[3];
        }
    }
    float w = 1.0f / (den + 1e-16f);
    const float4 bv = *(const float4*)(bias + c0);
    float4 v;
    v.x = ax * w + bv.x;  v.y = ay * w + bv.y;
    v.z = az * w + bv.z;  v.w = aw * w + bv.w;
    v.x = (v.x > 0.f) ? v.x : expm1f(v.x);
    v.y = (v.y > 0.f) ? v.y : expm1f(v.y);
    v.z = (v.z > 0.f) ? v.z : expm1f(v.z);
    v.w = (v.w > 0.f) ? v.w : expm1f(v.w);
    f16x4 oh;
    oh[0] = (_Float16)v.x; oh[1] = (_Float16)v.y;
    oh[2] = (_Float16)v.z; oh[3] = (_Float16)v.w;
    *(f16x4*)(Oh + (long)node * NHC + c0) = oh;
}

// ================= final: out[g,:] = (pooled[g,:]@fcW2)/cnt + fcb2 =================
__global__ void final_kernel(const float* __restrict__ pooled, const int* __restrict__ gcnt,
                             const float* __restrict__ fcW2, const float* __restrict__ fcb2,
                             float* __restrict__ out)
{
    int g = blockIdx.x;
    int j = threadIdx.x;
    if (j >= DOUT) return;
    float s = 0.f;
    for (int k = 0; k < NHC; k++) s += pooled[g * NHC + k] * fcW2[k * DOUT + j];
    int c = gcnt[g];
    out[g * DOUT + j] = (c > 0) ? (s / (float)c + fcb2[j]) : 0.f;
}

extern "C" void kernel_launch(void* const* d_in, const int* in_sizes, int n_in,
                              void* d_out, int out_size, void* d_ws, size_t ws_size,
                              hipStream_t stream)
{
    const float* x    = (const float*)d_in[0];
    const int*   ei   = (const int*)  d_in[1];
    const float* ea   = (const float*)d_in[2];
    const int*   bat  = (const int*)  d_in[3];
    const float* W[3]   = {(const float*)d_in[4],  (const float*)d_in[10], (const float*)d_in[16]};
    const float* Asl[3] = {(const float*)d_in[5],  (const float*)d_in[11], (const float*)d_in[17]};
    const float* Adl[3] = {(const float*)d_in[6],  (const float*)d_in[12], (const float*)d_in[18]};
    const float* Wel[3] = {(const float*)d_in[7],  (const float*)d_in[13], (const float*)d_in[19]};
    const float* Ael[3] = {(const float*)d_in[8],  (const float*)d_in[14], (const float*)d_in[20]};
    const float* Bil[3] = {(const float*)d_in[9],  (const float*)d_in[15], (const float*)d_in[21]};
    const float* fcW1 = (const float*)d_in[22];
    const float* fcb1 = (const float*)d_in[23];
    const float* fcW2 = (const float*)d_in[24];
    const float* fcb2 = (const float*)d_in[25];

    // ---- workspace carve (bytes) ----
    char* w = (char*)d_ws;
    _Float16* h    = (_Float16*)w;     w += (size_t)N_NODES * NHC * 2;   // fp16 h
    _Float16* xh   = (_Float16*)w;     w += (size_t)N_NODES * DIN * 2;
    _Float16* xbh  = (_Float16*)w;     w += (size_t)N_NODES * NHC * 2;
    float*    asb  = (float*)w;        w += (size_t)N_NODES * 8 * 4;
    float*    adb  = (float*)w;        w += (size_t)N_NODES * 8 * 4;
    float*    MeAll= (float*)w;        w += 120 * 4;
    float*    pooled=(float*)w;        w += (size_t)N_GRAPH * NHC * 4;
    _Float16* W1th = (_Float16*)w;     w += (size_t)NHC * DIN * 2;
    _Float16* W1tl = (_Float16*)w;     w += (size_t)NHC * DIN * 2;
    _Float16* W2th = (_Float16*)w;     w += (size_t)NHC * NHC * 2;
    _Float16* W2tl = (_Float16*)w;     w += (size_t)NHC * NHC * 2;
    _Float16* W3th = (_Float16*)w;     w += (size_t)NHC * NHC * 2;
    _Float16* W3tl = (_Float16*)w;     w += (size_t)NHC * NHC * 2;
    _Float16* F1th = (_Float16*)w;     w += (size_t)NHC * NHC * 2;
    _Float16* F1tl = (_Float16*)w;     w += (size_t)NHC * NHC * 2;
    int* gcnt     = (int*)w;           w += N_GRAPH * 4;
    int* deg      = (int*)w;           w += (size_t)N_NODES * 4;
    int* rowstart = (int*)w;           w += (size_t)(N_NODES + 1) * 4;
    int* cursor   = (int*)w;           w += (size_t)N_NODES * 4;
    int* partial  = (int*)w;           w += 256 * 4;
    w = (char*)(((size_t)w + 15) & ~(size_t)15);
    int2* csr     = (int2*)w;          w += (size_t)N_EDGES * 8;

    const int NB = (N_NODES + 255) / 256;

    prep_kernel<<<(JTOT + 255) / 256, 256, 0, stream>>>(
        x, W[0], W[1], W[2], fcW1,
        xh, W1th, W1tl, W2th, W2tl, W3th, W3tl, F1th, F1tl,
        pooled, deg, gcnt);
    count_hist_kernel<<<(N_EDGES + 255) / 256, 256, 0, stream>>>(ei, bat, deg, gcnt, N_EDGES, N_NODES);
    scan_block_kernel<<<NB, 256, 0, stream>>>(deg, rowstart, partial, N_NODES);
    scan_partial_kernel<<<1, 256, 0, stream>>>(partial, NB);
    scan_add_kernel<<<NB, 256, 0, stream>>>(rowstart, partial, cursor, N_NODES, N_EDGES);
    fill_kernel<<<(N_EDGES + 255) / 256, 256, 0, stream>>>(ei, cursor, csr, N_EDGES);
    me_all_kernel<<<3, 64, 0, stream>>>(Wel[0], Ael[0], Wel[1], Ael[1], Wel[2], Ael[2], MeAll);

    const int Hs[3] = {8, 8, 1};
    const int CL[3] = {5, 5, 8};
    const int Ks[3] = {DIN, NHC, NHC};

    const dim3 ggrid(4, 392);

    const _Float16* curh = xh;
    const _Float16* Wth[3] = {W1th, W2th, W3th};
    const _Float16* Wtl[3] = {W1tl, W2tl, W3tl};
    for (int l = 0; l < 3; l++) {
        const int H = Hs[l];
        const bool fuse = (l != 2);
        mfma_gemm_kernel<<<ggrid, 256, 0, stream>>>(
            curh, Wth[l], Wtl[l], nullptr, h,
            fuse ? Asl[l] : nullptr, fuse ? Adl[l] : nullptr, asb, adb,
            nullptr, nullptr,
            N_NODES, Ks[l], 0);
        if (!fuse)
            asd_kernel<<<(N_NODES + 255) / 256, 256, 0, stream>>>(
                h, Asl[l], Adl[l], asb, adb, N_NODES);
        gat_agg_kernel<<<(N_NODES + 3) / 4, 256, 0, stream>>>(
            rowstart, csr, ea, asb, adb, MeAll + l * 40, h, Bil[l], xbh, H, CL[l]);
        curh = xbh;
    }

    // fc1 + fused gelu + per-graph pooling (fc2 commutes with pooling)
    mfma_gemm_kernel<<<ggrid, 256, 0, stream>>>(
        xbh, F1th, F1tl, fcb1, nullptr,
        nullptr, nullptr, nullptr, nullptr,
        bat, pooled,
        N_NODES, NHC, 3);
    final_kernel<<<N_GRAPH, 64, 0, stream>>>(pooled, gcnt, fcW2, fcb2, (float*)d_out);
}

// Round 14
// 452.181 us; speedup vs baseline: 2.0882x; 1.0397x over previous
//
#include <hip/hip_runtime.h>
#include <math.h>

// GATNet_MLP R14: R13 + B-side lo plane dropped -> plain fp16 x fp16 GEMM
// (1 MFMA per product; -50% matrix work vs R13, B staging/LDS halved).
// Accuracy: empirical — R13's A-side fp16 rounding (same 2^-11 mechanism)
// left absmax bit-identical at 3.05e-5; one more equal-magnitude source
// predicts ~4-7e-5 < 1.24e-4 threshold.

#define N_NODES 50000
#define N_EDGES 400000
#define N_GRAPH 64
#define DIN     128
#define NHC     256
#define DOUT    32

typedef _Float16 f16x8 __attribute__((ext_vector_type(8)));
typedef _Float16 f16x4 __attribute__((ext_vector_type(4)));
typedef float    f32x4 __attribute__((ext_vector_type(4)));

#define LDP 40   // padded LDS row stride in halfs (80B; kills b128 conflicts)

// ================= fp16 MFMA GEMM, 128x64 tile, pipelined ==========
// mode 0: C fp16 [nrow][256]; if asl!=null also per-head a_s/a_d (C=32 layers).
// mode 3: NO C write; v=gelu(v+bias); per-graph pooled sums (batch sorted).
__global__ __launch_bounds__(256) void mfma_gemm_kernel(
    const _Float16* __restrict__ Ah, const _Float16* __restrict__ Bh,
    const float* __restrict__ bias, _Float16* __restrict__ Ch,
    const float* __restrict__ asl, const float* __restrict__ adl,
    float* __restrict__ asb, float* __restrict__ adb,
    const int* __restrict__ batch, float* __restrict__ pooled,
    int nrow, int K, int mode)
{
    __shared__ __align__(16) _Float16 sAh[128][LDP];
    __shared__ __align__(16) _Float16 sBh[64][LDP];

    const int tid = threadIdx.x, lane = tid & 63, wid = tid >> 6;
    const int wm = wid & 1, wn = wid >> 1;

    int xt, yt;
    if (gridDim.x == 4) {
        int bid = blockIdx.x + (blockIdx.y << 2);
        yt = (bid >> 5) * 8 + (bid & 7);
        xt = (bid >> 3) & 3;
    } else { xt = blockIdx.x; yt = blockIdx.y; }
    const int row0 = yt * 128, col0 = xt * 64;
    if (row0 >= nrow) return;

    const int frow = lane & 15, fk = (lane >> 4) * 8;
    const int ra = tid >> 2, kq = (tid & 3) * 8;

    f32x4 acc[4][2] = {};
    f16x8 pAh[2], pBh;

    {
#pragma unroll
        for (int p = 0; p < 2; p++) {
            int gr = row0 + p * 64 + ra;
            pAh[p] = (gr < nrow) ? *(const f16x8*)(Ah + (long)gr * K + kq) : (f16x8)0;
        }
        pBh = *(const f16x8*)(Bh + (long)(col0 + ra) * K + kq);
    }

    for (int k0 = 0; k0 < K; k0 += 32) {
#pragma unroll
        for (int p = 0; p < 2; p++)
            *(f16x8*)&sAh[p * 64 + ra][kq] = pAh[p];
        *(f16x8*)&sBh[ra][kq] = pBh;
        __syncthreads();

        if (k0 + 32 < K) {
            int kn = k0 + 32 + kq;
#pragma unroll
            for (int p = 0; p < 2; p++) {
                int gr = row0 + p * 64 + ra;
                pAh[p] = (gr < nrow) ? *(const f16x8*)(Ah + (long)gr * K + kn) : (f16x8)0;
            }
            pBh = *(const f16x8*)(Bh + (long)(col0 + ra) * K + kn);
        }

        f16x8 bh[2];
#pragma unroll
        for (int nt = 0; nt < 2; nt++)
            bh[nt] = *(const f16x8*)&sBh[wn * 32 + nt * 16 + frow][fk];
#pragma unroll
        for (int mt = 0; mt < 4; mt++) {
            f16x8 ah = *(const f16x8*)&sAh[wm * 64 + mt * 16 + frow][fk];
#pragma unroll
            for (int nt = 0; nt < 2; nt++)
                acc[mt][nt] = __builtin_amdgcn_mfma_f32_16x16x32_f16(ah, bh[nt], acc[mt][nt], 0, 0, 0);
        }
        __syncthreads();
    }

    const int crow0 = row0 + wm * 64 + (lane >> 4) * 4;
    const int ccol0 = col0 + wn * 32 + (lane & 15);

    if (mode == 0) {
#pragma unroll
        for (int mt = 0; mt < 4; mt++)
#pragma unroll
            for (int nt = 0; nt < 2; nt++) {
                int col = ccol0 + nt * 16;
#pragma unroll
                for (int r = 0; r < 4; r++) {
                    int row = crow0 + mt * 16 + r;
                    if (row < nrow) Ch[(long)row * 256 + col] = (_Float16)acc[mt][nt][r];
                }
            }
        // fused a_s/a_d from fp32 acc regs (C=32 layers): plain stores.
        if (asl != nullptr) {
            const float asl0 = asl[ccol0], asl1 = asl[ccol0 + 16];
            const float adl0 = adl[ccol0], adl1 = adl[ccol0 + 16];
            const int headw = (col0 + wn * 32) >> 5;
#pragma unroll
            for (int mt = 0; mt < 4; mt++) {
#pragma unroll
                for (int r = 0; r < 4; r++) {
                    float s = acc[mt][0][r] * asl0 + acc[mt][1][r] * asl1;
                    float d = acc[mt][0][r] * adl0 + acc[mt][1][r] * adl1;
                    s += __shfl_xor(s, 1); s += __shfl_xor(s, 2);
                    s += __shfl_xor(s, 4); s += __shfl_xor(s, 8);
                    d += __shfl_xor(d, 1); d += __shfl_xor(d, 2);
                    d += __shfl_xor(d, 4); d += __shfl_xor(d, 8);
                    if ((lane & 15) == 0) {
                        int row = crow0 + mt * 16 + r;
                        if (row < nrow) {
                            asb[row * 8 + headw] = s;
                            adb[row * 8 + headw] = d;
                        }
                    }
                }
            }
        }
    } else {
        // mode 3: gelu(v+bias) -> per-graph pooled sums, register pre-accum (R11).
        float* pool = (float*)&sAh[0][0];            // 16*64 floats = 4KB
        const int g0 = batch[row0];
        const int rlast = (row0 + 127 < nrow) ? row0 + 127 : nrow - 1;
        const int gspan = batch[rlast] - g0 + 1;
        const bool fits = (gspan <= 16);
        for (int i = tid; i < 16 * 64; i += 256) pool[i] = 0.f;
        __syncthreads();

        const float b0 = bias[ccol0], b1 = bias[ccol0 + 16];
        const int lc0 = ccol0 - col0, lc1 = lc0 + 16;
        float sum0 = 0.f, sum1 = 0.f;
        int curg = -1;
#pragma unroll
        for (int mt = 0; mt < 4; mt++) {
#pragma unroll
            for (int r = 0; r < 4; r++) {
                int row = crow0 + mt * 16 + r;
                if (row >= nrow) continue;
                int g = batch[row];
                if (g != curg) {
                    if (curg >= 0) {
                        if (fits) {
                            atomicAdd(&pool[(curg - g0) * 64 + lc0], sum0);
                            atomicAdd(&pool[(curg - g0) * 64 + lc1], sum1);
                        } else {
                            atomicAdd(&pooled[curg * 256 + ccol0], sum0);
                            atomicAdd(&pooled[curg * 256 + ccol0 + 16], sum1);
                        }
                    }
                    curg = g; sum0 = 0.f; sum1 = 0.f;
                }
                float v0 = acc[mt][0][r] + b0;
                float v1 = acc[mt][1][r] + b1;
                sum0 += 0.5f * v0 * (1.f + erff(v0 * 0.7071067811865475f));
                sum1 += 0.5f * v1 * (1.f + erff(v1 * 0.7071067811865475f));
            }
        }
        if (curg >= 0) {
            if (fits) {
                atomicAdd(&pool[(curg - g0) * 64 + lc0], sum0);
                atomicAdd(&pool[(curg - g0) * 64 + lc1], sum1);
            } else {
                atomicAdd(&pooled[curg * 256 + ccol0], sum0);
                atomicAdd(&pooled[curg * 256 + ccol0 + 16], sum1);
            }
        }
        __syncthreads();
        if (fits) {
            for (int i = tid; i < gspan * 64; i += 256) {
                float val = pool[i];
                if (val != 0.f)
                    atomicAdd(&pooled[(g0 + (i >> 6)) * 256 + col0 + (i & 63)], val);
            }
        }
    }
}

// ================= single prep kernel =================
#define J0 1600000                       // x convert (float4 units): N*DIN/4
#define J1 32768                         // W1 transpose (256 x 128)
#define J2 65536                         // W2
#define J3 65536                         // W3
#define J4 65536                         // fcW1
#define J5 16384                         // zero pooled (64*256)
#define J6 N_NODES                       // zero deg
#define J7 64                            // zero gcnt
#define JTOT (J0+J1+J2+J3+J4+J5+J6+J7)

__device__ __forceinline__ void t_one(const float* W, _Float16* Bh,
                                      int id, int K, int realN)
{
    int n = id / K, k = id - n * K;
    Bh[id] = (_Float16)W[(long)k * realN + n];
}

__global__ __launch_bounds__(256) void prep_kernel(
    const float* __restrict__ x,
    const float* __restrict__ W1, const float* __restrict__ W2, const float* __restrict__ W3,
    const float* __restrict__ F1,
    _Float16* __restrict__ xh,
    _Float16* __restrict__ W1th, _Float16* __restrict__ W2th,
    _Float16* __restrict__ W3th, _Float16* __restrict__ F1th,
    float* __restrict__ pooled, int* __restrict__ deg, int* __restrict__ gcnt)
{
    int idx = blockIdx.x * 256 + threadIdx.x;
    if (idx < J0) {
        float4 v = ((const float4*)x)[idx];
        f16x4 h;
        h[0] = (_Float16)v.x; h[1] = (_Float16)v.y;
        h[2] = (_Float16)v.z; h[3] = (_Float16)v.w;
        *(f16x4*)(xh + (long)idx * 4) = h;
        return;
    }
    idx -= J0;
    if (idx < J1) { t_one(W1, W1th, idx, DIN, NHC); return; }
    idx -= J1;
    if (idx < J2) { t_one(W2, W2th, idx, NHC, NHC); return; }
    idx -= J2;
    if (idx < J3) { t_one(W3, W3th, idx, NHC, NHC); return; }
    idx -= J3;
    if (idx < J4) { t_one(F1, F1th, idx, NHC, NHC); return; }
    idx -= J4;
    if (idx < J5) { pooled[idx] = 0.f; return; }
    idx -= J5;
    if (idx < J6) { deg[idx] = 0; return; }
    idx -= J6;
    if (idx < J7) { gcnt[idx] = 0; return; }
}

// -------- all 3 layers' Me[5][H] in one launch --------
__global__ void me_all_kernel(
    const float* __restrict__ We1, const float* __restrict__ ae1,
    const float* __restrict__ We2, const float* __restrict__ ae2,
    const float* __restrict__ We3, const float* __restrict__ ae3,
    float* __restrict__ MeAll)
{
    int l = blockIdx.x;
    const float* We = (l == 0) ? We1 : (l == 1) ? We2 : We3;
    const float* ae = (l == 0) ? ae1 : (l == 1) ? ae2 : ae3;
    int H = (l == 2) ? 1 : 8, C = (l == 2) ? 256 : 32;
    int t = threadIdx.x;
    if (t >= 5 * H) return;
    int j = t / H, hh = t - j * H;
    float s = 0.f;
    for (int c = 0; c < C; c++) s += We[j * NHC + hh * C + c] * ae[hh * C + c];
    MeAll[l * 40 + j * H + hh] = s;
}

// -------- asd (layer 3 only: H=1, C=256), fp16 h --------
__global__ __launch_bounds__(256) void asd_kernel(
    const _Float16* __restrict__ h, const float* __restrict__ atts, const float* __restrict__ attd,
    float* __restrict__ asb, float* __restrict__ adb, int total)
{
    int n = blockIdx.x * 256 + threadIdx.x;
    if (n >= total) return;
    const f16x8* hp = (const f16x8*)(h + (long)n * NHC);
    const float4* sp = (const float4*)atts;
    const float4* dp = (const float4*)attd;
    float ss = 0.f, dd = 0.f;
    for (int c = 0; c < NHC / 8; c++) {
        f16x8 hv = hp[c];
        float4 s1 = sp[2 * c], s2 = sp[2 * c + 1];
        float4 d1 = dp[2 * c], d2 = dp[2 * c + 1];
        ss += (float)hv[0] * s1.x + (float)hv[1] * s1.y + (float)hv[2] * s1.z + (float)hv[3] * s1.w
            + (float)hv[4] * s2.x + (float)hv[5] * s2.y + (float)hv[6] * s2.z + (float)hv[7] * s2.w;
        dd += (float)hv[0] * d1.x + (float)hv[1] * d1.y + (float)hv[2] * d1.z + (float)hv[3] * d1.w
            + (float)hv[4] * d2.x + (float)hv[5] * d2.y + (float)hv[6] * d2.z + (float)hv[7] * d2.w;
    }
    asb[n * 8] = ss; adb[n * 8] = dd;
}

// ================= CSR build =================
__global__ __launch_bounds__(256) void count_hist_kernel(
    const int* __restrict__ ei, const int* __restrict__ batch,
    int* __restrict__ deg, int* __restrict__ gcnt, int E, int N)
{
    __shared__ int hist[N_GRAPH];
    int t = threadIdx.x;
    if (t < N_GRAPH) hist[t] = 0;
    __syncthreads();
    int i = blockIdx.x * 256 + t;
    if (i < E) atomicAdd(&deg[ei[E + i]], 1);
    if (i < N) atomicAdd(&hist[batch[i]], 1);
    __syncthreads();
    if (t < N_GRAPH && hist[t] > 0) atomicAdd(&gcnt[t], hist[t]);
}

__global__ __launch_bounds__(256) void scan_block_kernel(
    const int* __restrict__ deg, int* __restrict__ rowstart, int* __restrict__ partial, int n)
{
    __shared__ int s[256];
    int i = blockIdx.x * 256 + threadIdx.x;
    int v = (i < n) ? deg[i] : 0;
    s[threadIdx.x] = v;
    __syncthreads();
    for (int off = 1; off < 256; off <<= 1) {
        int t = (threadIdx.x >= off) ? s[threadIdx.x - off] : 0;
        __syncthreads();
        s[threadIdx.x] += t;
        __syncthreads();
    }
    if (i < n) rowstart[i] = s[threadIdx.x] - v;
    if (threadIdx.x == 255) partial[blockIdx.x] = s[255];
}

__global__ __launch_bounds__(256) void scan_partial_kernel(int* __restrict__ partial, int nb)
{
    __shared__ int s[256];
    int v = (threadIdx.x < nb) ? partial[threadIdx.x] : 0;
    s[threadIdx.x] = v;
    __syncthreads();
    for (int off = 1; off < 256; off <<= 1) {
        int t = (threadIdx.x >= off) ? s[threadIdx.x - off] : 0;
        __syncthreads();
        s[threadIdx.x] += t;
        __syncthreads();
    }
    if (threadIdx.x < nb) partial[threadIdx.x] = s[threadIdx.x] - v;
}

__global__ __launch_bounds__(256) void scan_add_kernel(
    int* __restrict__ rowstart, const int* __restrict__ partial, int* __restrict__ cursor,
    int n, int E)
{
    int i = blockIdx.x * 256 + threadIdx.x;
    if (i < n) {
        int v = rowstart[i] + partial[blockIdx.x];
        rowstart[i] = v;
        cursor[i] = v;
    }
    if (i == 0) rowstart[n] = E;
}

__global__ __launch_bounds__(256) void fill_kernel(
    const int* __restrict__ ei, int* __restrict__ cursor, int2* __restrict__ csr, int E)
{
    int e = blockIdx.x * 256 + threadIdx.x;
    if (e >= E) return;
    int dst = ei[E + e];
    int pos = atomicAdd(&cursor[dst], 1);
    csr[pos] = make_int2(ei[e], e);
}

// ========== fused GAT aggregation, fp16 h gather, fp16 output ==========
__global__ __launch_bounds__(256) void gat_agg_kernel(
    const int* __restrict__ rowstart, const int2* __restrict__ csr,
    const float* __restrict__ ea, const float* __restrict__ asb,
    const float* __restrict__ adb, const float* __restrict__ MeL,
    const _Float16* __restrict__ h, const float* __restrict__ bias,
    _Float16* __restrict__ Oh, int H, int clog2)
{
    int node = blockIdx.x * 4 + (threadIdx.x >> 6);
    if (node >= N_NODES) return;
    int lane = threadIdx.x & 63;
    int c0 = lane * 4;
    int hc = c0 >> clog2;
    int heff = lane & (H - 1);
    float Mh0 = MeL[0 * H + heff], Mh1 = MeL[1 * H + heff], Mh2 = MeL[2 * H + heff],
          Mh3 = MeL[3 * H + heff], Mh4 = MeL[4 * H + heff];
    float adn = adb[node * 8 + heff];
    int beg = rowstart[node], end = rowstart[node + 1];
    float ax = 0.f, ay = 0.f, az = 0.f, aw = 0.f, den = 0.f;
    for (int i = beg; i < end; i += 8) {
        int idx = i + (lane >> 3);
        if (idx >= end) idx = end - 1;
        int2 se = csr[idx];
        const float* eap = ea + (long)se.y * 5;
        float aeh = eap[0] * Mh0 + eap[1] * Mh1 + eap[2] * Mh2 + eap[3] * Mh3 + eap[4] * Mh4;
        float al = asb[se.x * 8 + heff] + adn + aeh;
        al = fmaxf(al, 0.2f * al);
        float pv = expf(al);
        int nrem = end - i;
#pragma unroll
        for (int j = 0; j < 8; j++) {
            if (j >= nrem) break;
            float pj  = __shfl(pv, j * 8 + hc);
            int  srcj = __shfl(se.x, j * 8);
            const f16x4 hv = *(const f16x4*)(h + (long)srcj * NHC + c0);
            den += pj;
            ax += pj * (float)hv[0]; ay += pj * (float)hv[1];
            az += pj * (float)hv[2]; aw += pj * (float)hv[3];
        }
    }
    float w = 1.0f / (den + 1e-16f);
    const float4 bv = *(const float4*)(bias + c0);
    float4 v;
    v.x = ax * w + bv.x;  v.y = ay * w + bv.y;
    v.z = az * w + bv.z;  v.w = aw * w + bv.w;
    v.x = (v.x > 0.f) ? v.x : expm1f(v.x);
    v.y = (v.y > 0.f) ? v.y : expm1f(v.y);
    v.z = (v.z > 0.f) ? v.z : expm1f(v.z);
    v.w = (v.w > 0.f) ? v.w : expm1f(v.w);
    f16x4 oh;
    oh[0] = (_Float16)v.x; oh[1] = (_Float16)v.y;
    oh[2] = (_Float16)v.z; oh[3] = (_Float16)v.w;
    *(f16x4*)(Oh + (long)node * NHC + c0) = oh;
}

// ================= final: out[g,:] = (pooled[g,:]@fcW2)/cnt + fcb2 =================
__global__ void final_kernel(const float* __restrict__ pooled, const int* __restrict__ gcnt,
                             const float* __restrict__ fcW2, const float* __restrict__ fcb2,
                             float* __restrict__ out)
{
    int g = blockIdx.x;
    int j = threadIdx.x;
    if (j >= DOUT) return;
    float s = 0.f;
    for (int k = 0; k < NHC; k++) s += pooled[g * NHC + k] * fcW2[k * DOUT + j];
    int c = gcnt[g];
    out[g * DOUT + j] = (c > 0) ? (s / (float)c + fcb2[j]) : 0.f;
}

extern "C" void kernel_launch(void* const* d_in, const int* in_sizes, int n_in,
                              void* d_out, int out_size, void* d_ws, size_t ws_size,
                              hipStream_t stream)
{
    const float* x    = (const float*)d_in[0];
    const int*   ei   = (const int*)  d_in[1];
    const float* ea   = (const float*)d_in[2];
    const int*   bat  = (const int*)  d_in[3];
    const float* W[3]   = {(const float*)d_in[4],  (const float*)d_in[10], (const float*)d_in[16]};
    const float* Asl[3] = {(const float*)d_in[5],  (const float*)d_in[11], (const float*)d_in[17]};
    const float* Adl[3] = {(const float*)d_in[6],  (const float*)d_in[12], (const float*)d_in[18]};
    const float* Wel[3] = {(const float*)d_in[7],  (const float*)d_in[13], (const float*)d_in[19]};
    const float* Ael[3] = {(const float*)d_in[8],  (const float*)d_in[14], (const float*)d_in[20]};
    const float* Bil[3] = {(const float*)d_in[9],  (const float*)d_in[15], (const float*)d_in[21]};
    const float* fcW1 = (const float*)d_in[22];
    const float* fcb1 = (const float*)d_in[23];
    const float* fcW2 = (const float*)d_in[24];
    const float* fcb2 = (const float*)d_in[25];

    // ---- workspace carve (bytes) ----
    char* w = (char*)d_ws;
    _Float16* h    = (_Float16*)w;     w += (size_t)N_NODES * NHC * 2;   // fp16 h
    _Float16* xh   = (_Float16*)w;     w += (size_t)N_NODES * DIN * 2;
    _Float16* xbh  = (_Float16*)w;     w += (size_t)N_NODES * NHC * 2;
    float*    asb  = (float*)w;        w += (size_t)N_NODES * 8 * 4;
    float*    adb  = (float*)w;        w += (size_t)N_NODES * 8 * 4;
    float*    MeAll= (float*)w;        w += 120 * 4;
    float*    pooled=(float*)w;        w += (size_t)N_GRAPH * NHC * 4;
    _Float16* W1th = (_Float16*)w;     w += (size_t)NHC * DIN * 2;
    _Float16* W2th = (_Float16*)w;     w += (size_t)NHC * NHC * 2;
    _Float16* W3th = (_Float16*)w;     w += (size_t)NHC * NHC * 2;
    _Float16* F1th = (_Float16*)w;     w += (size_t)NHC * NHC * 2;
    int* gcnt     = (int*)w;           w += N_GRAPH * 4;
    int* deg      = (int*)w;           w += (size_t)N_NODES * 4;
    int* rowstart = (int*)w;           w += (size_t)(N_NODES + 1) * 4;
    int* cursor   = (int*)w;           w += (size_t)N_NODES * 4;
    int* partial  = (int*)w;           w += 256 * 4;
    w = (char*)(((size_t)w + 15) & ~(size_t)15);
    int2* csr     = (int2*)w;          w += (size_t)N_EDGES * 8;

    const int NB = (N_NODES + 255) / 256;

    prep_kernel<<<(JTOT + 255) / 256, 256, 0, stream>>>(
        x, W[0], W[1], W[2], fcW1,
        xh, W1th, W2th, W3th, F1th,
        pooled, deg, gcnt);
    count_hist_kernel<<<(N_EDGES + 255) / 256, 256, 0, stream>>>(ei, bat, deg, gcnt, N_EDGES, N_NODES);
    scan_block_kernel<<<NB, 256, 0, stream>>>(deg, rowstart, partial, N_NODES);
    scan_partial_kernel<<<1, 256, 0, stream>>>(partial, NB);
    scan_add_kernel<<<NB, 256, 0, stream>>>(rowstart, partial, cursor, N_NODES, N_EDGES);
    fill_kernel<<<(N_EDGES + 255) / 256, 256, 0, stream>>>(ei, cursor, csr, N_EDGES);
    me_all_kernel<<<3, 64, 0, stream>>>(Wel[0], Ael[0], Wel[1], Ael[1], Wel[2], Ael[2], MeAll);

    const int Hs[3] = {8, 8, 1};
    const int CL[3] = {5, 5, 8};
    const int Ks[3] = {DIN, NHC, NHC};

    const dim3 ggrid(4, 392);

    const _Float16* curh = xh;
    const _Float16* Wth[3] = {W1th, W2th, W3th};
    for (int l = 0; l < 3; l++) {
        const int H = Hs[l];
        const bool fuse = (l != 2);
        mfma_gemm_kernel<<<ggrid, 256, 0, stream>>>(
            curh, Wth[l], nullptr, h,
            fuse ? Asl[l] : nullptr, fuse ? Adl[l] : nullptr, asb, adb,
            nullptr, nullptr,
            N_NODES, Ks[l], 0);
        if (!fuse)
            asd_kernel<<<(N_NODES + 255) / 256, 256, 0, stream>>>(
                h, Asl[l], Adl[l], asb, adb, N_NODES);
        gat_agg_kernel<<<(N_NODES + 3) / 4, 256, 0, stream>>>(
            rowstart, csr, ea, asb, adb, MeAll + l * 40, h, Bil[l], xbh, H, CL[l]);
        curh = xbh;
    }

    // fc1 + fused gelu + per-graph pooling (fc2 commutes with pooling)
    mfma_gemm_kernel<<<ggrid, 256, 0, stream>>>(
        xbh, F1th, fcb1, nullptr,
        nullptr, nullptr, nullptr, nullptr,
        bat, pooled,
        N_NODES, NHC, 3);
    final_kernel<<<N_GRAPH, 64, 0, stream>>>(pooled, gcnt, fcW2, fcb2, (float*)d_out);
}

// Round 15
// 446.343 us; speedup vs baseline: 2.1155x; 1.0131x over previous
//
#include <hip/hip_runtime.h>
#include <math.h>

// GATNet_MLP R15: R14 + GEMM BK 32->64 (barrier rounds halve: 16->8 for K=256).
// R14 showed GEMMs are barrier/staging-latency-bound (halving MFMA work saved
// only 18us); LDS 27.6KB still gives 5 blocks/CU (m132's BK=128 cliff avoided).

#define N_NODES 50000
#define N_EDGES 400000
#define N_GRAPH 64
#define DIN     128
#define NHC     256
#define DOUT    32

typedef _Float16 f16x8 __attribute__((ext_vector_type(8)));
typedef _Float16 f16x4 __attribute__((ext_vector_type(4)));
typedef float    f32x4 __attribute__((ext_vector_type(4)));

#define LDP2 72   // padded LDS row stride in halfs for BK=64 (144B)

// ================= fp16 MFMA GEMM, 128x64 tile, BK=64, pipelined ==========
// mode 0: C fp16 [nrow][256]; if asl!=null also per-head a_s/a_d (C=32 layers).
// mode 3: NO C write; v=gelu(v+bias); per-graph pooled sums (batch sorted).
__global__ __launch_bounds__(256) void mfma_gemm_kernel(
    const _Float16* __restrict__ Ah, const _Float16* __restrict__ Bh,
    const float* __restrict__ bias, _Float16* __restrict__ Ch,
    const float* __restrict__ asl, const float* __restrict__ adl,
    float* __restrict__ asb, float* __restrict__ adb,
    const int* __restrict__ batch, float* __restrict__ pooled,
    int nrow, int K, int mode)
{
    __shared__ __align__(16) _Float16 sAh[128][LDP2];   // 18.4 KB
    __shared__ __align__(16) _Float16 sBh[64][LDP2];    //  9.2 KB

    const int tid = threadIdx.x, lane = tid & 63, wid = tid >> 6;
    const int wm = wid & 1, wn = wid >> 1;

    int xt, yt;
    if (gridDim.x == 4) {
        int bid = blockIdx.x + (blockIdx.y << 2);
        yt = (bid >> 5) * 8 + (bid & 7);
        xt = (bid >> 3) & 3;
    } else { xt = blockIdx.x; yt = blockIdx.y; }
    const int row0 = yt * 128, col0 = xt * 64;
    if (row0 >= nrow) return;

    const int frow = lane & 15, fk = (lane >> 4) * 8;
    const int rs = tid >> 3, cs = (tid & 7) * 8;     // staging map (idx = tid + p*256)

    f32x4 acc[4][2] = {};
    f16x8 pA[4], pB[2];

    // prefetch k-tile 0
#pragma unroll
    for (int p = 0; p < 4; p++) {
        int idx = tid + p * 256;                     // 0..1023
        int r = idx >> 3, ch = (idx & 7) * 8;
        int gr = row0 + r;
        pA[p] = (gr < nrow) ? *(const f16x8*)(Ah + (long)gr * K + ch) : (f16x8)0;
    }
#pragma unroll
    for (int p = 0; p < 2; p++) {
        int idx = tid + p * 256;                     // 0..511
        int r = idx >> 3, ch = (idx & 7) * 8;
        pB[p] = *(const f16x8*)(Bh + (long)(col0 + r) * K + ch);
    }

    for (int k0 = 0; k0 < K; k0 += 64) {
#pragma unroll
        for (int p = 0; p < 4; p++) {
            int idx = tid + p * 256;
            *(f16x8*)&sAh[idx >> 3][(idx & 7) * 8] = pA[p];
        }
#pragma unroll
        for (int p = 0; p < 2; p++) {
            int idx = tid + p * 256;
            *(f16x8*)&sBh[idx >> 3][(idx & 7) * 8] = pB[p];
        }
        __syncthreads();

        if (k0 + 64 < K) {
            int kn = k0 + 64;
#pragma unroll
            for (int p = 0; p < 4; p++) {
                int idx = tid + p * 256;
                int r = idx >> 3, ch = (idx & 7) * 8;
                int gr = row0 + r;
                pA[p] = (gr < nrow) ? *(const f16x8*)(Ah + (long)gr * K + kn + ch) : (f16x8)0;
            }
#pragma unroll
            for (int p = 0; p < 2; p++) {
                int idx = tid + p * 256;
                int r = idx >> 3, ch = (idx & 7) * 8;
                pB[p] = *(const f16x8*)(Bh + (long)(col0 + r) * K + kn + ch);
            }
        }

#pragma unroll
        for (int sub = 0; sub < 2; sub++) {
            const int fks = fk + sub * 32;
            f16x8 bh[2];
#pragma unroll
            for (int nt = 0; nt < 2; nt++)
                bh[nt] = *(const f16x8*)&sBh[wn * 32 + nt * 16 + frow][fks];
#pragma unroll
            for (int mt = 0; mt < 4; mt++) {
                f16x8 ah = *(const f16x8*)&sAh[wm * 64 + mt * 16 + frow][fks];
#pragma unroll
                for (int nt = 0; nt < 2; nt++)
                    acc[mt][nt] = __builtin_amdgcn_mfma_f32_16x16x32_f16(ah, bh[nt], acc[mt][nt], 0, 0, 0);
            }
        }
        __syncthreads();
    }

    const int crow0 = row0 + wm * 64 + (lane >> 4) * 4;
    const int ccol0 = col0 + wn * 32 + (lane & 15);

    if (mode == 0) {
#pragma unroll
        for (int mt = 0; mt < 4; mt++)
#pragma unroll
            for (int nt = 0; nt < 2; nt++) {
                int col = ccol0 + nt * 16;
#pragma unroll
                for (int r = 0; r < 4; r++) {
                    int row = crow0 + mt * 16 + r;
                    if (row < nrow) Ch[(long)row * 256 + col] = (_Float16)acc[mt][nt][r];
                }
            }
        // fused a_s/a_d from fp32 acc regs (C=32 layers): plain stores.
        if (asl != nullptr) {
            const float asl0 = asl[ccol0], asl1 = asl[ccol0 + 16];
            const float adl0 = adl[ccol0], adl1 = adl[ccol0 + 16];
            const int headw = (col0 + wn * 32) >> 5;
#pragma unroll
            for (int mt = 0; mt < 4; mt++) {
#pragma unroll
                for (int r = 0; r < 4; r++) {
                    float s = acc[mt][0][r] * asl0 + acc[mt][1][r] * asl1;
                    float d = acc[mt][0][r] * adl0 + acc[mt][1][r] * adl1;
                    s += __shfl_xor(s, 1); s += __shfl_xor(s, 2);
                    s += __shfl_xor(s, 4); s += __shfl_xor(s, 8);
                    d += __shfl_xor(d, 1); d += __shfl_xor(d, 2);
                    d += __shfl_xor(d, 4); d += __shfl_xor(d, 8);
                    if ((lane & 15) == 0) {
                        int row = crow0 + mt * 16 + r;
                        if (row < nrow) {
                            asb[row * 8 + headw] = s;
                            adb[row * 8 + headw] = d;
                        }
                    }
                }
            }
        }
    } else {
        // mode 3: gelu(v+bias) -> per-graph pooled sums, register pre-accum (R11).
        float* pool = (float*)&sAh[0][0];            // 16*64 floats = 4KB
        const int g0 = batch[row0];
        const int rlast = (row0 + 127 < nrow) ? row0 + 127 : nrow - 1;
        const int gspan = batch[rlast] - g0 + 1;
        const bool fits = (gspan <= 16);
        for (int i = tid; i < 16 * 64; i += 256) pool[i] = 0.f;
        __syncthreads();

        const float b0 = bias[ccol0], b1 = bias[ccol0 + 16];
        const int lc0 = ccol0 - col0, lc1 = lc0 + 16;
        float sum0 = 0.f, sum1 = 0.f;
        int curg = -1;
#pragma unroll
        for (int mt = 0; mt < 4; mt++) {
#pragma unroll
            for (int r = 0; r < 4; r++) {
                int row = crow0 + mt * 16 + r;
                if (row >= nrow) continue;
                int g = batch[row];
                if (g != curg) {
                    if (curg >= 0) {
                        if (fits) {
                            atomicAdd(&pool[(curg - g0) * 64 + lc0], sum0);
                            atomicAdd(&pool[(curg - g0) * 64 + lc1], sum1);
                        } else {
                            atomicAdd(&pooled[curg * 256 + ccol0], sum0);
                            atomicAdd(&pooled[curg * 256 + ccol0 + 16], sum1);
                        }
                    }
                    curg = g; sum0 = 0.f; sum1 = 0.f;
                }
                float v0 = acc[mt][0][r] + b0;
                float v1 = acc[mt][1][r] + b1;
                sum0 += 0.5f * v0 * (1.f + erff(v0 * 0.7071067811865475f));
                sum1 += 0.5f * v1 * (1.f + erff(v1 * 0.7071067811865475f));
            }
        }
        if (curg >= 0) {
            if (fits) {
                atomicAdd(&pool[(curg - g0) * 64 + lc0], sum0);
                atomicAdd(&pool[(curg - g0) * 64 + lc1], sum1);
            } else {
                atomicAdd(&pooled[curg * 256 + ccol0], sum0);
                atomicAdd(&pooled[curg * 256 + ccol0 + 16], sum1);
            }
        }
        __syncthreads();
        if (fits) {
            for (int i = tid; i < gspan * 64; i += 256) {
                float val = pool[i];
                if (val != 0.f)
                    atomicAdd(&pooled[(g0 + (i >> 6)) * 256 + col0 + (i & 63)], val);
            }
        }
    }
}

// ================= single prep kernel =================
#define J0 1600000                       // x convert (float4 units): N*DIN/4
#define J1 32768                         // W1 transpose (256 x 128)
#define J2 65536                         // W2
#define J3 65536                         // W3
#define J4 65536                         // fcW1
#define J5 16384                         // zero pooled (64*256)
#define J6 N_NODES                       // zero deg
#define J7 64                            // zero gcnt
#define JTOT (J0+J1+J2+J3+J4+J5+J6+J7)

__device__ __forceinline__ void t_one(const float* W, _Float16* Bh,
                                      int id, int K, int realN)
{
    int n = id / K, k = id - n * K;
    Bh[id] = (_Float16)W[(long)k * realN + n];
}

__global__ __launch_bounds__(256) void prep_kernel(
    const float* __restrict__ x,
    const float* __restrict__ W1, const float* __restrict__ W2, const float* __restrict__ W3,
    const float* __restrict__ F1,
    _Float16* __restrict__ xh,
    _Float16* __restrict__ W1th, _Float16* __restrict__ W2th,
    _Float16* __restrict__ W3th, _Float16* __restrict__ F1th,
    float* __restrict__ pooled, int* __restrict__ deg, int* __restrict__ gcnt)
{
    int idx = blockIdx.x * 256 + threadIdx.x;
    if (idx < J0) {
        float4 v = ((const float4*)x)[idx];
        f16x4 h;
        h[0] = (_Float16)v.x; h[1] = (_Float16)v.y;
        h[2] = (_Float16)v.z; h[3] = (_Float16)v.w;
        *(f16x4*)(xh + (long)idx * 4) = h;
        return;
    }
    idx -= J0;
    if (idx < J1) { t_one(W1, W1th, idx, DIN, NHC); return; }
    idx -= J1;
    if (idx < J2) { t_one(W2, W2th, idx, NHC, NHC); return; }
    idx -= J2;
    if (idx < J3) { t_one(W3, W3th, idx, NHC, NHC); return; }
    idx -= J3;
    if (idx < J4) { t_one(F1, F1th, idx, NHC, NHC); return; }
    idx -= J4;
    if (idx < J5) { pooled[idx] = 0.f; return; }
    idx -= J5;
    if (idx < J6) { deg[idx] = 0; return; }
    idx -= J6;
    if (idx < J7) { gcnt[idx] = 0; return; }
}

// -------- all 3 layers' Me[5][H] in one launch --------
__global__ void me_all_kernel(
    const float* __restrict__ We1, const float* __restrict__ ae1,
    const float* __restrict__ We2, const float* __restrict__ ae2,
    const float* __restrict__ We3, const float* __restrict__ ae3,
    float* __restrict__ MeAll)
{
    int l = blockIdx.x;
    const float* We = (l == 0) ? We1 : (l == 1) ? We2 : We3;
    const float* ae = (l == 0) ? ae1 : (l == 1) ? ae2 : ae3;
    int H = (l == 2) ? 1 : 8, C = (l == 2) ? 256 : 32;
    int t = threadIdx.x;
    if (t >= 5 * H) return;
    int j = t / H, hh = t - j * H;
    float s = 0.f;
    for (int c = 0; c < C; c++) s += We[j * NHC + hh * C + c] * ae[hh * C + c];
    MeAll[l * 40 + j * H + hh] = s;
}

// -------- asd (layer 3 only: H=1, C=256), fp16 h --------
__global__ __launch_bounds__(256) void asd_kernel(
    const _Float16* __restrict__ h, const float* __restrict__ atts, const float* __restrict__ attd,
    float* __restrict__ asb, float* __restrict__ adb, int total)
{
    int n = blockIdx.x * 256 + threadIdx.x;
    if (n >= total) return;
    const f16x8* hp = (const f16x8*)(h + (long)n * NHC);
    const float4* sp = (const float4*)atts;
    const float4* dp = (const float4*)attd;
    float ss = 0.f, dd = 0.f;
    for (int c = 0; c < NHC / 8; c++) {
        f16x8 hv = hp[c];
        float4 s1 = sp[2 * c], s2 = sp[2 * c + 1];
        float4 d1 = dp[2 * c], d2 = dp[2 * c + 1];
        ss += (float)hv[0] * s1.x + (float)hv[1] * s1.y + (float)hv[2] * s1.z + (float)hv[3] * s1.w
            + (float)hv[4] * s2.x + (float)hv[5] * s2.y + (float)hv[6] * s2.z + (float)hv[7] * s2.w;
        dd += (float)hv[0] * d1.x + (float)hv[1] * d1.y + (float)hv[2] * d1.z + (float)hv[3] * d1.w
            + (float)hv[4] * d2.x + (float)hv[5] * d2.y + (float)hv[6] * d2.z + (float)hv[7] * d2.w;
    }
    asb[n * 8] = ss; adb[n * 8] = dd;
}

// ================= CSR build =================
__global__ __launch_bounds__(256) void count_hist_kernel(
    const int* __restrict__ ei, const int* __restrict__ batch,
    int* __restrict__ deg, int* __restrict__ gcnt, int E, int N)
{
    __shared__ int hist[N_GRAPH];
    int t = threadIdx.x;
    if (t < N_GRAPH) hist[t] = 0;
    __syncthreads();
    int i = blockIdx.x * 256 + t;
    if (i < E) atomicAdd(&deg[ei[E + i]], 1);
    if (i < N) atomicAdd(&hist[batch[i]], 1);
    __syncthreads();
    if (t < N_GRAPH && hist[t] > 0) atomicAdd(&gcnt[t], hist[t]);
}

__global__ __launch_bounds__(256) void scan_block_kernel(
    const int* __restrict__ deg, int* __restrict__ rowstart, int* __restrict__ partial, int n)
{
    __shared__ int s[256];
    int i = blockIdx.x * 256 + threadIdx.x;
    int v = (i < n) ? deg[i] : 0;
    s[threadIdx.x] = v;
    __syncthreads();
    for (int off = 1; off < 256; off <<= 1) {
        int t = (threadIdx.x >= off) ? s[threadIdx.x - off] : 0;
        __syncthreads();
        s[threadIdx.x] += t;
        __syncthreads();
    }
    if (i < n) rowstart[i] = s[threadIdx.x] - v;
    if (threadIdx.x == 255) partial[blockIdx.x] = s[255];
}

__global__ __launch_bounds__(256) void scan_partial_kernel(int* __restrict__ partial, int nb)
{
    __shared__ int s[256];
    int v = (threadIdx.x < nb) ? partial[threadIdx.x] : 0;
    s[threadIdx.x] = v;
    __syncthreads();
    for (int off = 1; off < 256; off <<= 1) {
        int t = (threadIdx.x >= off) ? s[threadIdx.x - off] : 0;
        __syncthreads();
        s[threadIdx.x] += t;
        __syncthreads();
    }
    if (threadIdx.x < nb) partial[threadIdx.x] = s[threadIdx.x] - v;
}

__global__ __launch_bounds__(256) void scan_add_kernel(
    int* __restrict__ rowstart, const int* __restrict__ partial, int* __restrict__ cursor,
    int n, int E)
{
    int i = blockIdx.x * 256 + threadIdx.x;
    if (i < n) {
        int v = rowstart[i] + partial[blockIdx.x];
        rowstart[i] = v;
        cursor[i] = v;
    }
    if (i == 0) rowstart[n] = E;
}

__global__ __launch_bounds__(256) void fill_kernel(
    const int* __restrict__ ei, int* __restrict__ cursor, int2* __restrict__ csr, int E)
{
    int e = blockIdx.x * 256 + threadIdx.x;
    if (e >= E) return;
    int dst = ei[E + e];
    int pos = atomicAdd(&cursor[dst], 1);
    csr[pos] = make_int2(ei[e], e);
}

// ========== fused GAT aggregation, fp16 h gather, fp16 output ==========
__global__ __launch_bounds__(256) void gat_agg_kernel(
    const int* __restrict__ rowstart, const int2* __restrict__ csr,
    const float* __restrict__ ea, const float* __restrict__ asb,
    const float* __restrict__ adb, const float* __restrict__ MeL,
    const _Float16* __restrict__ h, const float* __restrict__ bias,
    _Float16* __restrict__ Oh, int H, int clog2)
{
    int node = blockIdx.x * 4 + (threadIdx.x >> 6);
    if (node >= N_NODES) return;
    int lane = threadIdx.x & 63;
    int c0 = lane * 4;
    int hc = c0 >> clog2;
    int heff = lane & (H - 1);
    float Mh0 = MeL[0 * H + heff], Mh1 = MeL[1 * H + heff], Mh2 = MeL[2 * H + heff],
          Mh3 = MeL[3 * H + heff], Mh4 = MeL[4 * H + heff];
    float adn = adb[node * 8 + heff];
    int beg = rowstart[node], end = rowstart[node + 1];
    float ax = 0.f, ay = 0.f, az = 0.f, aw = 0.f, den = 0.f;
    for (int i = beg; i < end; i += 8) {
        int idx = i + (lane >> 3);
        if (idx >= end) idx = end - 1;
        int2 se = csr[idx];
        const float* eap = ea + (long)se.y * 5;
        float aeh = eap[0] * Mh0 + eap[1] * Mh1 + eap[2] * Mh2 + eap[3] * Mh3 + eap[4] * Mh4;
        float al = asb[se.x * 8 + heff] + adn + aeh;
        al = fmaxf(al, 0.2f * al);
        float pv = expf(al);
        int nrem = end - i;
#pragma unroll
        for (int j = 0; j < 8; j++) {
            if (j >= nrem) break;
            float pj  = __shfl(pv, j * 8 + hc);
            int  srcj = __shfl(se.x, j * 8);
            const f16x4 hv = *(const f16x4*)(h + (long)srcj * NHC + c0);
            den += pj;
            ax += pj * (float)hv[0]; ay += pj * (float)hv[1];
            az += pj * (float)hv[2]; aw += pj * (float)hv[3];
        }
    }
    float w = 1.0f / (den + 1e-16f);
    const float4 bv = *(const float4*)(bias + c0);
    float4 v;
    v.x = ax * w + bv.x;  v.y = ay * w + bv.y;
    v.z = az * w + bv.z;  v.w = aw * w + bv.w;
    v.x = (v.x > 0.f) ? v.x : expm1f(v.x);
    v.y = (v.y > 0.f) ? v.y : expm1f(v.y);
    v.z = (v.z > 0.f) ? v.z : expm1f(v.z);
    v.w = (v.w > 0.f) ? v.w : expm1f(v.w);
    f16x4 oh;
    oh[0] = (_Float16)v.x; oh[1] = (_Float16)v.y;
    oh[2] = (_Float16)v.z; oh[3] = (_Float16)v.w;
    *(f16x4*)(Oh + (long)node * NHC + c0) = oh;
}

// ================= final: out[g,:] = (pooled[g,:]@fcW2)/cnt + fcb2 =================
__global__ void final_kernel(const float* __restrict__ pooled, const int* __restrict__ gcnt,
                             const float* __restrict__ fcW2, const float* __restrict__ fcb2,
                             float* __restrict__ out)
{
    int g = blockIdx.x;
    int j = threadIdx.x;
    if (j >= DOUT) return;
    float s = 0.f;
    for (int k = 0; k < NHC; k++) s += pooled[g * NHC + k] * fcW2[k * DOUT + j];
    int c = gcnt[g];
    out[g * DOUT + j] = (c > 0) ? (s / (float)c + fcb2[j]) : 0.f;
}

extern "C" void kernel_launch(void* const* d_in, const int* in_sizes, int n_in,
                              void* d_out, int out_size, void* d_ws, size_t ws_size,
                              hipStream_t stream)
{
    const float* x    = (const float*)d_in[0];
    const int*   ei   = (const int*)  d_in[1];
    const float* ea   = (const float*)d_in[2];
    const int*   bat  = (const int*)  d_in[3];
    const float* W[3]   = {(const float*)d_in[4],  (const float*)d_in[10], (const float*)d_in[16]};
    const float* Asl[3] = {(const float*)d_in[5],  (const float*)d_in[11], (const float*)d_in[17]};
    const float* Adl[3] = {(const float*)d_in[6],  (const float*)d_in[12], (const float*)d_in[18]};
    const float* Wel[3] = {(const float*)d_in[7],  (const float*)d_in[13], (const float*)d_in[19]};
    const float* Ael[3] = {(const float*)d_in[8],  (const float*)d_in[14], (const float*)d_in[20]};
    const float* Bil[3] = {(const float*)d_in[9],  (const float*)d_in[15], (const float*)d_in[21]};
    const float* fcW1 = (const float*)d_in[22];
    const float* fcb1 = (const float*)d_in[23];
    const float* fcW2 = (const float*)d_in[24];
    const float* fcb2 = (const float*)d_in[25];

    // ---- workspace carve (bytes) ----
    char* w = (char*)d_ws;
    _Float16* h    = (_Float16*)w;     w += (size_t)N_NODES * NHC * 2;   // fp16 h
    _Float16* xh   = (_Float16*)w;     w += (size_t)N_NODES * DIN * 2;
    _Float16* xbh  = (_Float16*)w;     w += (size_t)N_NODES * NHC * 2;
    float*    asb  = (float*)w;        w += (size_t)N_NODES * 8 * 4;
    float*    adb  = (float*)w;        w += (size_t)N_NODES * 8 * 4;
    float*    MeAll= (float*)w;        w += 120 * 4;
    float*    pooled=(float*)w;        w += (size_t)N_GRAPH * NHC * 4;
    _Float16* W1th = (_Float16*)w;     w += (size_t)NHC * DIN * 2;
    _Float16* W2th = (_Float16*)w;     w += (size_t)NHC * NHC * 2;
    _Float16* W3th = (_Float16*)w;     w += (size_t)NHC * NHC * 2;
    _Float16* F1th = (_Float16*)w;     w += (size_t)NHC * NHC * 2;
    int* gcnt     = (int*)w;           w += N_GRAPH * 4;
    int* deg      = (int*)w;           w += (size_t)N_NODES * 4;
    int* rowstart = (int*)w;           w += (size_t)(N_NODES + 1) * 4;
    int* cursor   = (int*)w;           w += (size_t)N_NODES * 4;
    int* partial  = (int*)w;           w += 256 * 4;
    w = (char*)(((size_t)w + 15) & ~(size_t)15);
    int2* csr     = (int2*)w;          w += (size_t)N_EDGES * 8;

    const int NB = (N_NODES + 255) / 256;

    prep_kernel<<<(JTOT + 255) / 256, 256, 0, stream>>>(
        x, W[0], W[1], W[2], fcW1,
        xh, W1th, W2th, W3th, F1th,
        pooled, deg, gcnt);
    count_hist_kernel<<<(N_EDGES + 255) / 256, 256, 0, stream>>>(ei, bat, deg, gcnt, N_EDGES, N_NODES);
    scan_block_kernel<<<NB, 256, 0, stream>>>(deg, rowstart, partial, N_NODES);
    scan_partial_kernel<<<1, 256, 0, stream>>>(partial, NB);
    scan_add_kernel<<<NB, 256, 0, stream>>>(rowstart, partial, cursor, N_NODES, N_EDGES);
    fill_kernel<<<(N_EDGES + 255) / 256, 256, 0, stream>>>(ei, cursor, csr, N_EDGES);
    me_all_kernel<<<3, 64, 0, stream>>>(Wel[0], Ael[0], Wel[1], Ael[1], Wel[2], Ael[2], MeAll);

    const int Hs[3] = {8, 8, 1};
    const int CL[3] = {5, 5, 8};
    const int Ks[3] = {DIN, NHC, NHC};

    const dim3 ggrid(4, 392);

    const _Float16* curh = xh;
    const _Float16* Wth[3] = {W1th, W2th, W3th};
    for (int l = 0; l < 3; l++) {
        const int H = Hs[l];
        const bool fuse = (l != 2);
        mfma_gemm_kernel<<<ggrid, 256, 0, stream>>>(
            curh, Wth[l], nullptr, h,
            fuse ? Asl[l] : nullptr, fuse ? Adl[l] : nullptr, asb, adb,
            nullptr, nullptr,
            N_NODES, Ks[l], 0);
        if (!fuse)
            asd_kernel<<<(N_NODES + 255) / 256, 256, 0, stream>>>(
                h, Asl[l], Adl[l], asb, adb, N_NODES);
        gat_agg_kernel<<<(N_NODES + 3) / 4, 256, 0, stream>>>(
            rowstart, csr, ea, asb, adb, MeAll + l * 40, h, Bil[l], xbh, H, CL[l]);
        curh = xbh;
    }

    // fc1 + fused gelu + per-graph pooling (fc2 commutes with pooling)
    mfma_gemm_kernel<<<ggrid, 256, 0, stream>>>(
        xbh, F1th, fcb1, nullptr,
        nullptr, nullptr, nullptr, nullptr,
        bat, pooled,
        N_NODES, NHC, 3);
    final_kernel<<<N_GRAPH, 64, 0, stream>>>(pooled, gcnt, fcW2, fcb2, (float*)d_out);
}